// Round 8
// baseline (621.430 us; speedup 1.0000x reference)
//
#include <hip/hip_runtime.h>
#include <hip/hip_bf16.h>

// GatedDeltaNet B=4 T=8192 D=768 H=12 K=V=64 — chunked WY + two-level scan.
// Round 8: GEMM = 3-buffer depth-2 pipeline with counted vmcnt(8) + raw
// s_barrier (T3/T4); scfuse restructured to 5 barriers/iter (9 LDS tiles);
// bgraw write predicated to live 24 cols.

typedef __attribute__((ext_vector_type(8))) short short8;
typedef __attribute__((ext_vector_type(4))) float floatx4;

#define DEVFN static __device__ __forceinline__

typedef const __attribute__((address_space(1))) unsigned int* as1_u32p;
typedef __attribute__((address_space(3))) unsigned int* as3_u32p;

DEVFN void gll16(const void* g, void* l) {
  __builtin_amdgcn_global_load_lds((as1_u32p)g, (as3_u32p)l, 16, 0, 0);
}

DEVFN unsigned short f2bf_u(float f) {
  __hip_bfloat16 h = __float2bfloat16(f);
  return __builtin_bit_cast(unsigned short, h);
}
DEVFN float bf2f(unsigned short u) {
  return __bfloat162float(__builtin_bit_cast(__hip_bfloat16, u));
}

static constexpr int T_LEN = 8192;
static constexpr int ROWS  = 4 * 8192;   // 32768
static constexpr int D     = 768;
static constexpr int NKV   = 1664;
static constexpr int NC    = 128;        // chunks per sequence (C=64)
static constexpr int NBH   = 48;         // B*H
static constexpr int NWG1  = NBH * NC;   // 6144
static constexpr int NG    = 16;         // groups per bh (8 chunks each)
static constexpr int NGRP  = NBH * NG;   // 768
static constexpr int CSTR  = 192;        // csbuf: [0:64) incl, [64:128) excl, [128:192) beta

// ---- swizzled 64-col bf16 LDS tile helpers (row stride 128B, slot-XOR) ----
DEVFN int swz16(int row, int slot) {
  return (row << 7) + (((slot ^ (row & 7)) & 7) << 4);
}
DEVFN int swzE(int row, int col) {
  return (row << 7) + ((((col >> 3) ^ (row & 7)) & 7) << 4) + ((col & 7) << 1);
}
DEVFN void st_bf(char* base, int row, int col, float v) {
  *(unsigned short*)(base + swzE(row, col)) = f2bf_u(v);
}
DEVFN float ld_bf(const char* base, int row, int col) {
  return bf2f(*(const unsigned short*)(base + swzE(row, col)));
}
// D[16-band x 64] += A[band]·B^T over 64-col tiles (both swizzled)
DEVFN void mm16x64(const char* aB, const char* bB, int wv, int lane, floatx4 acc[4]) {
  #pragma unroll
  for (int ks = 0; ks < 2; ++ks) {
    short8 af = *(const short8*)(aB + swz16(wv * 16 + (lane & 15), ks * 4 + (lane >> 4)));
    #pragma unroll
    for (int t = 0; t < 4; ++t) {
      short8 bf = *(const short8*)(bB + swz16(t * 16 + (lane & 15), ks * 4 + (lane >> 4)));
      acc[t] = __builtin_amdgcn_mfma_f32_16x16x32_bf16(af, bf, acc[t], 0, 0, 0);
    }
  }
}

// ---------------- weight prep ----------------
__global__ void k_prep_wt(const float* __restrict__ Wk, const float* __restrict__ Wv,
                          const float* __restrict__ Wb, const float* __restrict__ Wg,
                          __hip_bfloat16* __restrict__ WT) {
  int idx = blockIdx.x * 256 + threadIdx.x;
  if (idx >= NKV * D) return;
  int n = idx / D, k = idx % D;
  float v;
  if (n < 768)       v = Wk[k * 768 + n];
  else if (n < 1536) v = Wv[k * 768 + (n - 768)];
  else if (n < 1548) v = Wb[k * 12 + (n - 1536)];
  else if (n < 1560) v = Wg[k * 12 + (n - 1548)];
  else               v = 0.f;
  WT[idx] = __float2bfloat16(v);
}

__global__ void k_prep_wo(const float* __restrict__ Wo, __hip_bfloat16* __restrict__ WoT) {
  int idx = blockIdx.x * 256 + threadIdx.x;
  int n = idx / D, k = idx % D;
  WoT[idx] = __float2bfloat16(Wo[k * 768 + n]);
}

// ---------------- RMSNorm ----------------
__global__ void k_rmsnorm(const float* __restrict__ x, const float* __restrict__ wn,
                          __hip_bfloat16* __restrict__ xn) {
  int wid  = (blockIdx.x << 2) + (threadIdx.x >> 6);
  int lane = threadIdx.x & 63;
  const float* xr = x + (size_t)wid * D;
  float4 a = *(const float4*)(xr + lane * 4);
  float4 b = *(const float4*)(xr + 256 + lane * 4);
  float4 c = *(const float4*)(xr + 512 + lane * 4);
  float ss = a.x*a.x + a.y*a.y + a.z*a.z + a.w*a.w
           + b.x*b.x + b.y*b.y + b.z*b.z + b.w*b.w
           + c.x*c.x + c.y*c.y + c.z*c.z + c.w*c.w;
  #pragma unroll
  for (int m = 1; m < 64; m <<= 1) ss += __shfl_xor(ss, m);
  float rs = rsqrtf(ss * (1.f / 768.f) + 1e-6f);
  float4 w0 = *(const float4*)(wn + lane * 4);
  float4 w1 = *(const float4*)(wn + 256 + lane * 4);
  float4 w2 = *(const float4*)(wn + 512 + lane * 4);
  unsigned short* xo = (unsigned short*)(xn + (size_t)wid * D);
  ushort4 u;
  u.x = f2bf_u(a.x*rs*w0.x); u.y = f2bf_u(a.y*rs*w0.y); u.z = f2bf_u(a.z*rs*w0.z); u.w = f2bf_u(a.w*rs*w0.w);
  *(ushort4*)(xo + lane * 4) = u;
  u.x = f2bf_u(b.x*rs*w1.x); u.y = f2bf_u(b.y*rs*w1.y); u.z = f2bf_u(b.z*rs*w1.z); u.w = f2bf_u(b.w*rs*w1.w);
  *(ushort4*)(xo + 256 + lane * 4) = u;
  u.x = f2bf_u(c.x*rs*w2.x); u.y = f2bf_u(c.y*rs*w2.y); u.z = f2bf_u(c.z*rs*w2.z); u.w = f2bf_u(c.w*rs*w2.w);
  *(ushort4*)(xo + 512 + lane * 4) = u;
}

// ---------------- bf16 MFMA GEMM, 128x128 tile, 3-buffer depth-2 pipeline ----
// LDS (row r, slot s) holds GLOBAL chunk (r, s ^ (r&7)) (both-sides swizzle).
// Pipeline: tiles t+1, t+2 in flight across each barrier; per-iter
// s_waitcnt vmcnt(8) keeps t+2's 8 loads flying (T4 counted-vmcnt).
template <int EPI>
__global__ __launch_bounds__(256)
void k_gemm(const __hip_bfloat16* __restrict__ A, const __hip_bfloat16* __restrict__ Bt,
            __hip_bfloat16* __restrict__ Ck, __hip_bfloat16* __restrict__ Cv,
            float* __restrict__ Cbg, float* __restrict__ C0, const float* __restrict__ Xadd) {
  __shared__ __align__(16) unsigned short As[3][128 * 64];
  __shared__ __align__(16) unsigned short Bs[3][128 * 64];
  const int K = 768, NKT = 12;
  int tid = threadIdx.x, lane = tid & 63, w = tid >> 6;
  int wr = w >> 1, wc = w & 1;
  int bx = blockIdx.x;                     // 256 m-blocks = 8 XCD chunks of 32
  bx = (bx & 7) * 32 + (bx >> 3);
  int m0 = bx * 128, n0 = blockIdx.y * 128;
  floatx4 zero = {0.f, 0.f, 0.f, 0.f};
  floatx4 acc[4][4];
  #pragma unroll
  for (int i = 0; i < 4; ++i)
    #pragma unroll
    for (int j = 0; j < 4; ++j) acc[i][j] = zero;

  auto stage = [&](int buf, int kt) {      // 8 VMEM instrs per wave
    #pragma unroll
    for (int it = 0; it < 4; ++it) {
      int L = it * 256 + tid;
      int r = L >> 3, s = L & 7, sg = s ^ (r & 7);
      gll16(A  + (size_t)(m0 + r) * K + kt * 64 + sg * 8, &As[buf][L * 8]);
      gll16(Bt + (size_t)(n0 + r) * K + kt * 64 + sg * 8, &Bs[buf][L * 8]);
    }
  };

  stage(0, 0);
  stage(1, 1);
  asm volatile("s_waitcnt vmcnt(8)" ::: "memory");   // tile0 resident
  __builtin_amdgcn_s_barrier();
  for (int kt = 0; kt < NKT; ++kt) {
    int cb = kt % 3;
    if (kt + 2 < NKT) stage((kt + 2) % 3, kt + 2);   // overwrites tile kt-1's buf (safe post-barrier)
    __builtin_amdgcn_s_setprio(1);
    #pragma unroll
    for (int ks = 0; ks < 2; ++ks) {
      int c = ks * 4 + (lane >> 4);
      short8 af[4], bfr[4];
      #pragma unroll
      for (int i = 0; i < 4; ++i) {
        int ri = wr * 64 + i * 16 + (lane & 15);
        af[i] = *(const short8*)&As[cb][ri * 64 + ((c ^ (ri & 7)) << 3)];
      }
      #pragma unroll
      for (int j = 0; j < 4; ++j) {
        int rj = wc * 64 + j * 16 + (lane & 15);
        bfr[j] = *(const short8*)&Bs[cb][rj * 64 + ((c ^ (rj & 7)) << 3)];
      }
      #pragma unroll
      for (int i = 0; i < 4; ++i)
        #pragma unroll
        for (int j = 0; j < 4; ++j)
          acc[i][j] = __builtin_amdgcn_mfma_f32_16x16x32_bf16(af[i], bfr[j], acc[i][j], 0, 0, 0);
    }
    __builtin_amdgcn_s_setprio(0);
    if (kt + 2 < NKT)      asm volatile("s_waitcnt vmcnt(8)" ::: "memory");  // tile kt+1 done; kt+2 flying
    else if (kt + 1 < NKT) asm volatile("s_waitcnt vmcnt(0)" ::: "memory");  // drain tail
    __builtin_amdgcn_s_barrier();
  }

  if constexpr (EPI == 0) {
    if (n0 < 768) {
      #pragma unroll
      for (int i = 0; i < 4; ++i) {
        #pragma unroll
        for (int r = 0; r < 4; ++r) {
          float ss = 0.f;
          #pragma unroll
          for (int j = 0; j < 4; ++j) { float t = acc[i][j][r]; ss = fmaf(t, t, ss); }
          ss += __shfl_xor(ss, 1); ss += __shfl_xor(ss, 2);
          ss += __shfl_xor(ss, 4); ss += __shfl_xor(ss, 8);
          float sc = 1.f / fmaxf(sqrtf(ss), 1e-12f);
          int mm = m0 + wr * 64 + i * 16 + (lane >> 4) * 4 + r;
          #pragma unroll
          for (int j = 0; j < 4; ++j) {
            int n = n0 + wc * 64 + j * 16 + (lane & 15);
            Ck[(size_t)mm * 768 + n] = __float2bfloat16(acc[i][j][r] * sc);
          }
        }
      }
    } else if (n0 < 1536) {
      #pragma unroll
      for (int i = 0; i < 4; ++i)
        #pragma unroll
        for (int j = 0; j < 4; ++j) {
          int n = n0 + wc * 64 + j * 16 + (lane & 15) - 768;
          #pragma unroll
          for (int r = 0; r < 4; ++r) {
            int mm = m0 + wr * 64 + i * 16 + (lane >> 4) * 4 + r;
            Cv[(size_t)mm * 768 + n] = __float2bfloat16(acc[i][j][r]);
          }
        }
    } else {
      #pragma unroll
      for (int i = 0; i < 4; ++i)
        #pragma unroll
        for (int j = 0; j < 4; ++j) {
          int n = n0 + wc * 64 + j * 16 + (lane & 15) - 1536;
          if (n < 24) {                     // only 24 live beta/g cols
            #pragma unroll
            for (int r = 0; r < 4; ++r) {
              int mm = m0 + wr * 64 + i * 16 + (lane >> 4) * 4 + r;
              Cbg[(size_t)mm * 128 + n] = acc[i][j][r];
            }
          }
        }
    }
  } else {
    #pragma unroll
    for (int i = 0; i < 4; ++i)
      #pragma unroll
      for (int j = 0; j < 4; ++j) {
        int n = n0 + wc * 64 + j * 16 + (lane & 15);
        #pragma unroll
        for (int r = 0; r < 4; ++r) {
          int mm = m0 + wr * 64 + i * 16 + (lane >> 4) * 4 + r;
          size_t o = (size_t)mm * 768 + n;
          C0[o] = Xadd[o] + acc[i][j][r];
        }
      }
  }
}

// ---------------- fused sigmoid + gate prefix ----------------
__global__ void k_gates2(const float* __restrict__ bgraw, const float* __restrict__ bb,
                         const float* __restrict__ bgb, float* __restrict__ csbuf) {
  int wid  = blockIdx.x * 4 + (threadIdx.x >> 6);   // bh*NC + ck
  int lane = threadIdx.x & 63;
  int bh = wid >> 7, ck = wid & 127;
  int b = bh / 12, h = bh % 12;
  size_t row0 = (size_t)b * T_LEN + (size_t)ck * 64;
  const float* br = bgraw + (row0 + lane) * 128;
  float bet = 1.f / (1.f + __expf(-(br[h] + bb[h])));
  float g   = 1.f / (1.f + __expf(-(br[12 + h] + bgb[h])));
  float lg = __log2f(g);
  float ci = lg;
  #pragma unroll
  for (int d = 1; d < 64; d <<= 1) { float t = __shfl_up(ci, d); if (lane >= d) ci += t; }
  csbuf[(size_t)wid * CSTR + lane] = ci;
  csbuf[(size_t)wid * CSTR + 64 + lane] = ci - lg;
  csbuf[(size_t)wid * CSTR + 128 + lane] = bet;
}

// ---------------- pass 1: per-chunk WY factors (Uv, W) ----------------
__global__ __launch_bounds__(256)
void k_chunk1(const __hip_bfloat16* __restrict__ kb16, const __hip_bfloat16* __restrict__ vbuf,
              const float* __restrict__ csbuf,
              __hip_bfloat16* __restrict__ Uvt_g, __hip_bfloat16* __restrict__ W_g) {
  __shared__ __align__(16) char sm[6 * 8192 + 768];
  char* SA = sm;
  char* SB = sm + 8192;
  char* SC = sm + 2 * 8192;
  char* SD = sm + 3 * 8192;   // SD,SE contiguous (RHST spans both)
  char* SE = sm + 4 * 8192;
  char* SF = sm + 5 * 8192;
  float* cs   = (float*)(sm + 6 * 8192);
  float* cps  = (float*)(sm + 6 * 8192 + 256);
  float* bets = (float*)(sm + 6 * 8192 + 512);

  int blk = blockIdx.x, bh = blk >> 7, ck = blk & 127;
  int b = bh / 12, h = bh % 12;
  int tid = threadIdx.x, lane = tid & 63, wv = tid >> 6;
  size_t row0 = (size_t)b * T_LEN + (size_t)ck * 64;
  size_t wbase = (size_t)blk * 4096;

  if (tid < 64) {
    cs[tid]   = csbuf[(size_t)blk * CSTR + tid];
    cps[tid]  = csbuf[(size_t)blk * CSTR + 64 + tid];
    bets[tid] = csbuf[(size_t)blk * CSTR + 128 + tid];
  }
  int sr = tid >> 2, sc0 = (tid & 3) * 16;
  {
    const __hip_bfloat16* kp = kb16 + (row0 + sr) * 768 + h * 64 + sc0;
    short8 k0 = *(const short8*)kp;
    short8 k1 = *(const short8*)(kp + 8);
    *(short8*)(SA + swz16(sr, sc0 >> 3)) = k0;
    *(short8*)(SA + swz16(sr, (sc0 >> 3) + 1)) = k1;
  }
  short8 vreg0, vreg1;
  {
    const __hip_bfloat16* vp = vbuf + (row0 + sr) * 768 + h * 64 + sc0;
    vreg0 = *(const short8*)vp;
    vreg1 = *(const short8*)(vp + 8);
  }
  __syncthreads();

  floatx4 acc[4];
  auto zacc = [&] {
    #pragma unroll
    for (int t = 0; t < 4; ++t) acc[t] = (floatx4){0.f, 0.f, 0.f, 0.f};
  };
  auto forRC = [&](auto&& f) {
    #pragma unroll
    for (int t = 0; t < 4; ++t)
      #pragma unroll
      for (int r = 0; r < 4; ++r)
        f(wv * 16 + (lane >> 4) * 4 + r, t * 16 + (lane & 15), acc[t][r]);
  };

  // G = K K^T -> L(SB), Lt(SC), M1=I-L(SD)
  zacc(); mm16x64(SA, SA, wv, lane, acc);
  forRC([&](int i, int j, float v) {
    float Lv = 0.f;
    if (j < i) Lv = bets[i] * exp2f(cps[i] - cs[j]) * v;
    st_bf(SB, i, j, Lv);
    st_bf(SC, j, i, Lv);
    st_bf(SD, i, j, (i == j ? 1.f : 0.f) - Lv);
  });
  __syncthreads();

  auto power = [&](char* Ar, char* Bt, char* Or, char* Ot) {
    zacc(); mm16x64(Ar, Bt, wv, lane, acc);
    forRC([&](int i, int j, float v) { st_bf(Or, i, j, v); st_bf(Ot, j, i, v); });
    __syncthreads();
  };
  auto powerT = [&](char* Ar, char* Bt, char* Ot) {
    zacc(); mm16x64(Ar, Bt, wv, lane, acc);
    forRC([&](int i, int j, float v) { st_bf(Ot, j, i, v); });
    __syncthreads();
  };
  auto combine = [&](char* Mr, char* Pt, char* Out) {
    zacc(); mm16x64(Mr, Pt, wv, lane, acc);
    forRC([&](int i, int j, float v) { st_bf(Out, i, j, v + ld_bf(Mr, i, j)); });
    __syncthreads();
  };

  power(SB, SC, SE, SF);    // L^2
  combine(SD, SF, SB);      // M2
  power(SE, SF, SC, SD);    // L^4
  combine(SB, SD, SE);      // M3
  power(SC, SD, SF, SB);    // L^8
  combine(SE, SB, SC);      // M4
  power(SF, SB, SD, SE);    // L^16
  combine(SC, SE, SF);      // M5
  powerT(SD, SE, SB);       // L^32t
  combine(SF, SB, SC);      // T -> SC

  // RHST (128 x 64): rows c<64: beta_i*V[i][c]; rows 64+k: beta_i*gprev_i*K[i][k]
  {
    float be = bets[sr];
    #pragma unroll
    for (int q = 0; q < 8; ++q) {
      st_bf(SD, sc0 + q,     sr, be * bf2f(((unsigned short*)&vreg0)[q]));
      st_bf(SD, sc0 + 8 + q, sr, be * bf2f(((unsigned short*)&vreg1)[q]));
    }
    float scl = be * exp2f(cps[sr]);
    #pragma unroll
    for (int q = 0; q < 16; ++q) {
      float kv = ld_bf(SA, sr, sc0 + q);
      st_bf(SD, 64 + sc0 + q, sr, scl * kv);
    }
  }
  __syncthreads();

  // X = T * RHS -> Uvt to SF; W^T rows to HBM (Wt layout [k][j])
  {
    floatx4 xacc[8];
    #pragma unroll
    for (int t = 0; t < 8; ++t) xacc[t] = (floatx4){0.f, 0.f, 0.f, 0.f};
    #pragma unroll
    for (int ks = 0; ks < 2; ++ks) {
      short8 af = *(const short8*)(SC + swz16(wv * 16 + (lane & 15), ks * 4 + (lane >> 4)));
      #pragma unroll
      for (int t = 0; t < 8; ++t) {
        short8 bf = *(const short8*)(SD + swz16(t * 16 + (lane & 15), ks * 4 + (lane >> 4)));
        xacc[t] = __builtin_amdgcn_mfma_f32_16x16x32_bf16(af, bf, xacc[t], 0, 0, 0);
      }
    }
    #pragma unroll
    for (int t = 0; t < 8; ++t) {
      int c = t * 16 + (lane & 15);
      #pragma unroll
      for (int r = 0; r < 4; ++r) {
        int i = wv * 16 + (lane >> 4) * 4 + r;
        float v = xacc[t][r];
        if (c < 64) st_bf(SF, c, i, v);
        else        W_g[wbase + (size_t)(c - 64) * 64 + i] = __float2bfloat16(v);
      }
    }
  }
  __syncthreads();

  {
    int s2 = (tid & 3) * 2;
    short8 a0 = *(const short8*)(SF + swz16(sr, s2));
    short8 a1 = *(const short8*)(SF + swz16(sr, s2 + 1));
    *(short8*)(Uvt_g + wbase + (size_t)sr * 64 + s2 * 8) = a0;
    *(short8*)(Uvt_g + wbase + (size_t)sr * 64 + s2 * 8 + 8) = a1;
  }
}

// ---------------- scan A: per-group (8 chunks) map composition ----------------
__global__ __launch_bounds__(256)
void k_scanA(const __hip_bfloat16* __restrict__ kb16, const __hip_bfloat16* __restrict__ W_g,
             const __hip_bfloat16* __restrict__ Uvt_g, const float* __restrict__ csbuf,
             __hip_bfloat16* __restrict__ Ag_g, __hip_bfloat16* __restrict__ Bg_g) {
  __shared__ __align__(16) char sm[7 * 8192];
  char* SK  = sm;              // Ktil^T [k][t]
  char* SW  = sm + 8192;       // Wt [k][j]
  char* SU  = sm + 2 * 8192;   // Uvt [v][t]
  char* SAc = sm + 3 * 8192;   // Ac [ko][ki]
  char* SBc = sm + 4 * 8192;   // Bct [v][k]
  char* SAt = sm + 5 * 8192;   // Aacc^T [ki][ko]
  char* SBa = sm + 6 * 8192;   // Bacc [v][k]

  int blk = blockIdx.x, bh = blk >> 4, gg = blk & 15;
  int b = bh / 12, h = bh % 12;
  int tid = threadIdx.x, lane = tid & 63, wv = tid >> 6;
  int sr = tid >> 2, sc0 = (tid & 3) * 16, s2 = (tid & 3) * 2;
  int c0 = gg * 8;

  short8 z = {0, 0, 0, 0, 0, 0, 0, 0};
  *(short8*)(SAt + swz16(sr, s2)) = z;
  *(short8*)(SAt + swz16(sr, s2 + 1)) = z;
  *(short8*)(SBa + swz16(sr, s2)) = z;
  *(short8*)(SBa + swz16(sr, s2 + 1)) = z;
  __syncthreads();
  if (tid < 64) st_bf(SAt, tid, tid, 1.f);   // Aacc = I

  floatx4 acc[4];
  auto zacc = [&] {
    #pragma unroll
    for (int t = 0; t < 4; ++t) acc[t] = (floatx4){0.f, 0.f, 0.f, 0.f};
  };
  auto forRC = [&](auto&& f) {
    #pragma unroll
    for (int t = 0; t < 4; ++t)
      #pragma unroll
      for (int r = 0; r < 4; ++r)
        f(wv * 16 + (lane >> 4) * 4 + r, t * 16 + (lane & 15), acc[t][r]);
  };

  for (int cc = 0; cc < 8; ++cc) {
    int c = c0 + cc;
    size_t row0 = (size_t)b * T_LEN + (size_t)c * 64;
    size_t wb = ((size_t)bh * NC + c) * 4096;
    const float* csb = csbuf + (size_t)(bh * NC + c) * CSTR;
    float cs_sr = csb[sr], cs63 = csb[63];
    const __hip_bfloat16* kp = kb16 + (row0 + sr) * 768 + h * 64 + sc0;
    short8 k0 = *(const short8*)kp, k1 = *(const short8*)(kp + 8);
    const __hip_bfloat16* wp = W_g + wb + (size_t)sr * 64 + s2 * 8;
    short8 w0 = *(const short8*)wp, w1 = *(const short8*)(wp + 8);
    const __hip_bfloat16* up = Uvt_g + wb + (size_t)sr * 64 + s2 * 8;
    short8 u0 = *(const short8*)up, u1 = *(const short8*)(up + 8);
    // stage
    float scl = exp2f(cs63 - cs_sr);
    #pragma unroll
    for (int q = 0; q < 8; ++q) {
      st_bf(SK, sc0 + q,     sr, scl * bf2f(((unsigned short*)&k0)[q]));
      st_bf(SK, sc0 + 8 + q, sr, scl * bf2f(((unsigned short*)&k1)[q]));
    }
    *(short8*)(SW + swz16(sr, s2)) = w0;
    *(short8*)(SW + swz16(sr, s2 + 1)) = w1;
    *(short8*)(SU + swz16(sr, s2)) = u0;
    *(short8*)(SU + swz16(sr, s2 + 1)) = u1;
    __syncthreads();   // (a) staged; prev compose's SAc/SBc reads done
    float gC = exp2f(cs63);
    zacc(); mm16x64(SW, SK, wv, lane, acc);
    forRC([&](int i, int j, float v) { st_bf(SAc, j, i, ((i == j) ? gC : 0.f) - v); });
    zacc(); mm16x64(SU, SK, wv, lane, acc);
    forRC([&](int i, int j, float v) { st_bf(SBc, i, j, v); });
    __syncthreads();   // (b) Ac/Bc ready
    // compose in place (A-operand rows are wave-private)
    zacc(); mm16x64(SAt, SAc, wv, lane, acc);
    forRC([&](int i, int j, float v) { st_bf(SAt, i, j, v); });
    zacc(); mm16x64(SBa, SAc, wv, lane, acc);
    forRC([&](int i, int j, float v) { st_bf(SBa, i, j, v + ld_bf(SBc, i, j)); });
  }
  __syncthreads();
  // Ag rows [ko][ki] (scatter-transpose from SAt), Bg rows [v][k] (vector)
  size_t gb = (size_t)blk * 4096;
  #pragma unroll
  for (int q = 0; q < 16; ++q)
    Ag_g[gb + (size_t)(sc0 + q) * 64 + sr] = __float2bfloat16(ld_bf(SAt, sr, sc0 + q));
  {
    short8 b0 = *(const short8*)(SBa + swz16(sr, s2));
    short8 b1 = *(const short8*)(SBa + swz16(sr, s2 + 1));
    *(short8*)(Bg_g + gb + (size_t)sr * 64 + s2 * 8) = b0;
    *(short8*)(Bg_g + gb + (size_t)sr * 64 + s2 * 8 + 8) = b1;
  }
}

// ---------------- scan B: 16 serial group composes ----------------
__global__ __launch_bounds__(256)
void k_scanB(const __hip_bfloat16* __restrict__ Ag_g, const __hip_bfloat16* __restrict__ Bg_g,
             __hip_bfloat16* __restrict__ Sg_g, float* __restrict__ fstate) {
  __shared__ __align__(16) char sm[3 * 8192];
  char* SSt = sm;
  char* SAg = sm + 8192;
  char* SBg = sm + 2 * 8192;
  int bh = blockIdx.x;
  int tid = threadIdx.x, lane = tid & 63, wv = tid >> 6;
  int sr = tid >> 2, s2 = (tid & 3) * 2;

  short8 z = {0, 0, 0, 0, 0, 0, 0, 0};
  *(short8*)(SSt + swz16(sr, s2)) = z;
  *(short8*)(SSt + swz16(sr, s2 + 1)) = z;

  floatx4 acc[4];
  for (int g = 0; g < NG; ++g) {
    size_t gb = ((size_t)bh * NG + g) * 4096;
    const __hip_bfloat16* pa = Ag_g + gb + (size_t)sr * 64 + s2 * 8;
    short8 a0 = *(const short8*)pa, a1 = *(const short8*)(pa + 8);
    const __hip_bfloat16* pb = Bg_g + gb + (size_t)sr * 64 + s2 * 8;
    short8 b0 = *(const short8*)pb, b1 = *(const short8*)(pb + 8);
    __syncthreads();             // SSt stable; prev compose's SAg/SBg reads done
    {  // write group-start state
      short8 s0 = *(const short8*)(SSt + swz16(sr, s2));
      short8 s1 = *(const short8*)(SSt + swz16(sr, s2 + 1));
      *(short8*)(Sg_g + gb + (size_t)sr * 64 + s2 * 8) = s0;
      *(short8*)(Sg_g + gb + (size_t)sr * 64 + s2 * 8 + 8) = s1;
    }
    *(short8*)(SAg + swz16(sr, s2)) = a0;
    *(short8*)(SAg + swz16(sr, s2 + 1)) = a1;
    *(short8*)(SBg + swz16(sr, s2)) = b0;
    *(short8*)(SBg + swz16(sr, s2 + 1)) = b1;
    __syncthreads();
    #pragma unroll
    for (int t = 0; t < 4; ++t) acc[t] = (floatx4){0.f, 0.f, 0.f, 0.f};
    mm16x64(SSt, SAg, wv, lane, acc);
    #pragma unroll
    for (int t = 0; t < 4; ++t) {
      int j = t * 16 + (lane & 15);
      #pragma unroll
      for (int r = 0; r < 4; ++r) {
        int i = wv * 16 + (lane >> 4) * 4 + r;
        float val = acc[t][r] + ld_bf(SBg, i, j);
        st_bf(SSt, i, j, val);
        if (g == NG - 1) fstate[(size_t)bh * 4096 + (size_t)j * 64 + i] = val;
      }
    }
  }
}

// ---------------- fused scan C + outputs (5 barriers/iter, 9 tiles) ----------------
__global__ __launch_bounds__(256)
void k_scfuse(const __hip_bfloat16* __restrict__ kb16, const __hip_bfloat16* __restrict__ W_g,
              const __hip_bfloat16* __restrict__ Uvt_g, const float* __restrict__ csbuf,
              const __hip_bfloat16* __restrict__ Sg_g, __hip_bfloat16* __restrict__ outs) {
  __shared__ __align__(16) char sm[9 * 8192];
  char* SSt = sm;              // state [v][k]
  char* SKr = sm + 8192;       // raw K [t][k]; last phase: out bounce [t][v]
  char* SKt = sm + 2 * 8192;   // Ktil^T [k][t]
  char* SG  = sm + 3 * 8192;   // scaled G [i][j]
  char* SW  = sm + 4 * 8192;   // Wt [k][j]
  char* SW2 = sm + 5 * 8192;   // W row-major [j][k]
  char* SU  = sm + 6 * 8192;   // Uvt [v][t] -> Ueff
  char* SAc = sm + 7 * 8192;
  char* SBc = sm + 8 * 8192;

  int blk = blockIdx.x, bh = blk >> 4, gg = blk & 15;
  int b = bh / 12, h = bh % 12;
  int tid = threadIdx.x, lane = tid & 63, wv = tid >> 6;
  int sr = tid >> 2, sc0 = (tid & 3) * 16, s2 = (tid & 3) * 2;
  int c0 = gg * 8;
  int iR0 = wv * 16 + (lane >> 4) * 4;

  {
    const __hip_bfloat16* sp = Sg_g + (size_t)blk * 4096 + (size_t)sr * 64 + s2 * 8;
    short8 s0 = *(const short8*)sp, s1 = *(const short8*)(sp + 8);
    *(short8*)(SSt + swz16(sr, s2)) = s0;
    *(short8*)(SSt + swz16(sr, s2 + 1)) = s1;
  }

  floatx4 acc[4], pAcc[4];
  auto zacc = [&] {
    #pragma unroll
    for (int t = 0; t < 4; ++t) acc[t] = (floatx4){0.f, 0.f, 0.f, 0.f};
  };
  auto forRC = [&](auto&& f) {
    #pragma unroll
    for (int t = 0; t < 4; ++t)
      #pragma unroll
      for (int r = 0; r < 4; ++r)
        f(iR0 + r, t * 16 + (lane & 15), acc[t][r]);
  };

  for (int cc = 0; cc < 8; ++cc) {
    int c = c0 + cc;
    size_t row0 = (size_t)b * T_LEN + (size_t)c * 64;
    size_t wb = ((size_t)bh * NC + c) * 4096;
    const float* csb = csbuf + (size_t)(bh * NC + c) * CSTR;
    float cs_sr = csb[sr], cs63 = csb[63];
    float csI[4], csJ[4];
    #pragma unroll
    for (int r = 0; r < 4; ++r) csI[r] = csb[iR0 + r];
    #pragma unroll
    for (int t = 0; t < 4; ++t) csJ[t] = csb[t * 16 + (lane & 15)];
    const __hip_bfloat16* kp = kb16 + (row0 + sr) * 768 + h * 64 + sc0;
    short8 k0 = *(const short8*)kp, k1 = *(const short8*)(kp + 8);
    const __hip_bfloat16* wp = W_g + wb + (size_t)sr * 64 + sc0;
    short8 w0 = *(const short8*)wp, w1 = *(const short8*)(wp + 8);
    const __hip_bfloat16* up = Uvt_g + wb + (size_t)sr * 64 + sc0;
    short8 u0 = *(const short8*)up, u1 = *(const short8*)(up + 8);
    __syncthreads();             // bar0: prev iter's LDS reads done
    // stage all five tiles
    *(short8*)(SKr + swz16(sr, sc0 >> 3)) = k0;
    *(short8*)(SKr + swz16(sr, (sc0 >> 3) + 1)) = k1;
    {
      float scl = exp2f(cs63 - cs_sr);
      #pragma unroll
      for (int q = 0; q < 8; ++q) {
        st_bf(SKt, sc0 + q,     sr, scl * bf2f(((unsigned short*)&k0)[q]));
        st_bf(SKt, sc0 + 8 + q, sr, scl * bf2f(((unsigned short*)&k1)[q]));
      }
    }
    *(short8*)(SW + swz16(sr, s2)) = w0;
    *(short8*)(SW + swz16(sr, s2 + 1)) = w1;
    #pragma unroll
    for (int q = 0; q < 8; ++q) {   // W row-major [j][k]
      st_bf(SW2, sc0 + q,     sr, bf2f(((unsigned short*)&w0)[q]));
      st_bf(SW2, sc0 + 8 + q, sr, bf2f(((unsigned short*)&w1)[q]));
    }
    *(short8*)(SU + swz16(sr, s2)) = u0;
    *(short8*)(SU + swz16(sr, s2 + 1)) = u1;
    __syncthreads();             // bar1: staged
    // builds: Ac, Bc, scaled-G
    float gC = exp2f(cs63);
    zacc(); mm16x64(SW, SKt, wv, lane, acc);
    forRC([&](int i, int j, float v) { st_bf(SAc, j, i, ((i == j) ? gC : 0.f) - v); });
    zacc(); mm16x64(SU, SKt, wv, lane, acc);
    forRC([&](int i, int j, float v) { st_bf(SBc, i, j, v); });
    zacc(); mm16x64(SKr, SKr, wv, lane, acc);
    #pragma unroll
    for (int t = 0; t < 4; ++t) {
      int j = t * 16 + (lane & 15);
      #pragma unroll
      for (int r = 0; r < 4; ++r) {
        int i = iR0 + r;
        float gs = (j <= i) ? exp2f(csI[r] - csJ[t]) * acc[t][r] : 0.f;
        st_bf(SG, i, j, gs);
      }
    }
    __syncthreads();             // bar2: builds ready
    // P = K·S0^T (regs); Ueff = Uv - S0 x W (SU in place, own band)
    #pragma unroll
    for (int t = 0; t < 4; ++t) pAcc[t] = (floatx4){0.f, 0.f, 0.f, 0.f};
    mm16x64(SKr, SSt, wv, lane, pAcc);
    zacc(); mm16x64(SSt, SW2, wv, lane, acc);
    forRC([&](int i, int j, float v) { st_bf(SU, i, j, ld_bf(SU, i, j) - v); });
    __syncthreads();             // bar3
    // O2 = G·Ueff -> bounce into SKr; compose S' = S·Ac^T + Bc (in place)
    zacc(); mm16x64(SG, SU, wv, lane, acc);
    #pragma unroll
    for (int t = 0; t < 4; ++t) {
      int vc = t * 16 + (lane & 15);
      #pragma unroll
      for (int r = 0; r < 4; ++r) {
        int i = iR0 + r;
        float o = exp2f(csI[r]) * pAcc[t][r] + acc[t][r];
        st_bf(SKr, i, vc, o);
      }
    }
    zacc(); mm16x64(SSt, SAc, wv, lane, acc);
    forRC([&](int i, int j, float v) { st_bf(SSt, i, j, v + ld_bf(SBc, i, j)); });
    __syncthreads();             // bar4
    // coalesced out write from bounce
    {
      short8 a0 = *(const short8*)(SKr + swz16(sr, s2));
      short8 a1 = *(const short8*)(SKr + swz16(sr, s2 + 1));
      __hip_bfloat16* op = outs + (row0 + sr) * 768 + h * 64 + s2 * 8;
      *(short8*)op = a0;
      *(short8*)(op + 8) = a1;
    }
  }
}

// ---------------- host glue ----------------
extern "C" void kernel_launch(void* const* d_in, const int* in_sizes, int n_in,
                              void* d_out, int out_size, void* d_ws, size_t ws_size,
                              hipStream_t stream) {
  (void)in_sizes; (void)n_in; (void)out_size; (void)ws_size;
  const float* x   = (const float*)d_in[0];
  const float* wn  = (const float*)d_in[1];
  const float* Wk  = (const float*)d_in[2];
  const float* Wv  = (const float*)d_in[3];
  const float* Wo  = (const float*)d_in[4];
  const float* Wb  = (const float*)d_in[5];
  const float* bb  = (const float*)d_in[6];
  const float* Wg  = (const float*)d_in[7];
  const float* bgb = (const float*)d_in[8];
  float* out = (float*)d_out;

  char* ws = (char*)d_ws;
  size_t off = 0;
  const size_t TILE = (size_t)NWG1 * 4096 * 2;           // 50.3 MB
  const size_t GTILE = (size_t)NGRP * 4096 * 2;          // 6.3 MB
  // slot1: xn (dead after gemm<0>) ∪ Uvt_g (chunk1 -> scanA/scfuse)
  __hip_bfloat16* xn   = (__hip_bfloat16*)(ws + off);
  __hip_bfloat16* Uvt  = (__hip_bfloat16*)(ws + off); off += TILE;
  __hip_bfloat16* WT   = (__hip_bfloat16*)(ws + off); off += (size_t)NKV * D * 2;
  __hip_bfloat16* WoT  = (__hip_bfloat16*)(ws + off); off += (size_t)D * D * 2;
  __hip_bfloat16* kb16 = (__hip_bfloat16*)(ws + off); off += (size_t)ROWS * D * 2;
  // slot3: vbuf (dead after chunk1) ∪ outs (scfuse -> gemm<1>)
  __hip_bfloat16* vbuf = (__hip_bfloat16*)(ws + off);
  __hip_bfloat16* outsb= (__hip_bfloat16*)(ws + off); off += TILE;
  // slot4: bgraw (dead after gates2) ∪ [Ag|Bg|Sg|W_g]
  float* bgraw         = (float*)(ws + off);
  __hip_bfloat16* Ag_g = (__hip_bfloat16*)(ws + off);
  __hip_bfloat16* Bg_g = Ag_g + (size_t)NGRP * 4096;
  __hip_bfloat16* Sg_g = Bg_g + (size_t)NGRP * 4096;
  __hip_bfloat16* W_g  = Sg_g + (size_t)NGRP * 4096;
  off += 3 * GTILE + TILE;                               // 69.2 MB slot
  float* csbuf         = (float*)(ws + off);          off += (size_t)NWG1 * CSTR * 4;
  // total ~229 MiB

  k_prep_wt<<<(NKV * D + 255) / 256, 256, 0, stream>>>(Wk, Wv, Wb, Wg, WT);
  k_prep_wo<<<(D * D) / 256, 256, 0, stream>>>(Wo, WoT);
  k_rmsnorm<<<ROWS / 4, 256, 0, stream>>>(x, wn, xn);
  k_gemm<0><<<dim3(ROWS / 128, NKV / 128), 256, 0, stream>>>(xn, WT, kb16, vbuf, bgraw, nullptr, nullptr);
  k_gates2<<<NWG1 / 4, 256, 0, stream>>>(bgraw, bb, bgb, csbuf);
  k_chunk1<<<NWG1, 256, 0, stream>>>(kb16, vbuf, csbuf, Uvt, W_g);
  k_scanA<<<NGRP, 256, 0, stream>>>(kb16, W_g, Uvt, csbuf, Ag_g, Bg_g);
  k_scanB<<<NBH, 256, 0, stream>>>(Ag_g, Bg_g, Sg_g, out + (size_t)ROWS * D);
  k_scfuse<<<NGRP, 256, 0, stream>>>(kb16, W_g, Uvt, csbuf, Sg_g, outsb);
  k_gemm<1><<<dim3(ROWS / 128, D / 128), 256, 0, stream>>>(outsb, WoT, nullptr, nullptr, nullptr, out, x);
}

// Round 9
// 553.513 us; speedup vs baseline: 1.1227x; 1.1227x over previous
//
#include <hip/hip_runtime.h>
#include <hip/hip_bf16.h>

// GatedDeltaNet B=4 T=8192 D=768 H=12 K=V=64 — chunked WY + two-level scan.
// Round 9: round-7 pipeline; GEMM = 2-buffer prefetch with BK=32 (32KB LDS ->
// 4-5 blocks/CU for cross-wave latency hiding), swizzle re-derived for 4-slot
// rows; bgraw epilogue writes only 24 live cols.

typedef __attribute__((ext_vector_type(8))) short short8;
typedef __attribute__((ext_vector_type(4))) float floatx4;

#define DEVFN static __device__ __forceinline__

typedef const __attribute__((address_space(1))) unsigned int* as1_u32p;
typedef __attribute__((address_space(3))) unsigned int* as3_u32p;

DEVFN void gll16(const void* g, void* l) {
  __builtin_amdgcn_global_load_lds((as1_u32p)g, (as3_u32p)l, 16, 0, 0);
}

DEVFN unsigned short f2bf_u(float f) {
  __hip_bfloat16 h = __float2bfloat16(f);
  return __builtin_bit_cast(unsigned short, h);
}
DEVFN float bf2f(unsigned short u) {
  return __bfloat162float(__builtin_bit_cast(__hip_bfloat16, u));
}

static constexpr int T_LEN = 8192;
static constexpr int ROWS  = 4 * 8192;   // 32768
static constexpr int D     = 768;
static constexpr int NKV   = 1664;
static constexpr int NC    = 128;        // chunks per sequence (C=64)
static constexpr int NBH   = 48;         // B*H
static constexpr int NWG1  = NBH * NC;   // 6144
static constexpr int NG    = 16;         // groups per bh (8 chunks each)
static constexpr int NGRP  = NBH * NG;   // 768
static constexpr int CSTR  = 192;        // csbuf: [0:64) incl, [64:128) excl, [128:192) beta

// ---- swizzled 64-col bf16 LDS tile helpers (row stride 128B, slot-XOR) ----
DEVFN int swz16(int row, int slot) {
  return (row << 7) + (((slot ^ (row & 7)) & 7) << 4);
}
DEVFN int swzE(int row, int col) {
  return (row << 7) + ((((col >> 3) ^ (row & 7)) & 7) << 4) + ((col & 7) << 1);
}
DEVFN void st_bf(char* base, int row, int col, float v) {
  *(unsigned short*)(base + swzE(row, col)) = f2bf_u(v);
}
DEVFN float ld_bf(const char* base, int row, int col) {
  return bf2f(*(const unsigned short*)(base + swzE(row, col)));
}
// D[16-band x 64] += A[band]·B^T over 64-col tiles (both swizzled)
DEVFN void mm16x64(const char* aB, const char* bB, int wv, int lane, floatx4 acc[4]) {
  #pragma unroll
  for (int ks = 0; ks < 2; ++ks) {
    short8 af = *(const short8*)(aB + swz16(wv * 16 + (lane & 15), ks * 4 + (lane >> 4)));
    #pragma unroll
    for (int t = 0; t < 4; ++t) {
      short8 bf = *(const short8*)(bB + swz16(t * 16 + (lane & 15), ks * 4 + (lane >> 4)));
      acc[t] = __builtin_amdgcn_mfma_f32_16x16x32_bf16(af, bf, acc[t], 0, 0, 0);
    }
  }
}

// ---------------- weight prep ----------------
__global__ void k_prep_wt(const float* __restrict__ Wk, const float* __restrict__ Wv,
                          const float* __restrict__ Wb, const float* __restrict__ Wg,
                          __hip_bfloat16* __restrict__ WT) {
  int idx = blockIdx.x * 256 + threadIdx.x;
  if (idx >= NKV * D) return;
  int n = idx / D, k = idx % D;
  float v;
  if (n < 768)       v = Wk[k * 768 + n];
  else if (n < 1536) v = Wv[k * 768 + (n - 768)];
  else if (n < 1548) v = Wb[k * 12 + (n - 1536)];
  else if (n < 1560) v = Wg[k * 12 + (n - 1548)];
  else               v = 0.f;
  WT[idx] = __float2bfloat16(v);
}

__global__ void k_prep_wo(const float* __restrict__ Wo, __hip_bfloat16* __restrict__ WoT) {
  int idx = blockIdx.x * 256 + threadIdx.x;
  int n = idx / D, k = idx % D;
  WoT[idx] = __float2bfloat16(Wo[k * 768 + n]);
}

// ---------------- RMSNorm ----------------
__global__ void k_rmsnorm(const float* __restrict__ x, const float* __restrict__ wn,
                          __hip_bfloat16* __restrict__ xn) {
  int wid  = (blockIdx.x << 2) + (threadIdx.x >> 6);
  int lane = threadIdx.x & 63;
  const float* xr = x + (size_t)wid * D;
  float4 a = *(const float4*)(xr + lane * 4);
  float4 b = *(const float4*)(xr + 256 + lane * 4);
  float4 c = *(const float4*)(xr + 512 + lane * 4);
  float ss = a.x*a.x + a.y*a.y + a.z*a.z + a.w*a.w
           + b.x*b.x + b.y*b.y + b.z*b.z + b.w*b.w
           + c.x*c.x + c.y*c.y + c.z*c.z + c.w*c.w;
  #pragma unroll
  for (int m = 1; m < 64; m <<= 1) ss += __shfl_xor(ss, m);
  float rs = rsqrtf(ss * (1.f / 768.f) + 1e-6f);
  float4 w0 = *(const float4*)(wn + lane * 4);
  float4 w1 = *(const float4*)(wn + 256 + lane * 4);
  float4 w2 = *(const float4*)(wn + 512 + lane * 4);
  unsigned short* xo = (unsigned short*)(xn + (size_t)wid * D);
  ushort4 u;
  u.x = f2bf_u(a.x*rs*w0.x); u.y = f2bf_u(a.y*rs*w0.y); u.z = f2bf_u(a.z*rs*w0.z); u.w = f2bf_u(a.w*rs*w0.w);
  *(ushort4*)(xo + lane * 4) = u;
  u.x = f2bf_u(b.x*rs*w1.x); u.y = f2bf_u(b.y*rs*w1.y); u.z = f2bf_u(b.z*rs*w1.z); u.w = f2bf_u(b.w*rs*w1.w);
  *(ushort4*)(xo + 256 + lane * 4) = u;
  u.x = f2bf_u(c.x*rs*w2.x); u.y = f2bf_u(c.y*rs*w2.y); u.z = f2bf_u(c.z*rs*w2.z); u.w = f2bf_u(c.w*rs*w2.w);
  *(ushort4*)(xo + 512 + lane * 4) = u;
}

// ---------------- bf16 MFMA GEMM, 128x128 tile, BK=32 dbuf prefetch ----
// LDS row = 64B = 4 chunks of 16B; (row r, slot s) holds GLOBAL chunk
// (r, s ^ (r&3)): linear gll16 dest, inverse-swizzled source, swizzled read.
// Bank audit: 16 lanes -> 8 banks x 2-way (free). 32KB LDS -> 4-5 blocks/CU.
template <int EPI>
__global__ __launch_bounds__(256)
void k_gemm(const __hip_bfloat16* __restrict__ A, const __hip_bfloat16* __restrict__ Bt,
            __hip_bfloat16* __restrict__ Ck, __hip_bfloat16* __restrict__ Cv,
            float* __restrict__ Cbg, float* __restrict__ C0, const float* __restrict__ Xadd) {
  __shared__ __align__(16) unsigned short As[2][128 * 32];
  __shared__ __align__(16) unsigned short Bs[2][128 * 32];
  const int K = 768, NKT = 24;
  int tid = threadIdx.x, lane = tid & 63, w = tid >> 6;
  int wr = w >> 1, wc = w & 1;
  int bx = blockIdx.x;                     // 256 m-blocks = 8 XCD chunks of 32
  bx = (bx & 7) * 32 + (bx >> 3);
  int m0 = bx * 128, n0 = blockIdx.y * 128;
  floatx4 zero = {0.f, 0.f, 0.f, 0.f};
  floatx4 acc[4][4];
  #pragma unroll
  for (int i = 0; i < 4; ++i)
    #pragma unroll
    for (int j = 0; j < 4; ++j) acc[i][j] = zero;

  auto stage = [&](int buf, int kt) {      // 4 VMEM instrs per wave
    #pragma unroll
    for (int it = 0; it < 2; ++it) {
      int L = it * 256 + tid;              // [0,512) chunks of 16B
      int r = L >> 2, s = L & 3, sg = s ^ (r & 3);
      gll16(A  + (size_t)(m0 + r) * K + kt * 32 + sg * 8, &As[buf][L * 8]);
      gll16(Bt + (size_t)(n0 + r) * K + kt * 32 + sg * 8, &Bs[buf][L * 8]);
    }
  };

  stage(0, 0);
  __syncthreads();
  int buf = 0;
  for (int kt = 0; kt < NKT; ++kt) {
    if (kt + 1 < NKT) stage(buf ^ 1, kt + 1);
    __builtin_amdgcn_s_setprio(1);
    {
      int c = lane >> 4;                   // chunk 0..3
      short8 af[4], bfr[4];
      #pragma unroll
      for (int i = 0; i < 4; ++i) {
        int ri = wr * 64 + i * 16 + (lane & 15);
        af[i] = *(const short8*)&As[buf][ri * 32 + ((c ^ (ri & 3)) << 3)];
      }
      #pragma unroll
      for (int j = 0; j < 4; ++j) {
        int rj = wc * 64 + j * 16 + (lane & 15);
        bfr[j] = *(const short8*)&Bs[buf][rj * 32 + ((c ^ (rj & 3)) << 3)];
      }
      #pragma unroll
      for (int i = 0; i < 4; ++i)
        #pragma unroll
        for (int j = 0; j < 4; ++j)
          acc[i][j] = __builtin_amdgcn_mfma_f32_16x16x32_bf16(af[i], bfr[j], acc[i][j], 0, 0, 0);
    }
    __builtin_amdgcn_s_setprio(0);
    __syncthreads();              // drains vmcnt(0): next buffer complete
    buf ^= 1;
  }

  if constexpr (EPI == 0) {
    if (n0 < 768) {
      #pragma unroll
      for (int i = 0; i < 4; ++i) {
        #pragma unroll
        for (int r = 0; r < 4; ++r) {
          float ss = 0.f;
          #pragma unroll
          for (int j = 0; j < 4; ++j) { float t = acc[i][j][r]; ss = fmaf(t, t, ss); }
          ss += __shfl_xor(ss, 1); ss += __shfl_xor(ss, 2);
          ss += __shfl_xor(ss, 4); ss += __shfl_xor(ss, 8);
          float sc = 1.f / fmaxf(sqrtf(ss), 1e-12f);
          int mm = m0 + wr * 64 + i * 16 + (lane >> 4) * 4 + r;
          #pragma unroll
          for (int j = 0; j < 4; ++j) {
            int n = n0 + wc * 64 + j * 16 + (lane & 15);
            Ck[(size_t)mm * 768 + n] = __float2bfloat16(acc[i][j][r] * sc);
          }
        }
      }
    } else if (n0 < 1536) {
      #pragma unroll
      for (int i = 0; i < 4; ++i)
        #pragma unroll
        for (int j = 0; j < 4; ++j) {
          int n = n0 + wc * 64 + j * 16 + (lane & 15) - 768;
          #pragma unroll
          for (int r = 0; r < 4; ++r) {
            int mm = m0 + wr * 64 + i * 16 + (lane >> 4) * 4 + r;
            Cv[(size_t)mm * 768 + n] = __float2bfloat16(acc[i][j][r]);
          }
        }
    } else {
      #pragma unroll
      for (int i = 0; i < 4; ++i)
        #pragma unroll
        for (int j = 0; j < 4; ++j) {
          int n = n0 + wc * 64 + j * 16 + (lane & 15) - 1536;
          if (n < 24) {                     // only 24 live beta/g cols
            #pragma unroll
            for (int r = 0; r < 4; ++r) {
              int mm = m0 + wr * 64 + i * 16 + (lane >> 4) * 4 + r;
              Cbg[(size_t)mm * 128 + n] = acc[i][j][r];
            }
          }
        }
    }
  } else {
    #pragma unroll
    for (int i = 0; i < 4; ++i)
      #pragma unroll
      for (int j = 0; j < 4; ++j) {
        int n = n0 + wc * 64 + j * 16 + (lane & 15);
        #pragma unroll
        for (int r = 0; r < 4; ++r) {
          int mm = m0 + wr * 64 + i * 16 + (lane >> 4) * 4 + r;
          size_t o = (size_t)mm * 768 + n;
          C0[o] = Xadd[o] + acc[i][j][r];
        }
      }
  }
}

// ---------------- fused sigmoid + gate prefix ----------------
__global__ void k_gates2(const float* __restrict__ bgraw, const float* __restrict__ bb,
                         const float* __restrict__ bgb, float* __restrict__ csbuf) {
  int wid  = blockIdx.x * 4 + (threadIdx.x >> 6);   // bh*NC + ck
  int lane = threadIdx.x & 63;
  int bh = wid >> 7, ck = wid & 127;
  int b = bh / 12, h = bh % 12;
  size_t row0 = (size_t)b * T_LEN + (size_t)ck * 64;
  const float* br = bgraw + (row0 + lane) * 128;
  float bet = 1.f / (1.f + __expf(-(br[h] + bb[h])));
  float g   = 1.f / (1.f + __expf(-(br[12 + h] + bgb[h])));
  float lg = __log2f(g);
  float ci = lg;
  #pragma unroll
  for (int d = 1; d < 64; d <<= 1) { float t = __shfl_up(ci, d); if (lane >= d) ci += t; }
  csbuf[(size_t)wid * CSTR + lane] = ci;
  csbuf[(size_t)wid * CSTR + 64 + lane] = ci - lg;
  csbuf[(size_t)wid * CSTR + 128 + lane] = bet;
}

// ---------------- pass 1: per-chunk WY factors (Uv, W) ----------------
__global__ __launch_bounds__(256)
void k_chunk1(const __hip_bfloat16* __restrict__ kb16, const __hip_bfloat16* __restrict__ vbuf,
              const float* __restrict__ csbuf,
              __hip_bfloat16* __restrict__ Uvt_g, __hip_bfloat16* __restrict__ W_g) {
  __shared__ __align__(16) char sm[6 * 8192 + 768];
  char* SA = sm;
  char* SB = sm + 8192;
  char* SC = sm + 2 * 8192;
  char* SD = sm + 3 * 8192;   // SD,SE contiguous (RHST spans both)
  char* SE = sm + 4 * 8192;
  char* SF = sm + 5 * 8192;
  float* cs   = (float*)(sm + 6 * 8192);
  float* cps  = (float*)(sm + 6 * 8192 + 256);
  float* bets = (float*)(sm + 6 * 8192 + 512);

  int blk = blockIdx.x, bh = blk >> 7, ck = blk & 127;
  int b = bh / 12, h = bh % 12;
  int tid = threadIdx.x, lane = tid & 63, wv = tid >> 6;
  size_t row0 = (size_t)b * T_LEN + (size_t)ck * 64;
  size_t wbase = (size_t)blk * 4096;

  if (tid < 64) {
    cs[tid]   = csbuf[(size_t)blk * CSTR + tid];
    cps[tid]  = csbuf[(size_t)blk * CSTR + 64 + tid];
    bets[tid] = csbuf[(size_t)blk * CSTR + 128 + tid];
  }
  int sr = tid >> 2, sc0 = (tid & 3) * 16;
  {
    const __hip_bfloat16* kp = kb16 + (row0 + sr) * 768 + h * 64 + sc0;
    short8 k0 = *(const short8*)kp;
    short8 k1 = *(const short8*)(kp + 8);
    *(short8*)(SA + swz16(sr, sc0 >> 3)) = k0;
    *(short8*)(SA + swz16(sr, (sc0 >> 3) + 1)) = k1;
  }
  short8 vreg0, vreg1;
  {
    const __hip_bfloat16* vp = vbuf + (row0 + sr) * 768 + h * 64 + sc0;
    vreg0 = *(const short8*)vp;
    vreg1 = *(const short8*)(vp + 8);
  }
  __syncthreads();

  floatx4 acc[4];
  auto zacc = [&] {
    #pragma unroll
    for (int t = 0; t < 4; ++t) acc[t] = (floatx4){0.f, 0.f, 0.f, 0.f};
  };
  auto forRC = [&](auto&& f) {
    #pragma unroll
    for (int t = 0; t < 4; ++t)
      #pragma unroll
      for (int r = 0; r < 4; ++r)
        f(wv * 16 + (lane >> 4) * 4 + r, t * 16 + (lane & 15), acc[t][r]);
  };

  // G = K K^T -> L(SB), Lt(SC), M1=I-L(SD)
  zacc(); mm16x64(SA, SA, wv, lane, acc);
  forRC([&](int i, int j, float v) {
    float Lv = 0.f;
    if (j < i) Lv = bets[i] * exp2f(cps[i] - cs[j]) * v;
    st_bf(SB, i, j, Lv);
    st_bf(SC, j, i, Lv);
    st_bf(SD, i, j, (i == j ? 1.f : 0.f) - Lv);
  });
  __syncthreads();

  auto power = [&](char* Ar, char* Bt, char* Or, char* Ot) {
    zacc(); mm16x64(Ar, Bt, wv, lane, acc);
    forRC([&](int i, int j, float v) { st_bf(Or, i, j, v); st_bf(Ot, j, i, v); });
    __syncthreads();
  };
  auto powerT = [&](char* Ar, char* Bt, char* Ot) {
    zacc(); mm16x64(Ar, Bt, wv, lane, acc);
    forRC([&](int i, int j, float v) { st_bf(Ot, j, i, v); });
    __syncthreads();
  };
  auto combine = [&](char* Mr, char* Pt, char* Out) {
    zacc(); mm16x64(Mr, Pt, wv, lane, acc);
    forRC([&](int i, int j, float v) { st_bf(Out, i, j, v + ld_bf(Mr, i, j)); });
    __syncthreads();
  };

  power(SB, SC, SE, SF);    // L^2
  combine(SD, SF, SB);      // M2
  power(SE, SF, SC, SD);    // L^4
  combine(SB, SD, SE);      // M3
  power(SC, SD, SF, SB);    // L^8
  combine(SE, SB, SC);      // M4
  power(SF, SB, SD, SE);    // L^16
  combine(SC, SE, SF);      // M5
  powerT(SD, SE, SB);       // L^32t
  combine(SF, SB, SC);      // T -> SC

  // RHST (128 x 64): rows c<64: beta_i*V[i][c]; rows 64+k: beta_i*gprev_i*K[i][k]
  {
    float be = bets[sr];
    #pragma unroll
    for (int q = 0; q < 8; ++q) {
      st_bf(SD, sc0 + q,     sr, be * bf2f(((unsigned short*)&vreg0)[q]));
      st_bf(SD, sc0 + 8 + q, sr, be * bf2f(((unsigned short*)&vreg1)[q]));
    }
    float scl = be * exp2f(cps[sr]);
    #pragma unroll
    for (int q = 0; q < 16; ++q) {
      float kv = ld_bf(SA, sr, sc0 + q);
      st_bf(SD, 64 + sc0 + q, sr, scl * kv);
    }
  }
  __syncthreads();

  // X = T * RHS -> Uvt to SF; W^T rows to HBM (Wt layout [k][j])
  {
    floatx4 xacc[8];
    #pragma unroll
    for (int t = 0; t < 8; ++t) xacc[t] = (floatx4){0.f, 0.f, 0.f, 0.f};
    #pragma unroll
    for (int ks = 0; ks < 2; ++ks) {
      short8 af = *(const short8*)(SC + swz16(wv * 16 + (lane & 15), ks * 4 + (lane >> 4)));
      #pragma unroll
      for (int t = 0; t < 8; ++t) {
        short8 bf = *(const short8*)(SD + swz16(t * 16 + (lane & 15), ks * 4 + (lane >> 4)));
        xacc[t] = __builtin_amdgcn_mfma_f32_16x16x32_bf16(af, bf, xacc[t], 0, 0, 0);
      }
    }
    #pragma unroll
    for (int t = 0; t < 8; ++t) {
      int c = t * 16 + (lane & 15);
      #pragma unroll
      for (int r = 0; r < 4; ++r) {
        int i = wv * 16 + (lane >> 4) * 4 + r;
        float v = xacc[t][r];
        if (c < 64) st_bf(SF, c, i, v);
        else        W_g[wbase + (size_t)(c - 64) * 64 + i] = __float2bfloat16(v);
      }
    }
  }
  __syncthreads();

  {
    int s2 = (tid & 3) * 2;
    short8 a0 = *(const short8*)(SF + swz16(sr, s2));
    short8 a1 = *(const short8*)(SF + swz16(sr, s2 + 1));
    *(short8*)(Uvt_g + wbase + (size_t)sr * 64 + s2 * 8) = a0;
    *(short8*)(Uvt_g + wbase + (size_t)sr * 64 + s2 * 8 + 8) = a1;
  }
}

// ---------------- scan A: per-group (8 chunks) map composition ----------------
__global__ __launch_bounds__(256)
void k_scanA(const __hip_bfloat16* __restrict__ kb16, const __hip_bfloat16* __restrict__ W_g,
             const __hip_bfloat16* __restrict__ Uvt_g, const float* __restrict__ csbuf,
             __hip_bfloat16* __restrict__ Ag_g, __hip_bfloat16* __restrict__ Bg_g) {
  __shared__ __align__(16) char sm[7 * 8192];
  char* SK  = sm;              // Ktil^T [k][t]
  char* SW  = sm + 8192;       // Wt [k][j]
  char* SU  = sm + 2 * 8192;   // Uvt [v][t]
  char* SAc = sm + 3 * 8192;   // Ac [ko][ki]
  char* SBc = sm + 4 * 8192;   // Bct [v][k]
  char* SAt = sm + 5 * 8192;   // Aacc^T [ki][ko]
  char* SBa = sm + 6 * 8192;   // Bacc [v][k]

  int blk = blockIdx.x, bh = blk >> 4, gg = blk & 15;
  int b = bh / 12, h = bh % 12;
  int tid = threadIdx.x, lane = tid & 63, wv = tid >> 6;
  int sr = tid >> 2, sc0 = (tid & 3) * 16, s2 = (tid & 3) * 2;
  int c0 = gg * 8;

  short8 z = {0, 0, 0, 0, 0, 0, 0, 0};
  *(short8*)(SAt + swz16(sr, s2)) = z;
  *(short8*)(SAt + swz16(sr, s2 + 1)) = z;
  *(short8*)(SBa + swz16(sr, s2)) = z;
  *(short8*)(SBa + swz16(sr, s2 + 1)) = z;
  __syncthreads();
  if (tid < 64) st_bf(SAt, tid, tid, 1.f);   // Aacc = I

  floatx4 acc[4];
  auto zacc = [&] {
    #pragma unroll
    for (int t = 0; t < 4; ++t) acc[t] = (floatx4){0.f, 0.f, 0.f, 0.f};
  };
  auto forRC = [&](auto&& f) {
    #pragma unroll
    for (int t = 0; t < 4; ++t)
      #pragma unroll
      for (int r = 0; r < 4; ++r)
        f(wv * 16 + (lane >> 4) * 4 + r, t * 16 + (lane & 15), acc[t][r]);
  };

  for (int cc = 0; cc < 8; ++cc) {
    int c = c0 + cc;
    size_t row0 = (size_t)b * T_LEN + (size_t)c * 64;
    size_t wb = ((size_t)bh * NC + c) * 4096;
    const float* csb = csbuf + (size_t)(bh * NC + c) * CSTR;
    float cs_sr = csb[sr], cs63 = csb[63];
    const __hip_bfloat16* kp = kb16 + (row0 + sr) * 768 + h * 64 + sc0;
    short8 k0 = *(const short8*)kp, k1 = *(const short8*)(kp + 8);
    const __hip_bfloat16* wp = W_g + wb + (size_t)sr * 64 + s2 * 8;
    short8 w0 = *(const short8*)wp, w1 = *(const short8*)(wp + 8);
    const __hip_bfloat16* up = Uvt_g + wb + (size_t)sr * 64 + s2 * 8;
    short8 u0 = *(const short8*)up, u1 = *(const short8*)(up + 8);
    // stage
    float scl = exp2f(cs63 - cs_sr);
    #pragma unroll
    for (int q = 0; q < 8; ++q) {
      st_bf(SK, sc0 + q,     sr, scl * bf2f(((unsigned short*)&k0)[q]));
      st_bf(SK, sc0 + 8 + q, sr, scl * bf2f(((unsigned short*)&k1)[q]));
    }
    *(short8*)(SW + swz16(sr, s2)) = w0;
    *(short8*)(SW + swz16(sr, s2 + 1)) = w1;
    *(short8*)(SU + swz16(sr, s2)) = u0;
    *(short8*)(SU + swz16(sr, s2 + 1)) = u1;
    __syncthreads();   // (a) staged; prev compose's SAc/SBc reads done
    float gC = exp2f(cs63);
    zacc(); mm16x64(SW, SK, wv, lane, acc);
    forRC([&](int i, int j, float v) { st_bf(SAc, j, i, ((i == j) ? gC : 0.f) - v); });
    zacc(); mm16x64(SU, SK, wv, lane, acc);
    forRC([&](int i, int j, float v) { st_bf(SBc, i, j, v); });
    __syncthreads();   // (b) Ac/Bc ready
    // compose in place (A-operand rows are wave-private)
    zacc(); mm16x64(SAt, SAc, wv, lane, acc);
    forRC([&](int i, int j, float v) { st_bf(SAt, i, j, v); });
    zacc(); mm16x64(SBa, SAc, wv, lane, acc);
    forRC([&](int i, int j, float v) { st_bf(SBa, i, j, v + ld_bf(SBc, i, j)); });
  }
  __syncthreads();
  // Ag rows [ko][ki] (scatter-transpose from SAt), Bg rows [v][k] (vector)
  size_t gb = (size_t)blk * 4096;
  #pragma unroll
  for (int q = 0; q < 16; ++q)
    Ag_g[gb + (size_t)(sc0 + q) * 64 + sr] = __float2bfloat16(ld_bf(SAt, sr, sc0 + q));
  {
    short8 b0 = *(const short8*)(SBa + swz16(sr, s2));
    short8 b1 = *(const short8*)(SBa + swz16(sr, s2 + 1));
    *(short8*)(Bg_g + gb + (size_t)sr * 64 + s2 * 8) = b0;
    *(short8*)(Bg_g + gb + (size_t)sr * 64 + s2 * 8 + 8) = b1;
  }
}

// ---------------- scan B: 16 serial group composes ----------------
__global__ __launch_bounds__(256)
void k_scanB(const __hip_bfloat16* __restrict__ Ag_g, const __hip_bfloat16* __restrict__ Bg_g,
             __hip_bfloat16* __restrict__ Sg_g, float* __restrict__ fstate) {
  __shared__ __align__(16) char sm[3 * 8192];
  char* SSt = sm;
  char* SAg = sm + 8192;
  char* SBg = sm + 2 * 8192;
  int bh = blockIdx.x;
  int tid = threadIdx.x, lane = tid & 63, wv = tid >> 6;
  int sr = tid >> 2, s2 = (tid & 3) * 2;

  short8 z = {0, 0, 0, 0, 0, 0, 0, 0};
  *(short8*)(SSt + swz16(sr, s2)) = z;
  *(short8*)(SSt + swz16(sr, s2 + 1)) = z;

  floatx4 acc[4];
  for (int g = 0; g < NG; ++g) {
    size_t gb = ((size_t)bh * NG + g) * 4096;
    const __hip_bfloat16* pa = Ag_g + gb + (size_t)sr * 64 + s2 * 8;
    short8 a0 = *(const short8*)pa, a1 = *(const short8*)(pa + 8);
    const __hip_bfloat16* pb = Bg_g + gb + (size_t)sr * 64 + s2 * 8;
    short8 b0 = *(const short8*)pb, b1 = *(const short8*)(pb + 8);
    __syncthreads();             // SSt stable; prev compose's SAg/SBg reads done
    {  // write group-start state
      short8 s0 = *(const short8*)(SSt + swz16(sr, s2));
      short8 s1 = *(const short8*)(SSt + swz16(sr, s2 + 1));
      *(short8*)(Sg_g + gb + (size_t)sr * 64 + s2 * 8) = s0;
      *(short8*)(Sg_g + gb + (size_t)sr * 64 + s2 * 8 + 8) = s1;
    }
    *(short8*)(SAg + swz16(sr, s2)) = a0;
    *(short8*)(SAg + swz16(sr, s2 + 1)) = a1;
    *(short8*)(SBg + swz16(sr, s2)) = b0;
    *(short8*)(SBg + swz16(sr, s2 + 1)) = b1;
    __syncthreads();
    #pragma unroll
    for (int t = 0; t < 4; ++t) acc[t] = (floatx4){0.f, 0.f, 0.f, 0.f};
    mm16x64(SSt, SAg, wv, lane, acc);
    #pragma unroll
    for (int t = 0; t < 4; ++t) {
      int j = t * 16 + (lane & 15);
      #pragma unroll
      for (int r = 0; r < 4; ++r) {
        int i = wv * 16 + (lane >> 4) * 4 + r;
        float val = acc[t][r] + ld_bf(SBg, i, j);
        st_bf(SSt, i, j, val);
        if (g == NG - 1) fstate[(size_t)bh * 4096 + (size_t)j * 64 + i] = val;
      }
    }
  }
}

// ---------------- fused scan C + outputs ----------------
__global__ __launch_bounds__(256)
void k_scfuse(const __hip_bfloat16* __restrict__ kb16, const __hip_bfloat16* __restrict__ W_g,
              const __hip_bfloat16* __restrict__ Uvt_g, const float* __restrict__ csbuf,
              const __hip_bfloat16* __restrict__ Sg_g, __hip_bfloat16* __restrict__ outs) {
  __shared__ __align__(16) char sm[7 * 8192];
  char* SSt = sm;              // state [v][k]
  char* SKr = sm + 8192;       // raw K [t][k]; phase5: out bounce [t][v]
  char* SKt = sm + 2 * 8192;   // Ktil^T [k][t]; phase3+: G [i][j]
  char* SW  = sm + 3 * 8192;   // Wt [k][j]; phase3+: W row-major [j][k]
  char* SU  = sm + 4 * 8192;   // Uvt [v][t] -> Ueff
  char* SAc = sm + 5 * 8192;
  char* SBc = sm + 6 * 8192;

  int blk = blockIdx.x, bh = blk >> 4, gg = blk & 15;
  int b = bh / 12, h = bh % 12;
  int tid = threadIdx.x, lane = tid & 63, wv = tid >> 6;
  int sr = tid >> 2, sc0 = (tid & 3) * 16, s2 = (tid & 3) * 2;
  int c0 = gg * 8;
  int iR0 = wv * 16 + (lane >> 4) * 4;

  {
    const __hip_bfloat16* sp = Sg_g + (size_t)blk * 4096 + (size_t)sr * 64 + s2 * 8;
    short8 s0 = *(const short8*)sp, s1 = *(const short8*)(sp + 8);
    *(short8*)(SSt + swz16(sr, s2)) = s0;
    *(short8*)(SSt + swz16(sr, s2 + 1)) = s1;
  }

  floatx4 acc[4], pAcc[4];
  auto zacc = [&] {
    #pragma unroll
    for (int t = 0; t < 4; ++t) acc[t] = (floatx4){0.f, 0.f, 0.f, 0.f};
  };
  auto forRC = [&](auto&& f) {
    #pragma unroll
    for (int t = 0; t < 4; ++t)
      #pragma unroll
      for (int r = 0; r < 4; ++r)
        f(iR0 + r, t * 16 + (lane & 15), acc[t][r]);
  };

  for (int cc = 0; cc < 8; ++cc) {
    int c = c0 + cc;
    size_t row0 = (size_t)b * T_LEN + (size_t)c * 64;
    size_t wb = ((size_t)bh * NC + c) * 4096;
    const float* csb = csbuf + (size_t)(bh * NC + c) * CSTR;
    float cs_sr = csb[sr], cs63 = csb[63];
    float csI[4], csJ[4];
    #pragma unroll
    for (int r = 0; r < 4; ++r) csI[r] = csb[iR0 + r];
    #pragma unroll
    for (int t = 0; t < 4; ++t) csJ[t] = csb[t * 16 + (lane & 15)];
    const __hip_bfloat16* kp = kb16 + (row0 + sr) * 768 + h * 64 + sc0;
    short8 k0 = *(const short8*)kp, k1 = *(const short8*)(kp + 8);
    const __hip_bfloat16* wp = W_g + wb + (size_t)sr * 64 + sc0;
    short8 w0 = *(const short8*)wp, w1 = *(const short8*)(wp + 8);
    const __hip_bfloat16* up = Uvt_g + wb + (size_t)sr * 64 + sc0;
    short8 u0 = *(const short8*)up, u1 = *(const short8*)(up + 8);
    __syncthreads();             // bar0: prev iter's tile reads done
    // stage
    *(short8*)(SKr + swz16(sr, sc0 >> 3)) = k0;
    *(short8*)(SKr + swz16(sr, (sc0 >> 3) + 1)) = k1;
    {
      float scl = exp2f(cs63 - cs_sr);
      #pragma unroll
      for (int q = 0; q < 8; ++q) {
        st_bf(SKt, sc0 + q,     sr, scl * bf2f(((unsigned short*)&k0)[q]));
        st_bf(SKt, sc0 + 8 + q, sr, scl * bf2f(((unsigned short*)&k1)[q]));
      }
    }
    *(short8*)(SW + swz16(sr, s2)) = w0;
    *(short8*)(SW + swz16(sr, s2 + 1)) = w1;
    *(short8*)(SU + swz16(sr, s2)) = u0;
    *(short8*)(SU + swz16(sr, s2 + 1)) = u1;
    __syncthreads();             // bar1
    // builds
    float gC = exp2f(cs63);
    zacc(); mm16x64(SW, SKt, wv, lane, acc);
    forRC([&](int i, int j, float v) { st_bf(SAc, j, i, ((i == j) ? gC : 0.f) - v); });
    zacc(); mm16x64(SU, SKt, wv, lane, acc);
    forRC([&](int i, int j, float v) { st_bf(SBc, i, j, v); });
    __syncthreads();             // bar2: builds done; SKt,SW free
    // W row-major into SW slot; scaled-G into SKt slot
    #pragma unroll
    for (int q = 0; q < 8; ++q) {
      st_bf(SW, sc0 + q,     sr, bf2f(((unsigned short*)&w0)[q]));
      st_bf(SW, sc0 + 8 + q, sr, bf2f(((unsigned short*)&w1)[q]));
    }
    zacc(); mm16x64(SKr, SKr, wv, lane, acc);
    #pragma unroll
    for (int t = 0; t < 4; ++t) {
      int j = t * 16 + (lane & 15);
      #pragma unroll
      for (int r = 0; r < 4; ++r) {
        int i = iR0 + r;
        float gs = (j <= i) ? exp2f(csI[r] - csJ[t]) * acc[t][r] : 0.f;
        st_bf(SKt, i, j, gs);
      }
    }
    __syncthreads();             // bar3
    // P = K·S0^T (regs); Ueff = Uv - S0 x W (SU in place, own band)
    #pragma unroll
    for (int t = 0; t < 4; ++t) pAcc[t] = (floatx4){0.f, 0.f, 0.f, 0.f};
    mm16x64(SKr, SSt, wv, lane, pAcc);
    zacc(); mm16x64(SSt, SW, wv, lane, acc);
    forRC([&](int i, int j, float v) { st_bf(SU, i, j, ld_bf(SU, i, j) - v); });
    __syncthreads();             // bar4
    // O2 = G·Ueff; out -> SKr bounce; compose S' = S·Ac^T + Bc (in place)
    zacc(); mm16x64(SKt, SU, wv, lane, acc);
    #pragma unroll
    for (int t = 0; t < 4; ++t) {
      int vc = t * 16 + (lane & 15);
      #pragma unroll
      for (int r = 0; r < 4; ++r) {
        int i = iR0 + r;
        float o = exp2f(csI[r]) * pAcc[t][r] + acc[t][r];
        st_bf(SKr, i, vc, o);
      }
    }
    zacc(); mm16x64(SSt, SAc, wv, lane, acc);
    forRC([&](int i, int j, float v) { st_bf(SSt, i, j, v + ld_bf(SBc, i, j)); });
    __syncthreads();             // bar5
    // coalesced out write from bounce
    {
      short8 a0 = *(const short8*)(SKr + swz16(sr, s2));
      short8 a1 = *(const short8*)(SKr + swz16(sr, s2 + 1));
      __hip_bfloat16* op = outs + (row0 + sr) * 768 + h * 64 + s2 * 8;
      *(short8*)op = a0;
      *(short8*)(op + 8) = a1;
    }
  }
}

// ---------------- host glue ----------------
extern "C" void kernel_launch(void* const* d_in, const int* in_sizes, int n_in,
                              void* d_out, int out_size, void* d_ws, size_t ws_size,
                              hipStream_t stream) {
  (void)in_sizes; (void)n_in; (void)out_size; (void)ws_size;
  const float* x   = (const float*)d_in[0];
  const float* wn  = (const float*)d_in[1];
  const float* Wk  = (const float*)d_in[2];
  const float* Wv  = (const float*)d_in[3];
  const float* Wo  = (const float*)d_in[4];
  const float* Wb  = (const float*)d_in[5];
  const float* bb  = (const float*)d_in[6];
  const float* Wg  = (const float*)d_in[7];
  const float* bgb = (const float*)d_in[8];
  float* out = (float*)d_out;

  char* ws = (char*)d_ws;
  size_t off = 0;
  const size_t TILE = (size_t)NWG1 * 4096 * 2;           // 50.3 MB
  const size_t GTILE = (size_t)NGRP * 4096 * 2;          // 6.3 MB
  // slot1: xn (dead after gemm<0>) ∪ Uvt_g (chunk1 -> scanA/scfuse)
  __hip_bfloat16* xn   = (__hip_bfloat16*)(ws + off);
  __hip_bfloat16* Uvt  = (__hip_bfloat16*)(ws + off); off += TILE;
  __hip_bfloat16* WT   = (__hip_bfloat16*)(ws + off); off += (size_t)NKV * D * 2;
  __hip_bfloat16* WoT  = (__hip_bfloat16*)(ws + off); off += (size_t)D * D * 2;
  __hip_bfloat16* kb16 = (__hip_bfloat16*)(ws + off); off += (size_t)ROWS * D * 2;
  // slot3: vbuf (dead after chunk1) ∪ outs (scfuse -> gemm<1>)
  __hip_bfloat16* vbuf = (__hip_bfloat16*)(ws + off);
  __hip_bfloat16* outsb= (__hip_bfloat16*)(ws + off); off += TILE;
  // slot4: bgraw (dead after gates2) ∪ [Ag|Bg|Sg|W_g]
  float* bgraw         = (float*)(ws + off);
  __hip_bfloat16* Ag_g = (__hip_bfloat16*)(ws + off);
  __hip_bfloat16* Bg_g = Ag_g + (size_t)NGRP * 4096;
  __hip_bfloat16* Sg_g = Bg_g + (size_t)NGRP * 4096;
  __hip_bfloat16* W_g  = Sg_g + (size_t)NGRP * 4096;
  off += 3 * GTILE + TILE;                               // 69.2 MB slot
  float* csbuf         = (float*)(ws + off);          off += (size_t)NWG1 * CSTR * 4;
  // total ~229 MiB

  k_prep_wt<<<(NKV * D + 255) / 256, 256, 0, stream>>>(Wk, Wv, Wb, Wg, WT);
  k_prep_wo<<<(D * D) / 256, 256, 0, stream>>>(Wo, WoT);
  k_rmsnorm<<<ROWS / 4, 256, 0, stream>>>(x, wn, xn);
  k_gemm<0><<<dim3(ROWS / 128, NKV / 128), 256, 0, stream>>>(xn, WT, kb16, vbuf, bgraw, nullptr, nullptr);
  k_gates2<<<NWG1 / 4, 256, 0, stream>>>(bgraw, bb, bgb, csbuf);
  k_chunk1<<<NWG1, 256, 0, stream>>>(kb16, vbuf, csbuf, Uvt, W_g);
  k_scanA<<<NGRP, 256, 0, stream>>>(kb16, W_g, Uvt, csbuf, Ag_g, Bg_g);
  k_scanB<<<NBH, 256, 0, stream>>>(Ag_g, Bg_g, Sg_g, out + (size_t)ROWS * D);
  k_scfuse<<<NGRP, 256, 0, stream>>>(kb16, W_g, Uvt, csbuf, Sg_g, outsb);
  k_gemm<1><<<dim3(ROWS / 128, D / 128), 256, 0, stream>>>(outsb, WoT, nullptr, nullptr, nullptr, out, x);
}

// Round 10
// 551.128 us; speedup vs baseline: 1.1276x; 1.0043x over previous
//
#include <hip/hip_runtime.h>
#include <hip/hip_bf16.h>

// GatedDeltaNet B=4 T=8192 D=768 H=12 K=V=64 — chunked WY + two-level scan.
// Round 10: BK=32 dbuf GEMM with CORRECTED swizzle sg = s ^ ((r>>1)&3):
// quarter-wave (16-lane) covers all 8 (parity,chunk) bank positions 2-way
// (free, per m136 + round-7 zero-conflict evidence). Scan side unchanged.

typedef __attribute__((ext_vector_type(8))) short short8;
typedef __attribute__((ext_vector_type(4))) float floatx4;

#define DEVFN static __device__ __forceinline__

typedef const __attribute__((address_space(1))) unsigned int* as1_u32p;
typedef __attribute__((address_space(3))) unsigned int* as3_u32p;

DEVFN void gll16(const void* g, void* l) {
  __builtin_amdgcn_global_load_lds((as1_u32p)g, (as3_u32p)l, 16, 0, 0);
}

DEVFN unsigned short f2bf_u(float f) {
  __hip_bfloat16 h = __float2bfloat16(f);
  return __builtin_bit_cast(unsigned short, h);
}
DEVFN float bf2f(unsigned short u) {
  return __bfloat162float(__builtin_bit_cast(__hip_bfloat16, u));
}

static constexpr int T_LEN = 8192;
static constexpr int ROWS  = 4 * 8192;   // 32768
static constexpr int D     = 768;
static constexpr int NKV   = 1664;
static constexpr int NC    = 128;        // chunks per sequence (C=64)
static constexpr int NBH   = 48;         // B*H
static constexpr int NWG1  = NBH * NC;   // 6144
static constexpr int NG    = 16;         // groups per bh (8 chunks each)
static constexpr int NGRP  = NBH * NG;   // 768
static constexpr int CSTR  = 192;        // csbuf: [0:64) incl, [64:128) excl, [128:192) beta

// ---- swizzled 64-col bf16 LDS tile helpers (row stride 128B, slot-XOR) ----
DEVFN int swz16(int row, int slot) {
  return (row << 7) + (((slot ^ (row & 7)) & 7) << 4);
}
DEVFN int swzE(int row, int col) {
  return (row << 7) + ((((col >> 3) ^ (row & 7)) & 7) << 4) + ((col & 7) << 1);
}
DEVFN void st_bf(char* base, int row, int col, float v) {
  *(unsigned short*)(base + swzE(row, col)) = f2bf_u(v);
}
DEVFN float ld_bf(const char* base, int row, int col) {
  return bf2f(*(const unsigned short*)(base + swzE(row, col)));
}
// D[16-band x 64] += A[band]·B^T over 64-col tiles (both swizzled)
DEVFN void mm16x64(const char* aB, const char* bB, int wv, int lane, floatx4 acc[4]) {
  #pragma unroll
  for (int ks = 0; ks < 2; ++ks) {
    short8 af = *(const short8*)(aB + swz16(wv * 16 + (lane & 15), ks * 4 + (lane >> 4)));
    #pragma unroll
    for (int t = 0; t < 4; ++t) {
      short8 bf = *(const short8*)(bB + swz16(t * 16 + (lane & 15), ks * 4 + (lane >> 4)));
      acc[t] = __builtin_amdgcn_mfma_f32_16x16x32_bf16(af, bf, acc[t], 0, 0, 0);
    }
  }
}

// ---------------- weight prep ----------------
__global__ void k_prep_wt(const float* __restrict__ Wk, const float* __restrict__ Wv,
                          const float* __restrict__ Wb, const float* __restrict__ Wg,
                          __hip_bfloat16* __restrict__ WT) {
  int idx = blockIdx.x * 256 + threadIdx.x;
  if (idx >= NKV * D) return;
  int n = idx / D, k = idx % D;
  float v;
  if (n < 768)       v = Wk[k * 768 + n];
  else if (n < 1536) v = Wv[k * 768 + (n - 768)];
  else if (n < 1548) v = Wb[k * 12 + (n - 1536)];
  else if (n < 1560) v = Wg[k * 12 + (n - 1548)];
  else               v = 0.f;
  WT[idx] = __float2bfloat16(v);
}

__global__ void k_prep_wo(const float* __restrict__ Wo, __hip_bfloat16* __restrict__ WoT) {
  int idx = blockIdx.x * 256 + threadIdx.x;
  int n = idx / D, k = idx % D;
  WoT[idx] = __float2bfloat16(Wo[k * 768 + n]);
}

// ---------------- RMSNorm ----------------
__global__ void k_rmsnorm(const float* __restrict__ x, const float* __restrict__ wn,
                          __hip_bfloat16* __restrict__ xn) {
  int wid  = (blockIdx.x << 2) + (threadIdx.x >> 6);
  int lane = threadIdx.x & 63;
  const float* xr = x + (size_t)wid * D;
  float4 a = *(const float4*)(xr + lane * 4);
  float4 b = *(const float4*)(xr + 256 + lane * 4);
  float4 c = *(const float4*)(xr + 512 + lane * 4);
  float ss = a.x*a.x + a.y*a.y + a.z*a.z + a.w*a.w
           + b.x*b.x + b.y*b.y + b.z*b.z + b.w*b.w
           + c.x*c.x + c.y*c.y + c.z*c.z + c.w*c.w;
  #pragma unroll
  for (int m = 1; m < 64; m <<= 1) ss += __shfl_xor(ss, m);
  float rs = rsqrtf(ss * (1.f / 768.f) + 1e-6f);
  float4 w0 = *(const float4*)(wn + lane * 4);
  float4 w1 = *(const float4*)(wn + 256 + lane * 4);
  float4 w2 = *(const float4*)(wn + 512 + lane * 4);
  unsigned short* xo = (unsigned short*)(xn + (size_t)wid * D);
  ushort4 u;
  u.x = f2bf_u(a.x*rs*w0.x); u.y = f2bf_u(a.y*rs*w0.y); u.z = f2bf_u(a.z*rs*w0.z); u.w = f2bf_u(a.w*rs*w0.w);
  *(ushort4*)(xo + lane * 4) = u;
  u.x = f2bf_u(b.x*rs*w1.x); u.y = f2bf_u(b.y*rs*w1.y); u.z = f2bf_u(b.z*rs*w1.z); u.w = f2bf_u(b.w*rs*w1.w);
  *(ushort4*)(xo + 256 + lane * 4) = u;
  u.x = f2bf_u(c.x*rs*w2.x); u.y = f2bf_u(c.y*rs*w2.y); u.z = f2bf_u(c.z*rs*w2.z); u.w = f2bf_u(c.w*rs*w2.w);
  *(ushort4*)(xo + 512 + lane * 4) = u;
}

// ---------------- bf16 MFMA GEMM, 128x128 tile, BK=32 dbuf prefetch ----
// LDS row = 64B = 4 chunks of 16B; (row r, slot s) holds GLOBAL chunk
// (r, s ^ ((r>>1)&3)). Quarter-wave: parity(r) x chunk covers 8 bank
// positions 2-way -> conflict-free. 32KB LDS -> 4-5 blocks/CU.
template <int EPI>
__global__ __launch_bounds__(256)
void k_gemm(const __hip_bfloat16* __restrict__ A, const __hip_bfloat16* __restrict__ Bt,
            __hip_bfloat16* __restrict__ Ck, __hip_bfloat16* __restrict__ Cv,
            float* __restrict__ Cbg, float* __restrict__ C0, const float* __restrict__ Xadd) {
  __shared__ __align__(16) unsigned short As[2][128 * 32];
  __shared__ __align__(16) unsigned short Bs[2][128 * 32];
  const int K = 768, NKT = 24;
  int tid = threadIdx.x, lane = tid & 63, w = tid >> 6;
  int wr = w >> 1, wc = w & 1;
  int bx = blockIdx.x;                     // 256 m-blocks = 8 XCD chunks of 32
  bx = (bx & 7) * 32 + (bx >> 3);
  int m0 = bx * 128, n0 = blockIdx.y * 128;
  floatx4 zero = {0.f, 0.f, 0.f, 0.f};
  floatx4 acc[4][4];
  #pragma unroll
  for (int i = 0; i < 4; ++i)
    #pragma unroll
    for (int j = 0; j < 4; ++j) acc[i][j] = zero;

  auto stage = [&](int buf, int kt) {      // 4 VMEM instrs per wave
    #pragma unroll
    for (int it = 0; it < 2; ++it) {
      int L = it * 256 + tid;              // [0,512) chunks of 16B
      int r = L >> 2, s = L & 3, sg = s ^ ((r >> 1) & 3);
      gll16(A  + (size_t)(m0 + r) * K + kt * 32 + sg * 8, &As[buf][L * 8]);
      gll16(Bt + (size_t)(n0 + r) * K + kt * 32 + sg * 8, &Bs[buf][L * 8]);
    }
  };

  stage(0, 0);
  __syncthreads();
  int buf = 0;
  for (int kt = 0; kt < NKT; ++kt) {
    if (kt + 1 < NKT) stage(buf ^ 1, kt + 1);
    __builtin_amdgcn_s_setprio(1);
    {
      int c = lane >> 4;                   // chunk 0..3
      short8 af[4], bfr[4];
      #pragma unroll
      for (int i = 0; i < 4; ++i) {
        int ri = wr * 64 + i * 16 + (lane & 15);
        af[i] = *(const short8*)&As[buf][ri * 32 + ((c ^ ((ri >> 1) & 3)) << 3)];
      }
      #pragma unroll
      for (int j = 0; j < 4; ++j) {
        int rj = wc * 64 + j * 16 + (lane & 15);
        bfr[j] = *(const short8*)&Bs[buf][rj * 32 + ((c ^ ((rj >> 1) & 3)) << 3)];
      }
      #pragma unroll
      for (int i = 0; i < 4; ++i)
        #pragma unroll
        for (int j = 0; j < 4; ++j)
          acc[i][j] = __builtin_amdgcn_mfma_f32_16x16x32_bf16(af[i], bfr[j], acc[i][j], 0, 0, 0);
    }
    __builtin_amdgcn_s_setprio(0);
    __syncthreads();              // drains vmcnt(0): next buffer complete
    buf ^= 1;
  }

  if constexpr (EPI == 0) {
    if (n0 < 768) {
      #pragma unroll
      for (int i = 0; i < 4; ++i) {
        #pragma unroll
        for (int r = 0; r < 4; ++r) {
          float ss = 0.f;
          #pragma unroll
          for (int j = 0; j < 4; ++j) { float t = acc[i][j][r]; ss = fmaf(t, t, ss); }
          ss += __shfl_xor(ss, 1); ss += __shfl_xor(ss, 2);
          ss += __shfl_xor(ss, 4); ss += __shfl_xor(ss, 8);
          float sc = 1.f / fmaxf(sqrtf(ss), 1e-12f);
          int mm = m0 + wr * 64 + i * 16 + (lane >> 4) * 4 + r;
          #pragma unroll
          for (int j = 0; j < 4; ++j) {
            int n = n0 + wc * 64 + j * 16 + (lane & 15);
            Ck[(size_t)mm * 768 + n] = __float2bfloat16(acc[i][j][r] * sc);
          }
        }
      }
    } else if (n0 < 1536) {
      #pragma unroll
      for (int i = 0; i < 4; ++i)
        #pragma unroll
        for (int j = 0; j < 4; ++j) {
          int n = n0 + wc * 64 + j * 16 + (lane & 15) - 768;
          #pragma unroll
          for (int r = 0; r < 4; ++r) {
            int mm = m0 + wr * 64 + i * 16 + (lane >> 4) * 4 + r;
            Cv[(size_t)mm * 768 + n] = __float2bfloat16(acc[i][j][r]);
          }
        }
    } else {
      #pragma unroll
      for (int i = 0; i < 4; ++i)
        #pragma unroll
        for (int j = 0; j < 4; ++j) {
          int n = n0 + wc * 64 + j * 16 + (lane & 15) - 1536;
          if (n < 24) {                     // only 24 live beta/g cols
            #pragma unroll
            for (int r = 0; r < 4; ++r) {
              int mm = m0 + wr * 64 + i * 16 + (lane >> 4) * 4 + r;
              Cbg[(size_t)mm * 128 + n] = acc[i][j][r];
            }
          }
        }
    }
  } else {
    #pragma unroll
    for (int i = 0; i < 4; ++i)
      #pragma unroll
      for (int j = 0; j < 4; ++j) {
        int n = n0 + wc * 64 + j * 16 + (lane & 15);
        #pragma unroll
        for (int r = 0; r < 4; ++r) {
          int mm = m0 + wr * 64 + i * 16 + (lane >> 4) * 4 + r;
          size_t o = (size_t)mm * 768 + n;
          C0[o] = Xadd[o] + acc[i][j][r];
        }
      }
  }
}

// ---------------- fused sigmoid + gate prefix ----------------
__global__ void k_gates2(const float* __restrict__ bgraw, const float* __restrict__ bb,
                         const float* __restrict__ bgb, float* __restrict__ csbuf) {
  int wid  = blockIdx.x * 4 + (threadIdx.x >> 6);   // bh*NC + ck
  int lane = threadIdx.x & 63;
  int bh = wid >> 7, ck = wid & 127;
  int b = bh / 12, h = bh % 12;
  size_t row0 = (size_t)b * T_LEN + (size_t)ck * 64;
  const float* br = bgraw + (row0 + lane) * 128;
  float bet = 1.f / (1.f + __expf(-(br[h] + bb[h])));
  float g   = 1.f / (1.f + __expf(-(br[12 + h] + bgb[h])));
  float lg = __log2f(g);
  float ci = lg;
  #pragma unroll
  for (int d = 1; d < 64; d <<= 1) { float t = __shfl_up(ci, d); if (lane >= d) ci += t; }
  csbuf[(size_t)wid * CSTR + lane] = ci;
  csbuf[(size_t)wid * CSTR + 64 + lane] = ci - lg;
  csbuf[(size_t)wid * CSTR + 128 + lane] = bet;
}

// ---------------- pass 1: per-chunk WY factors (Uv, W) ----------------
__global__ __launch_bounds__(256)
void k_chunk1(const __hip_bfloat16* __restrict__ kb16, const __hip_bfloat16* __restrict__ vbuf,
              const float* __restrict__ csbuf,
              __hip_bfloat16* __restrict__ Uvt_g, __hip_bfloat16* __restrict__ W_g) {
  __shared__ __align__(16) char sm[6 * 8192 + 768];
  char* SA = sm;
  char* SB = sm + 8192;
  char* SC = sm + 2 * 8192;
  char* SD = sm + 3 * 8192;   // SD,SE contiguous (RHST spans both)
  char* SE = sm + 4 * 8192;
  char* SF = sm + 5 * 8192;
  float* cs   = (float*)(sm + 6 * 8192);
  float* cps  = (float*)(sm + 6 * 8192 + 256);
  float* bets = (float*)(sm + 6 * 8192 + 512);

  int blk = blockIdx.x, bh = blk >> 7, ck = blk & 127;
  int b = bh / 12, h = bh % 12;
  int tid = threadIdx.x, lane = tid & 63, wv = tid >> 6;
  size_t row0 = (size_t)b * T_LEN + (size_t)ck * 64;
  size_t wbase = (size_t)blk * 4096;

  if (tid < 64) {
    cs[tid]   = csbuf[(size_t)blk * CSTR + tid];
    cps[tid]  = csbuf[(size_t)blk * CSTR + 64 + tid];
    bets[tid] = csbuf[(size_t)blk * CSTR + 128 + tid];
  }
  int sr = tid >> 2, sc0 = (tid & 3) * 16;
  {
    const __hip_bfloat16* kp = kb16 + (row0 + sr) * 768 + h * 64 + sc0;
    short8 k0 = *(const short8*)kp;
    short8 k1 = *(const short8*)(kp + 8);
    *(short8*)(SA + swz16(sr, sc0 >> 3)) = k0;
    *(short8*)(SA + swz16(sr, (sc0 >> 3) + 1)) = k1;
  }
  short8 vreg0, vreg1;
  {
    const __hip_bfloat16* vp = vbuf + (row0 + sr) * 768 + h * 64 + sc0;
    vreg0 = *(const short8*)vp;
    vreg1 = *(const short8*)(vp + 8);
  }
  __syncthreads();

  floatx4 acc[4];
  auto zacc = [&] {
    #pragma unroll
    for (int t = 0; t < 4; ++t) acc[t] = (floatx4){0.f, 0.f, 0.f, 0.f};
  };
  auto forRC = [&](auto&& f) {
    #pragma unroll
    for (int t = 0; t < 4; ++t)
      #pragma unroll
      for (int r = 0; r < 4; ++r)
        f(wv * 16 + (lane >> 4) * 4 + r, t * 16 + (lane & 15), acc[t][r]);
  };

  // G = K K^T -> L(SB), Lt(SC), M1=I-L(SD)
  zacc(); mm16x64(SA, SA, wv, lane, acc);
  forRC([&](int i, int j, float v) {
    float Lv = 0.f;
    if (j < i) Lv = bets[i] * exp2f(cps[i] - cs[j]) * v;
    st_bf(SB, i, j, Lv);
    st_bf(SC, j, i, Lv);
    st_bf(SD, i, j, (i == j ? 1.f : 0.f) - Lv);
  });
  __syncthreads();

  auto power = [&](char* Ar, char* Bt, char* Or, char* Ot) {
    zacc(); mm16x64(Ar, Bt, wv, lane, acc);
    forRC([&](int i, int j, float v) { st_bf(Or, i, j, v); st_bf(Ot, j, i, v); });
    __syncthreads();
  };
  auto powerT = [&](char* Ar, char* Bt, char* Ot) {
    zacc(); mm16x64(Ar, Bt, wv, lane, acc);
    forRC([&](int i, int j, float v) { st_bf(Ot, j, i, v); });
    __syncthreads();
  };
  auto combine = [&](char* Mr, char* Pt, char* Out) {
    zacc(); mm16x64(Mr, Pt, wv, lane, acc);
    forRC([&](int i, int j, float v) { st_bf(Out, i, j, v + ld_bf(Mr, i, j)); });
    __syncthreads();
  };

  power(SB, SC, SE, SF);    // L^2
  combine(SD, SF, SB);      // M2
  power(SE, SF, SC, SD);    // L^4
  combine(SB, SD, SE);      // M3
  power(SC, SD, SF, SB);    // L^8
  combine(SE, SB, SC);      // M4
  power(SF, SB, SD, SE);    // L^16
  combine(SC, SE, SF);      // M5
  powerT(SD, SE, SB);       // L^32t
  combine(SF, SB, SC);      // T -> SC

  // RHST (128 x 64): rows c<64: beta_i*V[i][c]; rows 64+k: beta_i*gprev_i*K[i][k]
  {
    float be = bets[sr];
    #pragma unroll
    for (int q = 0; q < 8; ++q) {
      st_bf(SD, sc0 + q,     sr, be * bf2f(((unsigned short*)&vreg0)[q]));
      st_bf(SD, sc0 + 8 + q, sr, be * bf2f(((unsigned short*)&vreg1)[q]));
    }
    float scl = be * exp2f(cps[sr]);
    #pragma unroll
    for (int q = 0; q < 16; ++q) {
      float kv = ld_bf(SA, sr, sc0 + q);
      st_bf(SD, 64 + sc0 + q, sr, scl * kv);
    }
  }
  __syncthreads();

  // X = T * RHS -> Uvt to SF; W^T rows to HBM (Wt layout [k][j])
  {
    floatx4 xacc[8];
    #pragma unroll
    for (int t = 0; t < 8; ++t) xacc[t] = (floatx4){0.f, 0.f, 0.f, 0.f};
    #pragma unroll
    for (int ks = 0; ks < 2; ++ks) {
      short8 af = *(const short8*)(SC + swz16(wv * 16 + (lane & 15), ks * 4 + (lane >> 4)));
      #pragma unroll
      for (int t = 0; t < 8; ++t) {
        short8 bf = *(const short8*)(SD + swz16(t * 16 + (lane & 15), ks * 4 + (lane >> 4)));
        xacc[t] = __builtin_amdgcn_mfma_f32_16x16x32_bf16(af, bf, xacc[t], 0, 0, 0);
      }
    }
    #pragma unroll
    for (int t = 0; t < 8; ++t) {
      int c = t * 16 + (lane & 15);
      #pragma unroll
      for (int r = 0; r < 4; ++r) {
        int i = wv * 16 + (lane >> 4) * 4 + r;
        float v = xacc[t][r];
        if (c < 64) st_bf(SF, c, i, v);
        else        W_g[wbase + (size_t)(c - 64) * 64 + i] = __float2bfloat16(v);
      }
    }
  }
  __syncthreads();

  {
    int s2 = (tid & 3) * 2;
    short8 a0 = *(const short8*)(SF + swz16(sr, s2));
    short8 a1 = *(const short8*)(SF + swz16(sr, s2 + 1));
    *(short8*)(Uvt_g + wbase + (size_t)sr * 64 + s2 * 8) = a0;
    *(short8*)(Uvt_g + wbase + (size_t)sr * 64 + s2 * 8 + 8) = a1;
  }
}

// ---------------- scan A: per-group (8 chunks) map composition ----------------
__global__ __launch_bounds__(256)
void k_scanA(const __hip_bfloat16* __restrict__ kb16, const __hip_bfloat16* __restrict__ W_g,
             const __hip_bfloat16* __restrict__ Uvt_g, const float* __restrict__ csbuf,
             __hip_bfloat16* __restrict__ Ag_g, __hip_bfloat16* __restrict__ Bg_g) {
  __shared__ __align__(16) char sm[7 * 8192];
  char* SK  = sm;              // Ktil^T [k][t]
  char* SW  = sm + 8192;       // Wt [k][j]
  char* SU  = sm + 2 * 8192;   // Uvt [v][t]
  char* SAc = sm + 3 * 8192;   // Ac [ko][ki]
  char* SBc = sm + 4 * 8192;   // Bct [v][k]
  char* SAt = sm + 5 * 8192;   // Aacc^T [ki][ko]
  char* SBa = sm + 6 * 8192;   // Bacc [v][k]

  int blk = blockIdx.x, bh = blk >> 4, gg = blk & 15;
  int b = bh / 12, h = bh % 12;
  int tid = threadIdx.x, lane = tid & 63, wv = tid >> 6;
  int sr = tid >> 2, sc0 = (tid & 3) * 16, s2 = (tid & 3) * 2;
  int c0 = gg * 8;

  short8 z = {0, 0, 0, 0, 0, 0, 0, 0};
  *(short8*)(SAt + swz16(sr, s2)) = z;
  *(short8*)(SAt + swz16(sr, s2 + 1)) = z;
  *(short8*)(SBa + swz16(sr, s2)) = z;
  *(short8*)(SBa + swz16(sr, s2 + 1)) = z;
  __syncthreads();
  if (tid < 64) st_bf(SAt, tid, tid, 1.f);   // Aacc = I

  floatx4 acc[4];
  auto zacc = [&] {
    #pragma unroll
    for (int t = 0; t < 4; ++t) acc[t] = (floatx4){0.f, 0.f, 0.f, 0.f};
  };
  auto forRC = [&](auto&& f) {
    #pragma unroll
    for (int t = 0; t < 4; ++t)
      #pragma unroll
      for (int r = 0; r < 4; ++r)
        f(wv * 16 + (lane >> 4) * 4 + r, t * 16 + (lane & 15), acc[t][r]);
  };

  for (int cc = 0; cc < 8; ++cc) {
    int c = c0 + cc;
    size_t row0 = (size_t)b * T_LEN + (size_t)c * 64;
    size_t wb = ((size_t)bh * NC + c) * 4096;
    const float* csb = csbuf + (size_t)(bh * NC + c) * CSTR;
    float cs_sr = csb[sr], cs63 = csb[63];
    const __hip_bfloat16* kp = kb16 + (row0 + sr) * 768 + h * 64 + sc0;
    short8 k0 = *(const short8*)kp, k1 = *(const short8*)(kp + 8);
    const __hip_bfloat16* wp = W_g + wb + (size_t)sr * 64 + s2 * 8;
    short8 w0 = *(const short8*)wp, w1 = *(const short8*)(wp + 8);
    const __hip_bfloat16* up = Uvt_g + wb + (size_t)sr * 64 + s2 * 8;
    short8 u0 = *(const short8*)up, u1 = *(const short8*)(up + 8);
    // stage
    float scl = exp2f(cs63 - cs_sr);
    #pragma unroll
    for (int q = 0; q < 8; ++q) {
      st_bf(SK, sc0 + q,     sr, scl * bf2f(((unsigned short*)&k0)[q]));
      st_bf(SK, sc0 + 8 + q, sr, scl * bf2f(((unsigned short*)&k1)[q]));
    }
    *(short8*)(SW + swz16(sr, s2)) = w0;
    *(short8*)(SW + swz16(sr, s2 + 1)) = w1;
    *(short8*)(SU + swz16(sr, s2)) = u0;
    *(short8*)(SU + swz16(sr, s2 + 1)) = u1;
    __syncthreads();   // (a) staged; prev compose's SAc/SBc reads done
    float gC = exp2f(cs63);
    zacc(); mm16x64(SW, SK, wv, lane, acc);
    forRC([&](int i, int j, float v) { st_bf(SAc, j, i, ((i == j) ? gC : 0.f) - v); });
    zacc(); mm16x64(SU, SK, wv, lane, acc);
    forRC([&](int i, int j, float v) { st_bf(SBc, i, j, v); });
    __syncthreads();   // (b) Ac/Bc ready
    // compose in place (A-operand rows are wave-private)
    zacc(); mm16x64(SAt, SAc, wv, lane, acc);
    forRC([&](int i, int j, float v) { st_bf(SAt, i, j, v); });
    zacc(); mm16x64(SBa, SAc, wv, lane, acc);
    forRC([&](int i, int j, float v) { st_bf(SBa, i, j, v + ld_bf(SBc, i, j)); });
  }
  __syncthreads();
  // Ag rows [ko][ki] (scatter-transpose from SAt), Bg rows [v][k] (vector)
  size_t gb = (size_t)blk * 4096;
  #pragma unroll
  for (int q = 0; q < 16; ++q)
    Ag_g[gb + (size_t)(sc0 + q) * 64 + sr] = __float2bfloat16(ld_bf(SAt, sr, sc0 + q));
  {
    short8 b0 = *(const short8*)(SBa + swz16(sr, s2));
    short8 b1 = *(const short8*)(SBa + swz16(sr, s2 + 1));
    *(short8*)(Bg_g + gb + (size_t)sr * 64 + s2 * 8) = b0;
    *(short8*)(Bg_g + gb + (size_t)sr * 64 + s2 * 8 + 8) = b1;
  }
}

// ---------------- scan B: 16 serial group composes ----------------
__global__ __launch_bounds__(256)
void k_scanB(const __hip_bfloat16* __restrict__ Ag_g, const __hip_bfloat16* __restrict__ Bg_g,
             __hip_bfloat16* __restrict__ Sg_g, float* __restrict__ fstate) {
  __shared__ __align__(16) char sm[3 * 8192];
  char* SSt = sm;
  char* SAg = sm + 8192;
  char* SBg = sm + 2 * 8192;
  int bh = blockIdx.x;
  int tid = threadIdx.x, lane = tid & 63, wv = tid >> 6;
  int sr = tid >> 2, s2 = (tid & 3) * 2;

  short8 z = {0, 0, 0, 0, 0, 0, 0, 0};
  *(short8*)(SSt + swz16(sr, s2)) = z;
  *(short8*)(SSt + swz16(sr, s2 + 1)) = z;

  floatx4 acc[4];
  for (int g = 0; g < NG; ++g) {
    size_t gb = ((size_t)bh * NG + g) * 4096;
    const __hip_bfloat16* pa = Ag_g + gb + (size_t)sr * 64 + s2 * 8;
    short8 a0 = *(const short8*)pa, a1 = *(const short8*)(pa + 8);
    const __hip_bfloat16* pb = Bg_g + gb + (size_t)sr * 64 + s2 * 8;
    short8 b0 = *(const short8*)pb, b1 = *(const short8*)(pb + 8);
    __syncthreads();             // SSt stable; prev compose's SAg/SBg reads done
    {  // write group-start state
      short8 s0 = *(const short8*)(SSt + swz16(sr, s2));
      short8 s1 = *(const short8*)(SSt + swz16(sr, s2 + 1));
      *(short8*)(Sg_g + gb + (size_t)sr * 64 + s2 * 8) = s0;
      *(short8*)(Sg_g + gb + (size_t)sr * 64 + s2 * 8 + 8) = s1;
    }
    *(short8*)(SAg + swz16(sr, s2)) = a0;
    *(short8*)(SAg + swz16(sr, s2 + 1)) = a1;
    *(short8*)(SBg + swz16(sr, s2)) = b0;
    *(short8*)(SBg + swz16(sr, s2 + 1)) = b1;
    __syncthreads();
    #pragma unroll
    for (int t = 0; t < 4; ++t) acc[t] = (floatx4){0.f, 0.f, 0.f, 0.f};
    mm16x64(SSt, SAg, wv, lane, acc);
    #pragma unroll
    for (int t = 0; t < 4; ++t) {
      int j = t * 16 + (lane & 15);
      #pragma unroll
      for (int r = 0; r < 4; ++r) {
        int i = wv * 16 + (lane >> 4) * 4 + r;
        float val = acc[t][r] + ld_bf(SBg, i, j);
        st_bf(SSt, i, j, val);
        if (g == NG - 1) fstate[(size_t)bh * 4096 + (size_t)j * 64 + i] = val;
      }
    }
  }
}

// ---------------- fused scan C + outputs ----------------
__global__ __launch_bounds__(256)
void k_scfuse(const __hip_bfloat16* __restrict__ kb16, const __hip_bfloat16* __restrict__ W_g,
              const __hip_bfloat16* __restrict__ Uvt_g, const float* __restrict__ csbuf,
              const __hip_bfloat16* __restrict__ Sg_g, __hip_bfloat16* __restrict__ outs) {
  __shared__ __align__(16) char sm[7 * 8192];
  char* SSt = sm;              // state [v][k]
  char* SKr = sm + 8192;       // raw K [t][k]; phase5: out bounce [t][v]
  char* SKt = sm + 2 * 8192;   // Ktil^T [k][t]; phase3+: G [i][j]
  char* SW  = sm + 3 * 8192;   // Wt [k][j]; phase3+: W row-major [j][k]
  char* SU  = sm + 4 * 8192;   // Uvt [v][t] -> Ueff
  char* SAc = sm + 5 * 8192;
  char* SBc = sm + 6 * 8192;

  int blk = blockIdx.x, bh = blk >> 4, gg = blk & 15;
  int b = bh / 12, h = bh % 12;
  int tid = threadIdx.x, lane = tid & 63, wv = tid >> 6;
  int sr = tid >> 2, sc0 = (tid & 3) * 16, s2 = (tid & 3) * 2;
  int c0 = gg * 8;
  int iR0 = wv * 16 + (lane >> 4) * 4;

  {
    const __hip_bfloat16* sp = Sg_g + (size_t)blk * 4096 + (size_t)sr * 64 + s2 * 8;
    short8 s0 = *(const short8*)sp, s1 = *(const short8*)(sp + 8);
    *(short8*)(SSt + swz16(sr, s2)) = s0;
    *(short8*)(SSt + swz16(sr, s2 + 1)) = s1;
  }

  floatx4 acc[4], pAcc[4];
  auto zacc = [&] {
    #pragma unroll
    for (int t = 0; t < 4; ++t) acc[t] = (floatx4){0.f, 0.f, 0.f, 0.f};
  };
  auto forRC = [&](auto&& f) {
    #pragma unroll
    for (int t = 0; t < 4; ++t)
      #pragma unroll
      for (int r = 0; r < 4; ++r)
        f(iR0 + r, t * 16 + (lane & 15), acc[t][r]);
  };

  for (int cc = 0; cc < 8; ++cc) {
    int c = c0 + cc;
    size_t row0 = (size_t)b * T_LEN + (size_t)c * 64;
    size_t wb = ((size_t)bh * NC + c) * 4096;
    const float* csb = csbuf + (size_t)(bh * NC + c) * CSTR;
    float cs_sr = csb[sr], cs63 = csb[63];
    float csI[4], csJ[4];
    #pragma unroll
    for (int r = 0; r < 4; ++r) csI[r] = csb[iR0 + r];
    #pragma unroll
    for (int t = 0; t < 4; ++t) csJ[t] = csb[t * 16 + (lane & 15)];
    const __hip_bfloat16* kp = kb16 + (row0 + sr) * 768 + h * 64 + sc0;
    short8 k0 = *(const short8*)kp, k1 = *(const short8*)(kp + 8);
    const __hip_bfloat16* wp = W_g + wb + (size_t)sr * 64 + sc0;
    short8 w0 = *(const short8*)wp, w1 = *(const short8*)(wp + 8);
    const __hip_bfloat16* up = Uvt_g + wb + (size_t)sr * 64 + sc0;
    short8 u0 = *(const short8*)up, u1 = *(const short8*)(up + 8);
    __syncthreads();             // bar0: prev iter's tile reads done
    // stage
    *(short8*)(SKr + swz16(sr, sc0 >> 3)) = k0;
    *(short8*)(SKr + swz16(sr, (sc0 >> 3) + 1)) = k1;
    {
      float scl = exp2f(cs63 - cs_sr);
      #pragma unroll
      for (int q = 0; q < 8; ++q) {
        st_bf(SKt, sc0 + q,     sr, scl * bf2f(((unsigned short*)&k0)[q]));
        st_bf(SKt, sc0 + 8 + q, sr, scl * bf2f(((unsigned short*)&k1)[q]));
      }
    }
    *(short8*)(SW + swz16(sr, s2)) = w0;
    *(short8*)(SW + swz16(sr, s2 + 1)) = w1;
    *(short8*)(SU + swz16(sr, s2)) = u0;
    *(short8*)(SU + swz16(sr, s2 + 1)) = u1;
    __syncthreads();             // bar1
    // builds
    float gC = exp2f(cs63);
    zacc(); mm16x64(SW, SKt, wv, lane, acc);
    forRC([&](int i, int j, float v) { st_bf(SAc, j, i, ((i == j) ? gC : 0.f) - v); });
    zacc(); mm16x64(SU, SKt, wv, lane, acc);
    forRC([&](int i, int j, float v) { st_bf(SBc, i, j, v); });
    __syncthreads();             // bar2: builds done; SKt,SW free
    // W row-major into SW slot; scaled-G into SKt slot
    #pragma unroll
    for (int q = 0; q < 8; ++q) {
      st_bf(SW, sc0 + q,     sr, bf2f(((unsigned short*)&w0)[q]));
      st_bf(SW, sc0 + 8 + q, sr, bf2f(((unsigned short*)&w1)[q]));
    }
    zacc(); mm16x64(SKr, SKr, wv, lane, acc);
    #pragma unroll
    for (int t = 0; t < 4; ++t) {
      int j = t * 16 + (lane & 15);
      #pragma unroll
      for (int r = 0; r < 4; ++r) {
        int i = iR0 + r;
        float gs = (j <= i) ? exp2f(csI[r] - csJ[t]) * acc[t][r] : 0.f;
        st_bf(SKt, i, j, gs);
      }
    }
    __syncthreads();             // bar3
    // P = K·S0^T (regs); Ueff = Uv - S0 x W (SU in place, own band)
    #pragma unroll
    for (int t = 0; t < 4; ++t) pAcc[t] = (floatx4){0.f, 0.f, 0.f, 0.f};
    mm16x64(SKr, SSt, wv, lane, pAcc);
    zacc(); mm16x64(SSt, SW, wv, lane, acc);
    forRC([&](int i, int j, float v) { st_bf(SU, i, j, ld_bf(SU, i, j) - v); });
    __syncthreads();             // bar4
    // O2 = G·Ueff; out -> SKr bounce; compose S' = S·Ac^T + Bc (in place)
    zacc(); mm16x64(SKt, SU, wv, lane, acc);
    #pragma unroll
    for (int t = 0; t < 4; ++t) {
      int vc = t * 16 + (lane & 15);
      #pragma unroll
      for (int r = 0; r < 4; ++r) {
        int i = iR0 + r;
        float o = exp2f(csI[r]) * pAcc[t][r] + acc[t][r];
        st_bf(SKr, i, vc, o);
      }
    }
    zacc(); mm16x64(SSt, SAc, wv, lane, acc);
    forRC([&](int i, int j, float v) { st_bf(SSt, i, j, v + ld_bf(SBc, i, j)); });
    __syncthreads();             // bar5
    // coalesced out write from bounce
    {
      short8 a0 = *(const short8*)(SKr + swz16(sr, s2));
      short8 a1 = *(const short8*)(SKr + swz16(sr, s2 + 1));
      __hip_bfloat16* op = outs + (row0 + sr) * 768 + h * 64 + s2 * 8;
      *(short8*)op = a0;
      *(short8*)(op + 8) = a1;
    }
  }
}

// ---------------- host glue ----------------
extern "C" void kernel_launch(void* const* d_in, const int* in_sizes, int n_in,
                              void* d_out, int out_size, void* d_ws, size_t ws_size,
                              hipStream_t stream) {
  (void)in_sizes; (void)n_in; (void)out_size; (void)ws_size;
  const float* x   = (const float*)d_in[0];
  const float* wn  = (const float*)d_in[1];
  const float* Wk  = (const float*)d_in[2];
  const float* Wv  = (const float*)d_in[3];
  const float* Wo  = (const float*)d_in[4];
  const float* Wb  = (const float*)d_in[5];
  const float* bb  = (const float*)d_in[6];
  const float* Wg  = (const float*)d_in[7];
  const float* bgb = (const float*)d_in[8];
  float* out = (float*)d_out;

  char* ws = (char*)d_ws;
  size_t off = 0;
  const size_t TILE = (size_t)NWG1 * 4096 * 2;           // 50.3 MB
  const size_t GTILE = (size_t)NGRP * 4096 * 2;          // 6.3 MB
  // slot1: xn (dead after gemm<0>) ∪ Uvt_g (chunk1 -> scanA/scfuse)
  __hip_bfloat16* xn   = (__hip_bfloat16*)(ws + off);
  __hip_bfloat16* Uvt  = (__hip_bfloat16*)(ws + off); off += TILE;
  __hip_bfloat16* WT   = (__hip_bfloat16*)(ws + off); off += (size_t)NKV * D * 2;
  __hip_bfloat16* WoT  = (__hip_bfloat16*)(ws + off); off += (size_t)D * D * 2;
  __hip_bfloat16* kb16 = (__hip_bfloat16*)(ws + off); off += (size_t)ROWS * D * 2;
  // slot3: vbuf (dead after chunk1) ∪ outs (scfuse -> gemm<1>)
  __hip_bfloat16* vbuf = (__hip_bfloat16*)(ws + off);
  __hip_bfloat16* outsb= (__hip_bfloat16*)(ws + off); off += TILE;
  // slot4: bgraw (dead after gates2) ∪ [Ag|Bg|Sg|W_g]
  float* bgraw         = (float*)(ws + off);
  __hip_bfloat16* Ag_g = (__hip_bfloat16*)(ws + off);
  __hip_bfloat16* Bg_g = Ag_g + (size_t)NGRP * 4096;
  __hip_bfloat16* Sg_g = Bg_g + (size_t)NGRP * 4096;
  __hip_bfloat16* W_g  = Sg_g + (size_t)NGRP * 4096;
  off += 3 * GTILE + TILE;                               // 69.2 MB slot
  float* csbuf         = (float*)(ws + off);          off += (size_t)NWG1 * CSTR * 4;
  // total ~229 MiB

  k_prep_wt<<<(NKV * D + 255) / 256, 256, 0, stream>>>(Wk, Wv, Wb, Wg, WT);
  k_prep_wo<<<(D * D) / 256, 256, 0, stream>>>(Wo, WoT);
  k_rmsnorm<<<ROWS / 4, 256, 0, stream>>>(x, wn, xn);
  k_gemm<0><<<dim3(ROWS / 128, NKV / 128), 256, 0, stream>>>(xn, WT, kb16, vbuf, bgraw, nullptr, nullptr);
  k_gates2<<<NWG1 / 4, 256, 0, stream>>>(bgraw, bb, bgb, csbuf);
  k_chunk1<<<NWG1, 256, 0, stream>>>(kb16, vbuf, csbuf, Uvt, W_g);
  k_scanA<<<NGRP, 256, 0, stream>>>(kb16, W_g, Uvt, csbuf, Ag_g, Bg_g);
  k_scanB<<<NBH, 256, 0, stream>>>(Ag_g, Bg_g, Sg_g, out + (size_t)ROWS * D);
  k_scfuse<<<NGRP, 256, 0, stream>>>(kb16, W_g, Uvt, csbuf, Sg_g, outsb);
  k_gemm<1><<<dim3(ROWS / 128, D / 128), 256, 0, stream>>>(outsb, WoT, nullptr, nullptr, nullptr, out, x);
}

// Round 11
// 481.911 us; speedup vs baseline: 1.2895x; 1.1436x over previous
//
#include <hip/hip_runtime.h>
#include <hip/hip_bf16.h>

// GatedDeltaNet B=4 T=8192 D=768 H=12 K=V=64 — chunked WY + two-level scan.
// Round 11: GEMM = round-7 BK=64 dbuf+prefetch+swizzle (proven 130us);
// scfuse rebuilt on the Ueff identity S' = gC*S + Ueff*Ktil (4 barriers,
// 5 matmuls, 48KB LDS -> 3 blocks/CU). Rest as round 7.

typedef __attribute__((ext_vector_type(8))) short short8;
typedef __attribute__((ext_vector_type(4))) float floatx4;

#define DEVFN static __device__ __forceinline__

typedef const __attribute__((address_space(1))) unsigned int* as1_u32p;
typedef __attribute__((address_space(3))) unsigned int* as3_u32p;

DEVFN void gll16(const void* g, void* l) {
  __builtin_amdgcn_global_load_lds((as1_u32p)g, (as3_u32p)l, 16, 0, 0);
}

DEVFN unsigned short f2bf_u(float f) {
  __hip_bfloat16 h = __float2bfloat16(f);
  return __builtin_bit_cast(unsigned short, h);
}
DEVFN float bf2f(unsigned short u) {
  return __bfloat162float(__builtin_bit_cast(__hip_bfloat16, u));
}

static constexpr int T_LEN = 8192;
static constexpr int ROWS  = 4 * 8192;   // 32768
static constexpr int D     = 768;
static constexpr int NKV   = 1664;
static constexpr int NC    = 128;        // chunks per sequence (C=64)
static constexpr int NBH   = 48;         // B*H
static constexpr int NWG1  = NBH * NC;   // 6144
static constexpr int NG    = 16;         // groups per bh (8 chunks each)
static constexpr int NGRP  = NBH * NG;   // 768
static constexpr int CSTR  = 192;        // csbuf: [0:64) incl, [64:128) excl, [128:192) beta

// ---- swizzled 64-col bf16 LDS tile helpers (row stride 128B, slot-XOR) ----
DEVFN int swz16(int row, int slot) {
  return (row << 7) + (((slot ^ (row & 7)) & 7) << 4);
}
DEVFN int swzE(int row, int col) {
  return (row << 7) + ((((col >> 3) ^ (row & 7)) & 7) << 4) + ((col & 7) << 1);
}
DEVFN void st_bf(char* base, int row, int col, float v) {
  *(unsigned short*)(base + swzE(row, col)) = f2bf_u(v);
}
DEVFN float ld_bf(const char* base, int row, int col) {
  return bf2f(*(const unsigned short*)(base + swzE(row, col)));
}
// D[16-band x 64] += A[band]·B^T over 64-col tiles (both swizzled)
DEVFN void mm16x64(const char* aB, const char* bB, int wv, int lane, floatx4 acc[4]) {
  #pragma unroll
  for (int ks = 0; ks < 2; ++ks) {
    short8 af = *(const short8*)(aB + swz16(wv * 16 + (lane & 15), ks * 4 + (lane >> 4)));
    #pragma unroll
    for (int t = 0; t < 4; ++t) {
      short8 bf = *(const short8*)(bB + swz16(t * 16 + (lane & 15), ks * 4 + (lane >> 4)));
      acc[t] = __builtin_amdgcn_mfma_f32_16x16x32_bf16(af, bf, acc[t], 0, 0, 0);
    }
  }
}

// ---------------- weight prep ----------------
__global__ void k_prep_wt(const float* __restrict__ Wk, const float* __restrict__ Wv,
                          const float* __restrict__ Wb, const float* __restrict__ Wg,
                          __hip_bfloat16* __restrict__ WT) {
  int idx = blockIdx.x * 256 + threadIdx.x;
  if (idx >= NKV * D) return;
  int n = idx / D, k = idx % D;
  float v;
  if (n < 768)       v = Wk[k * 768 + n];
  else if (n < 1536) v = Wv[k * 768 + (n - 768)];
  else if (n < 1548) v = Wb[k * 12 + (n - 1536)];
  else if (n < 1560) v = Wg[k * 12 + (n - 1548)];
  else               v = 0.f;
  WT[idx] = __float2bfloat16(v);
}

__global__ void k_prep_wo(const float* __restrict__ Wo, __hip_bfloat16* __restrict__ WoT) {
  int idx = blockIdx.x * 256 + threadIdx.x;
  int n = idx / D, k = idx % D;
  WoT[idx] = __float2bfloat16(Wo[k * 768 + n]);
}

// ---------------- RMSNorm ----------------
__global__ void k_rmsnorm(const float* __restrict__ x, const float* __restrict__ wn,
                          __hip_bfloat16* __restrict__ xn) {
  int wid  = (blockIdx.x << 2) + (threadIdx.x >> 6);
  int lane = threadIdx.x & 63;
  const float* xr = x + (size_t)wid * D;
  float4 a = *(const float4*)(xr + lane * 4);
  float4 b = *(const float4*)(xr + 256 + lane * 4);
  float4 c = *(const float4*)(xr + 512 + lane * 4);
  float ss = a.x*a.x + a.y*a.y + a.z*a.z + a.w*a.w
           + b.x*b.x + b.y*b.y + b.z*b.z + b.w*b.w
           + c.x*c.x + c.y*c.y + c.z*c.z + c.w*c.w;
  #pragma unroll
  for (int m = 1; m < 64; m <<= 1) ss += __shfl_xor(ss, m);
  float rs = rsqrtf(ss * (1.f / 768.f) + 1e-6f);
  float4 w0 = *(const float4*)(wn + lane * 4);
  float4 w1 = *(const float4*)(wn + 256 + lane * 4);
  float4 w2 = *(const float4*)(wn + 512 + lane * 4);
  unsigned short* xo = (unsigned short*)(xn + (size_t)wid * D);
  ushort4 u;
  u.x = f2bf_u(a.x*rs*w0.x); u.y = f2bf_u(a.y*rs*w0.y); u.z = f2bf_u(a.z*rs*w0.z); u.w = f2bf_u(a.w*rs*w0.w);
  *(ushort4*)(xo + lane * 4) = u;
  u.x = f2bf_u(b.x*rs*w1.x); u.y = f2bf_u(b.y*rs*w1.y); u.z = f2bf_u(b.z*rs*w1.z); u.w = f2bf_u(b.w*rs*w1.w);
  *(ushort4*)(xo + 256 + lane * 4) = u;
  u.x = f2bf_u(c.x*rs*w2.x); u.y = f2bf_u(c.y*rs*w2.y); u.z = f2bf_u(c.z*rs*w2.z); u.w = f2bf_u(c.w*rs*w2.w);
  *(ushort4*)(xo + 512 + lane * 4) = u;
}

// ---------------- bf16 MFMA GEMM, 128x128 tile, BK=64 dbuf prefetch ----
// LDS (row r, slot s) holds GLOBAL chunk (r, s ^ (r&7)) (both-sides swizzle).
template <int EPI>
__global__ __launch_bounds__(256)
void k_gemm(const __hip_bfloat16* __restrict__ A, const __hip_bfloat16* __restrict__ Bt,
            __hip_bfloat16* __restrict__ Ck, __hip_bfloat16* __restrict__ Cv,
            float* __restrict__ Cbg, float* __restrict__ C0, const float* __restrict__ Xadd) {
  __shared__ __align__(16) unsigned short As[2][128 * 64];
  __shared__ __align__(16) unsigned short Bs[2][128 * 64];
  const int K = 768, NKT = 12;
  int tid = threadIdx.x, lane = tid & 63, w = tid >> 6;
  int wr = w >> 1, wc = w & 1;
  int bx = blockIdx.x;                     // 256 m-blocks = 8 XCD chunks of 32
  bx = (bx & 7) * 32 + (bx >> 3);
  int m0 = bx * 128, n0 = blockIdx.y * 128;
  floatx4 zero = {0.f, 0.f, 0.f, 0.f};
  floatx4 acc[4][4];
  #pragma unroll
  for (int i = 0; i < 4; ++i)
    #pragma unroll
    for (int j = 0; j < 4; ++j) acc[i][j] = zero;

  auto stage = [&](int buf, int kt) {
    #pragma unroll
    for (int it = 0; it < 4; ++it) {
      int L = it * 256 + tid;
      int r = L >> 3, s = L & 7, sg = s ^ (r & 7);
      gll16(A  + (size_t)(m0 + r) * K + kt * 64 + sg * 8, &As[buf][L * 8]);
      gll16(Bt + (size_t)(n0 + r) * K + kt * 64 + sg * 8, &Bs[buf][L * 8]);
    }
  };

  stage(0, 0);
  __syncthreads();
  int buf = 0;
  for (int kt = 0; kt < NKT; ++kt) {
    if (kt + 1 < NKT) stage(buf ^ 1, kt + 1);
    __builtin_amdgcn_s_setprio(1);
    #pragma unroll
    for (int ks = 0; ks < 2; ++ks) {
      int c = ks * 4 + (lane >> 4);
      short8 af[4], bfr[4];
      #pragma unroll
      for (int i = 0; i < 4; ++i) {
        int ri = wr * 64 + i * 16 + (lane & 15);
        af[i] = *(const short8*)&As[buf][ri * 64 + ((c ^ (ri & 7)) << 3)];
      }
      #pragma unroll
      for (int j = 0; j < 4; ++j) {
        int rj = wc * 64 + j * 16 + (lane & 15);
        bfr[j] = *(const short8*)&Bs[buf][rj * 64 + ((c ^ (rj & 7)) << 3)];
      }
      #pragma unroll
      for (int i = 0; i < 4; ++i)
        #pragma unroll
        for (int j = 0; j < 4; ++j)
          acc[i][j] = __builtin_amdgcn_mfma_f32_16x16x32_bf16(af[i], bfr[j], acc[i][j], 0, 0, 0);
    }
    __builtin_amdgcn_s_setprio(0);
    __syncthreads();              // drains vmcnt(0): next buffer complete
    buf ^= 1;
  }

  if constexpr (EPI == 0) {
    if (n0 < 768) {
      #pragma unroll
      for (int i = 0; i < 4; ++i) {
        #pragma unroll
        for (int r = 0; r < 4; ++r) {
          float ss = 0.f;
          #pragma unroll
          for (int j = 0; j < 4; ++j) { float t = acc[i][j][r]; ss = fmaf(t, t, ss); }
          ss += __shfl_xor(ss, 1); ss += __shfl_xor(ss, 2);
          ss += __shfl_xor(ss, 4); ss += __shfl_xor(ss, 8);
          float sc = 1.f / fmaxf(sqrtf(ss), 1e-12f);
          int mm = m0 + wr * 64 + i * 16 + (lane >> 4) * 4 + r;
          #pragma unroll
          for (int j = 0; j < 4; ++j) {
            int n = n0 + wc * 64 + j * 16 + (lane & 15);
            Ck[(size_t)mm * 768 + n] = __float2bfloat16(acc[i][j][r] * sc);
          }
        }
      }
    } else if (n0 < 1536) {
      #pragma unroll
      for (int i = 0; i < 4; ++i)
        #pragma unroll
        for (int j = 0; j < 4; ++j) {
          int n = n0 + wc * 64 + j * 16 + (lane & 15) - 768;
          #pragma unroll
          for (int r = 0; r < 4; ++r) {
            int mm = m0 + wr * 64 + i * 16 + (lane >> 4) * 4 + r;
            Cv[(size_t)mm * 768 + n] = __float2bfloat16(acc[i][j][r]);
          }
        }
    } else {
      #pragma unroll
      for (int i = 0; i < 4; ++i)
        #pragma unroll
        for (int j = 0; j < 4; ++j) {
          int n = n0 + wc * 64 + j * 16 + (lane & 15) - 1536;
          if (n < 24) {                     // only 24 live beta/g cols
            #pragma unroll
            for (int r = 0; r < 4; ++r) {
              int mm = m0 + wr * 64 + i * 16 + (lane >> 4) * 4 + r;
              Cbg[(size_t)mm * 128 + n] = acc[i][j][r];
            }
          }
        }
    }
  } else {
    #pragma unroll
    for (int i = 0; i < 4; ++i)
      #pragma unroll
      for (int j = 0; j < 4; ++j) {
        int n = n0 + wc * 64 + j * 16 + (lane & 15);
        #pragma unroll
        for (int r = 0; r < 4; ++r) {
          int mm = m0 + wr * 64 + i * 16 + (lane >> 4) * 4 + r;
          size_t o = (size_t)mm * 768 + n;
          C0[o] = Xadd[o] + acc[i][j][r];
        }
      }
  }
}

// ---------------- fused sigmoid + gate prefix ----------------
__global__ void k_gates2(const float* __restrict__ bgraw, const float* __restrict__ bb,
                         const float* __restrict__ bgb, float* __restrict__ csbuf) {
  int wid  = blockIdx.x * 4 + (threadIdx.x >> 6);   // bh*NC + ck
  int lane = threadIdx.x & 63;
  int bh = wid >> 7, ck = wid & 127;
  int b = bh / 12, h = bh % 12;
  size_t row0 = (size_t)b * T_LEN + (size_t)ck * 64;
  const float* br = bgraw + (row0 + lane) * 128;
  float bet = 1.f / (1.f + __expf(-(br[h] + bb[h])));
  float g   = 1.f / (1.f + __expf(-(br[12 + h] + bgb[h])));
  float lg = __log2f(g);
  float ci = lg;
  #pragma unroll
  for (int d = 1; d < 64; d <<= 1) { float t = __shfl_up(ci, d); if (lane >= d) ci += t; }
  csbuf[(size_t)wid * CSTR + lane] = ci;
  csbuf[(size_t)wid * CSTR + 64 + lane] = ci - lg;
  csbuf[(size_t)wid * CSTR + 128 + lane] = bet;
}

// ---------------- pass 1: per-chunk WY factors (Uv, W) ----------------
__global__ __launch_bounds__(256)
void k_chunk1(const __hip_bfloat16* __restrict__ kb16, const __hip_bfloat16* __restrict__ vbuf,
              const float* __restrict__ csbuf,
              __hip_bfloat16* __restrict__ Uvt_g, __hip_bfloat16* __restrict__ W_g) {
  __shared__ __align__(16) char sm[6 * 8192 + 768];
  char* SA = sm;
  char* SB = sm + 8192;
  char* SC = sm + 2 * 8192;
  char* SD = sm + 3 * 8192;   // SD,SE contiguous (RHST spans both)
  char* SE = sm + 4 * 8192;
  char* SF = sm + 5 * 8192;
  float* cs   = (float*)(sm + 6 * 8192);
  float* cps  = (float*)(sm + 6 * 8192 + 256);
  float* bets = (float*)(sm + 6 * 8192 + 512);

  int blk = blockIdx.x, bh = blk >> 7, ck = blk & 127;
  int b = bh / 12, h = bh % 12;
  int tid = threadIdx.x, lane = tid & 63, wv = tid >> 6;
  size_t row0 = (size_t)b * T_LEN + (size_t)ck * 64;
  size_t wbase = (size_t)blk * 4096;

  if (tid < 64) {
    cs[tid]   = csbuf[(size_t)blk * CSTR + tid];
    cps[tid]  = csbuf[(size_t)blk * CSTR + 64 + tid];
    bets[tid] = csbuf[(size_t)blk * CSTR + 128 + tid];
  }
  int sr = tid >> 2, sc0 = (tid & 3) * 16;
  {
    const __hip_bfloat16* kp = kb16 + (row0 + sr) * 768 + h * 64 + sc0;
    short8 k0 = *(const short8*)kp;
    short8 k1 = *(const short8*)(kp + 8);
    *(short8*)(SA + swz16(sr, sc0 >> 3)) = k0;
    *(short8*)(SA + swz16(sr, (sc0 >> 3) + 1)) = k1;
  }
  short8 vreg0, vreg1;
  {
    const __hip_bfloat16* vp = vbuf + (row0 + sr) * 768 + h * 64 + sc0;
    vreg0 = *(const short8*)vp;
    vreg1 = *(const short8*)(vp + 8);
  }
  __syncthreads();

  floatx4 acc[4];
  auto zacc = [&] {
    #pragma unroll
    for (int t = 0; t < 4; ++t) acc[t] = (floatx4){0.f, 0.f, 0.f, 0.f};
  };
  auto forRC = [&](auto&& f) {
    #pragma unroll
    for (int t = 0; t < 4; ++t)
      #pragma unroll
      for (int r = 0; r < 4; ++r)
        f(wv * 16 + (lane >> 4) * 4 + r, t * 16 + (lane & 15), acc[t][r]);
  };

  // G = K K^T -> L(SB), Lt(SC), M1=I-L(SD)
  zacc(); mm16x64(SA, SA, wv, lane, acc);
  forRC([&](int i, int j, float v) {
    float Lv = 0.f;
    if (j < i) Lv = bets[i] * exp2f(cps[i] - cs[j]) * v;
    st_bf(SB, i, j, Lv);
    st_bf(SC, j, i, Lv);
    st_bf(SD, i, j, (i == j ? 1.f : 0.f) - Lv);
  });
  __syncthreads();

  auto power = [&](char* Ar, char* Bt, char* Or, char* Ot) {
    zacc(); mm16x64(Ar, Bt, wv, lane, acc);
    forRC([&](int i, int j, float v) { st_bf(Or, i, j, v); st_bf(Ot, j, i, v); });
    __syncthreads();
  };
  auto powerT = [&](char* Ar, char* Bt, char* Ot) {
    zacc(); mm16x64(Ar, Bt, wv, lane, acc);
    forRC([&](int i, int j, float v) { st_bf(Ot, j, i, v); });
    __syncthreads();
  };
  auto combine = [&](char* Mr, char* Pt, char* Out) {
    zacc(); mm16x64(Mr, Pt, wv, lane, acc);
    forRC([&](int i, int j, float v) { st_bf(Out, i, j, v + ld_bf(Mr, i, j)); });
    __syncthreads();
  };

  power(SB, SC, SE, SF);    // L^2
  combine(SD, SF, SB);      // M2
  power(SE, SF, SC, SD);    // L^4
  combine(SB, SD, SE);      // M3
  power(SC, SD, SF, SB);    // L^8
  combine(SE, SB, SC);      // M4
  power(SF, SB, SD, SE);    // L^16
  combine(SC, SE, SF);      // M5
  powerT(SD, SE, SB);       // L^32t
  combine(SF, SB, SC);      // T -> SC

  // RHST (128 x 64): rows c<64: beta_i*V[i][c]; rows 64+k: beta_i*gprev_i*K[i][k]
  {
    float be = bets[sr];
    #pragma unroll
    for (int q = 0; q < 8; ++q) {
      st_bf(SD, sc0 + q,     sr, be * bf2f(((unsigned short*)&vreg0)[q]));
      st_bf(SD, sc0 + 8 + q, sr, be * bf2f(((unsigned short*)&vreg1)[q]));
    }
    float scl = be * exp2f(cps[sr]);
    #pragma unroll
    for (int q = 0; q < 16; ++q) {
      float kv = ld_bf(SA, sr, sc0 + q);
      st_bf(SD, 64 + sc0 + q, sr, scl * kv);
    }
  }
  __syncthreads();

  // X = T * RHS -> Uvt to SF; W^T rows to HBM (Wt layout [k][j])
  {
    floatx4 xacc[8];
    #pragma unroll
    for (int t = 0; t < 8; ++t) xacc[t] = (floatx4){0.f, 0.f, 0.f, 0.f};
    #pragma unroll
    for (int ks = 0; ks < 2; ++ks) {
      short8 af = *(const short8*)(SC + swz16(wv * 16 + (lane & 15), ks * 4 + (lane >> 4)));
      #pragma unroll
      for (int t = 0; t < 8; ++t) {
        short8 bf = *(const short8*)(SD + swz16(t * 16 + (lane & 15), ks * 4 + (lane >> 4)));
        xacc[t] = __builtin_amdgcn_mfma_f32_16x16x32_bf16(af, bf, xacc[t], 0, 0, 0);
      }
    }
    #pragma unroll
    for (int t = 0; t < 8; ++t) {
      int c = t * 16 + (lane & 15);
      #pragma unroll
      for (int r = 0; r < 4; ++r) {
        int i = wv * 16 + (lane >> 4) * 4 + r;
        float v = xacc[t][r];
        if (c < 64) st_bf(SF, c, i, v);
        else        W_g[wbase + (size_t)(c - 64) * 64 + i] = __float2bfloat16(v);
      }
    }
  }
  __syncthreads();

  {
    int s2 = (tid & 3) * 2;
    short8 a0 = *(const short8*)(SF + swz16(sr, s2));
    short8 a1 = *(const short8*)(SF + swz16(sr, s2 + 1));
    *(short8*)(Uvt_g + wbase + (size_t)sr * 64 + s2 * 8) = a0;
    *(short8*)(Uvt_g + wbase + (size_t)sr * 64 + s2 * 8 + 8) = a1;
  }
}

// ---------------- scan A: per-group (8 chunks) map composition ----------------
__global__ __launch_bounds__(256)
void k_scanA(const __hip_bfloat16* __restrict__ kb16, const __hip_bfloat16* __restrict__ W_g,
             const __hip_bfloat16* __restrict__ Uvt_g, const float* __restrict__ csbuf,
             __hip_bfloat16* __restrict__ Ag_g, __hip_bfloat16* __restrict__ Bg_g) {
  __shared__ __align__(16) char sm[7 * 8192];
  char* SK  = sm;              // Ktil^T [k][t]
  char* SW  = sm + 8192;       // Wt [k][j]
  char* SU  = sm + 2 * 8192;   // Uvt [v][t]
  char* SAc = sm + 3 * 8192;   // Ac [ko][ki]
  char* SBc = sm + 4 * 8192;   // Bct [v][k]
  char* SAt = sm + 5 * 8192;   // Aacc^T [ki][ko]
  char* SBa = sm + 6 * 8192;   // Bacc [v][k]

  int blk = blockIdx.x, bh = blk >> 4, gg = blk & 15;
  int b = bh / 12, h = bh % 12;
  int tid = threadIdx.x, lane = tid & 63, wv = tid >> 6;
  int sr = tid >> 2, sc0 = (tid & 3) * 16, s2 = (tid & 3) * 2;
  int c0 = gg * 8;

  short8 z = {0, 0, 0, 0, 0, 0, 0, 0};
  *(short8*)(SAt + swz16(sr, s2)) = z;
  *(short8*)(SAt + swz16(sr, s2 + 1)) = z;
  *(short8*)(SBa + swz16(sr, s2)) = z;
  *(short8*)(SBa + swz16(sr, s2 + 1)) = z;
  __syncthreads();
  if (tid < 64) st_bf(SAt, tid, tid, 1.f);   // Aacc = I

  floatx4 acc[4];
  auto zacc = [&] {
    #pragma unroll
    for (int t = 0; t < 4; ++t) acc[t] = (floatx4){0.f, 0.f, 0.f, 0.f};
  };
  auto forRC = [&](auto&& f) {
    #pragma unroll
    for (int t = 0; t < 4; ++t)
      #pragma unroll
      for (int r = 0; r < 4; ++r)
        f(wv * 16 + (lane >> 4) * 4 + r, t * 16 + (lane & 15), acc[t][r]);
  };

  for (int cc = 0; cc < 8; ++cc) {
    int c = c0 + cc;
    size_t row0 = (size_t)b * T_LEN + (size_t)c * 64;
    size_t wb = ((size_t)bh * NC + c) * 4096;
    const float* csb = csbuf + (size_t)(bh * NC + c) * CSTR;
    float cs_sr = csb[sr], cs63 = csb[63];
    const __hip_bfloat16* kp = kb16 + (row0 + sr) * 768 + h * 64 + sc0;
    short8 k0 = *(const short8*)kp, k1 = *(const short8*)(kp + 8);
    const __hip_bfloat16* wp = W_g + wb + (size_t)sr * 64 + s2 * 8;
    short8 w0 = *(const short8*)wp, w1 = *(const short8*)(wp + 8);
    const __hip_bfloat16* up = Uvt_g + wb + (size_t)sr * 64 + s2 * 8;
    short8 u0 = *(const short8*)up, u1 = *(const short8*)(up + 8);
    // stage
    float scl = exp2f(cs63 - cs_sr);
    #pragma unroll
    for (int q = 0; q < 8; ++q) {
      st_bf(SK, sc0 + q,     sr, scl * bf2f(((unsigned short*)&k0)[q]));
      st_bf(SK, sc0 + 8 + q, sr, scl * bf2f(((unsigned short*)&k1)[q]));
    }
    *(short8*)(SW + swz16(sr, s2)) = w0;
    *(short8*)(SW + swz16(sr, s2 + 1)) = w1;
    *(short8*)(SU + swz16(sr, s2)) = u0;
    *(short8*)(SU + swz16(sr, s2 + 1)) = u1;
    __syncthreads();   // (a) staged; prev compose's SAc/SBc reads done
    float gC = exp2f(cs63);
    zacc(); mm16x64(SW, SK, wv, lane, acc);
    forRC([&](int i, int j, float v) { st_bf(SAc, j, i, ((i == j) ? gC : 0.f) - v); });
    zacc(); mm16x64(SU, SK, wv, lane, acc);
    forRC([&](int i, int j, float v) { st_bf(SBc, i, j, v); });
    __syncthreads();   // (b) Ac/Bc ready
    // compose in place (A-operand rows are wave-private)
    zacc(); mm16x64(SAt, SAc, wv, lane, acc);
    forRC([&](int i, int j, float v) { st_bf(SAt, i, j, v); });
    zacc(); mm16x64(SBa, SAc, wv, lane, acc);
    forRC([&](int i, int j, float v) { st_bf(SBa, i, j, v + ld_bf(SBc, i, j)); });
  }
  __syncthreads();
  // Ag rows [ko][ki] (scatter-transpose from SAt), Bg rows [v][k] (vector)
  size_t gb = (size_t)blk * 4096;
  #pragma unroll
  for (int q = 0; q < 16; ++q)
    Ag_g[gb + (size_t)(sc0 + q) * 64 + sr] = __float2bfloat16(ld_bf(SAt, sr, sc0 + q));
  {
    short8 b0 = *(const short8*)(SBa + swz16(sr, s2));
    short8 b1 = *(const short8*)(SBa + swz16(sr, s2 + 1));
    *(short8*)(Bg_g + gb + (size_t)sr * 64 + s2 * 8) = b0;
    *(short8*)(Bg_g + gb + (size_t)sr * 64 + s2 * 8 + 8) = b1;
  }
}

// ---------------- scan B: 16 serial group composes ----------------
__global__ __launch_bounds__(256)
void k_scanB(const __hip_bfloat16* __restrict__ Ag_g, const __hip_bfloat16* __restrict__ Bg_g,
             __hip_bfloat16* __restrict__ Sg_g, float* __restrict__ fstate) {
  __shared__ __align__(16) char sm[3 * 8192];
  char* SSt = sm;
  char* SAg = sm + 8192;
  char* SBg = sm + 2 * 8192;
  int bh = blockIdx.x;
  int tid = threadIdx.x, lane = tid & 63, wv = tid >> 6;
  int sr = tid >> 2, s2 = (tid & 3) * 2;

  short8 z = {0, 0, 0, 0, 0, 0, 0, 0};
  *(short8*)(SSt + swz16(sr, s2)) = z;
  *(short8*)(SSt + swz16(sr, s2 + 1)) = z;

  floatx4 acc[4];
  for (int g = 0; g < NG; ++g) {
    size_t gb = ((size_t)bh * NG + g) * 4096;
    const __hip_bfloat16* pa = Ag_g + gb + (size_t)sr * 64 + s2 * 8;
    short8 a0 = *(const short8*)pa, a1 = *(const short8*)(pa + 8);
    const __hip_bfloat16* pb = Bg_g + gb + (size_t)sr * 64 + s2 * 8;
    short8 b0 = *(const short8*)pb, b1 = *(const short8*)(pb + 8);
    __syncthreads();             // SSt stable; prev compose's SAg/SBg reads done
    {  // write group-start state
      short8 s0 = *(const short8*)(SSt + swz16(sr, s2));
      short8 s1 = *(const short8*)(SSt + swz16(sr, s2 + 1));
      *(short8*)(Sg_g + gb + (size_t)sr * 64 + s2 * 8) = s0;
      *(short8*)(Sg_g + gb + (size_t)sr * 64 + s2 * 8 + 8) = s1;
    }
    *(short8*)(SAg + swz16(sr, s2)) = a0;
    *(short8*)(SAg + swz16(sr, s2 + 1)) = a1;
    *(short8*)(SBg + swz16(sr, s2)) = b0;
    *(short8*)(SBg + swz16(sr, s2 + 1)) = b1;
    __syncthreads();
    #pragma unroll
    for (int t = 0; t < 4; ++t) acc[t] = (floatx4){0.f, 0.f, 0.f, 0.f};
    mm16x64(SSt, SAg, wv, lane, acc);
    #pragma unroll
    for (int t = 0; t < 4; ++t) {
      int j = t * 16 + (lane & 15);
      #pragma unroll
      for (int r = 0; r < 4; ++r) {
        int i = wv * 16 + (lane >> 4) * 4 + r;
        float val = acc[t][r] + ld_bf(SBg, i, j);
        st_bf(SSt, i, j, val);
        if (g == NG - 1) fstate[(size_t)bh * 4096 + (size_t)j * 64 + i] = val;
      }
    }
  }
}

// ---------------- fused scan C + outputs (Ueff compose, 4 barriers/iter) ----
// Per chunk: stage Kraw/Ktil^T/W[j][k]/Uv; G build + P=K·S0^T + Ueff=Uv−S0·W^T;
// out = e^cs·P + G·Ueff; S' = gC·S + Ueff·Ktil (exact identity with Ac/Bc form).
__global__ __launch_bounds__(256)
void k_scfuse(const __hip_bfloat16* __restrict__ kb16, const __hip_bfloat16* __restrict__ W_g,
              const __hip_bfloat16* __restrict__ Uvt_g, const float* __restrict__ csbuf,
              const __hip_bfloat16* __restrict__ Sg_g, __hip_bfloat16* __restrict__ outs) {
  __shared__ __align__(16) char sm[6 * 8192];
  char* SSt = sm;              // state [v][k]
  char* SKr = sm + 8192;       // raw K [t][k]; last phase: out bounce [t][v]
  char* SKt = sm + 2 * 8192;   // Ktil^T [k][t]
  char* SG  = sm + 3 * 8192;   // scaled G [t][t']
  char* SW2 = sm + 4 * 8192;   // W row-major [t][k]
  char* SU  = sm + 5 * 8192;   // Uvt [v][t] -> Ueff

  int blk = blockIdx.x, bh = blk >> 4, gg = blk & 15;
  int b = bh / 12, h = bh % 12;
  int tid = threadIdx.x, lane = tid & 63, wv = tid >> 6;
  int sr = tid >> 2, sc0 = (tid & 3) * 16, s2 = (tid & 3) * 2;
  int c0 = gg * 8;
  int iR0 = wv * 16 + (lane >> 4) * 4;

  {
    const __hip_bfloat16* sp = Sg_g + (size_t)blk * 4096 + (size_t)sr * 64 + s2 * 8;
    short8 s0 = *(const short8*)sp, s1 = *(const short8*)(sp + 8);
    *(short8*)(SSt + swz16(sr, s2)) = s0;
    *(short8*)(SSt + swz16(sr, s2 + 1)) = s1;
  }

  floatx4 acc[4], pAcc[4];
  auto zacc = [&] {
    #pragma unroll
    for (int t = 0; t < 4; ++t) acc[t] = (floatx4){0.f, 0.f, 0.f, 0.f};
  };
  auto forRC = [&](auto&& f) {
    #pragma unroll
    for (int t = 0; t < 4; ++t)
      #pragma unroll
      for (int r = 0; r < 4; ++r)
        f(iR0 + r, t * 16 + (lane & 15), acc[t][r]);
  };

  for (int cc = 0; cc < 8; ++cc) {
    int c = c0 + cc;
    size_t row0 = (size_t)b * T_LEN + (size_t)c * 64;
    size_t wb = ((size_t)bh * NC + c) * 4096;
    const float* csb = csbuf + (size_t)(bh * NC + c) * CSTR;
    float cs_sr = csb[sr], cs63 = csb[63];
    float csI[4], csJ[4];
    #pragma unroll
    for (int r = 0; r < 4; ++r) csI[r] = csb[iR0 + r];
    #pragma unroll
    for (int t = 0; t < 4; ++t) csJ[t] = csb[t * 16 + (lane & 15)];
    const __hip_bfloat16* kp = kb16 + (row0 + sr) * 768 + h * 64 + sc0;
    short8 k0 = *(const short8*)kp, k1 = *(const short8*)(kp + 8);
    const __hip_bfloat16* wp = W_g + wb + (size_t)sr * 64 + sc0;
    short8 w0 = *(const short8*)wp, w1 = *(const short8*)(wp + 8);
    const __hip_bfloat16* up = Uvt_g + wb + (size_t)sr * 64 + sc0;
    short8 u0 = *(const short8*)up, u1 = *(const short8*)(up + 8);
    __syncthreads();             // bar A: prev iter's bounce-read + compose done
    // stage 4 tiles
    *(short8*)(SKr + swz16(sr, sc0 >> 3)) = k0;
    *(short8*)(SKr + swz16(sr, (sc0 >> 3) + 1)) = k1;
    {
      float scl = exp2f(cs63 - cs_sr);
      #pragma unroll
      for (int q = 0; q < 8; ++q) {
        st_bf(SKt, sc0 + q,     sr, scl * bf2f(((unsigned short*)&k0)[q]));
        st_bf(SKt, sc0 + 8 + q, sr, scl * bf2f(((unsigned short*)&k1)[q]));
      }
    }
    #pragma unroll
    for (int q = 0; q < 8; ++q) {          // W row-major [j][k] from Wt rows
      st_bf(SW2, sc0 + q,     sr, bf2f(((unsigned short*)&w0)[q]));
      st_bf(SW2, sc0 + 8 + q, sr, bf2f(((unsigned short*)&w1)[q]));
    }
    *(short8*)(SU + swz16(sr, s2)) = u0;
    *(short8*)(SU + swz16(sr, s2 + 1)) = u1;
    __syncthreads();             // bar B: staged
    // G (scaled, lower-tri), P = K·S0^T (regs), Ueff = Uv − S0·W^T (in place)
    zacc(); mm16x64(SKr, SKr, wv, lane, acc);
    #pragma unroll
    for (int t = 0; t < 4; ++t) {
      int j = t * 16 + (lane & 15);
      #pragma unroll
      for (int r = 0; r < 4; ++r) {
        int i = iR0 + r;
        float gs = (j <= i) ? exp2f(csI[r] - csJ[t]) * acc[t][r] : 0.f;
        st_bf(SG, i, j, gs);
      }
    }
    #pragma unroll
    for (int t = 0; t < 4; ++t) pAcc[t] = (floatx4){0.f, 0.f, 0.f, 0.f};
    mm16x64(SKr, SSt, wv, lane, pAcc);
    zacc(); mm16x64(SSt, SW2, wv, lane, acc);
    forRC([&](int i, int j, float v) { st_bf(SU, i, j, ld_bf(SU, i, j) - v); });
    __syncthreads();             // bar C: G, Ueff final; SKr free
    // O2 = G·Ueff -> out bounce in SKr; compose S' = gC·S + Ueff·Ktil
    zacc(); mm16x64(SG, SU, wv, lane, acc);
    #pragma unroll
    for (int t = 0; t < 4; ++t) {
      int vc = t * 16 + (lane & 15);
      #pragma unroll
      for (int r = 0; r < 4; ++r) {
        int i = iR0 + r;
        float o = exp2f(csI[r]) * pAcc[t][r] + acc[t][r];
        st_bf(SKr, i, vc, o);
      }
    }
    if (cc < 7) {
      float gC = exp2f(cs63);
      zacc(); mm16x64(SU, SKt, wv, lane, acc);
      forRC([&](int i, int j, float v) { st_bf(SSt, i, j, gC * ld_bf(SSt, i, j) + v); });
    }
    __syncthreads();             // bar D: bounce + state ready
    {
      short8 a0 = *(const short8*)(SKr + swz16(sr, s2));
      short8 a1 = *(const short8*)(SKr + swz16(sr, s2 + 1));
      __hip_bfloat16* op = outs + (row0 + sr) * 768 + h * 64 + s2 * 8;
      *(short8*)op = a0;
      *(short8*)(op + 8) = a1;
    }
  }
}

// ---------------- host glue ----------------
extern "C" void kernel_launch(void* const* d_in, const int* in_sizes, int n_in,
                              void* d_out, int out_size, void* d_ws, size_t ws_size,
                              hipStream_t stream) {
  (void)in_sizes; (void)n_in; (void)out_size; (void)ws_size;
  const float* x   = (const float*)d_in[0];
  const float* wn  = (const float*)d_in[1];
  const float* Wk  = (const float*)d_in[2];
  const float* Wv  = (const float*)d_in[3];
  const float* Wo  = (const float*)d_in[4];
  const float* Wb  = (const float*)d_in[5];
  const float* bb  = (const float*)d_in[6];
  const float* Wg  = (const float*)d_in[7];
  const float* bgb = (const float*)d_in[8];
  float* out = (float*)d_out;

  char* ws = (char*)d_ws;
  size_t off = 0;
  const size_t TILE = (size_t)NWG1 * 4096 * 2;           // 50.3 MB
  const size_t GTILE = (size_t)NGRP * 4096 * 2;          // 6.3 MB
  // slot1: xn (dead after gemm<0>) ∪ Uvt_g (chunk1 -> scanA/scfuse)
  __hip_bfloat16* xn   = (__hip_bfloat16*)(ws + off);
  __hip_bfloat16* Uvt  = (__hip_bfloat16*)(ws + off); off += TILE;
  __hip_bfloat16* WT   = (__hip_bfloat16*)(ws + off); off += (size_t)NKV * D * 2;
  __hip_bfloat16* WoT  = (__hip_bfloat16*)(ws + off); off += (size_t)D * D * 2;
  __hip_bfloat16* kb16 = (__hip_bfloat16*)(ws + off); off += (size_t)ROWS * D * 2;
  // slot3: vbuf (dead after chunk1) ∪ outs (scfuse -> gemm<1>)
  __hip_bfloat16* vbuf = (__hip_bfloat16*)(ws + off);
  __hip_bfloat16* outsb= (__hip_bfloat16*)(ws + off); off += TILE;
  // slot4: bgraw (dead after gates2) ∪ [Ag|Bg|Sg|W_g]
  float* bgraw         = (float*)(ws + off);
  __hip_bfloat16* Ag_g = (__hip_bfloat16*)(ws + off);
  __hip_bfloat16* Bg_g = Ag_g + (size_t)NGRP * 4096;
  __hip_bfloat16* Sg_g = Bg_g + (size_t)NGRP * 4096;
  __hip_bfloat16* W_g  = Sg_g + (size_t)NGRP * 4096;
  off += 3 * GTILE + TILE;                               // 69.2 MB slot
  float* csbuf         = (float*)(ws + off);          off += (size_t)NWG1 * CSTR * 4;
  // total ~229 MiB

  k_prep_wt<<<(NKV * D + 255) / 256, 256, 0, stream>>>(Wk, Wv, Wb, Wg, WT);
  k_prep_wo<<<(D * D) / 256, 256, 0, stream>>>(Wo, WoT);
  k_rmsnorm<<<ROWS / 4, 256, 0, stream>>>(x, wn, xn);
  k_gemm<0><<<dim3(ROWS / 128, NKV / 128), 256, 0, stream>>>(xn, WT, kb16, vbuf, bgraw, nullptr, nullptr);
  k_gates2<<<NWG1 / 4, 256, 0, stream>>>(bgraw, bb, bgb, csbuf);
  k_chunk1<<<NWG1, 256, 0, stream>>>(kb16, vbuf, csbuf, Uvt, W_g);
  k_scanA<<<NGRP, 256, 0, stream>>>(kb16, W_g, Uvt, csbuf, Ag_g, Bg_g);
  k_scanB<<<NBH, 256, 0, stream>>>(Ag_g, Bg_g, Sg_g, out + (size_t)ROWS * D);
  k_scfuse<<<NGRP, 256, 0, stream>>>(kb16, W_g, Uvt, csbuf, Sg_g, outsb);
  k_gemm<1><<<dim3(ROWS / 128, D / 128), 256, 0, stream>>>(outsb, WoT, nullptr, nullptr, nullptr, out, x);
}

// Round 12
// 453.395 us; speedup vs baseline: 1.3706x; 1.0629x over previous
//
#include <hip/hip_runtime.h>
#include <hip/hip_bf16.h>

// GatedDeltaNet B=4 T=8192 D=768 H=12 K=V=64 — chunked WY + two-level scan.
// Round 12: chunk1 rebuilt as merged ladder (8 barriers, M resident in MFMA
// accumulators, K/V in regs); scanA drops SBc tile via C-seeded compose
// (48KB -> 3 blocks/CU). GEMMs/scfuse/scanB as round 11 (481.9us).

typedef __attribute__((ext_vector_type(8))) short short8;
typedef __attribute__((ext_vector_type(4))) float floatx4;

#define DEVFN static __device__ __forceinline__

typedef const __attribute__((address_space(1))) unsigned int* as1_u32p;
typedef __attribute__((address_space(3))) unsigned int* as3_u32p;

DEVFN void gll16(const void* g, void* l) {
  __builtin_amdgcn_global_load_lds((as1_u32p)g, (as3_u32p)l, 16, 0, 0);
}

DEVFN unsigned short f2bf_u(float f) {
  __hip_bfloat16 h = __float2bfloat16(f);
  return __builtin_bit_cast(unsigned short, h);
}
DEVFN float bf2f(unsigned short u) {
  return __bfloat162float(__builtin_bit_cast(__hip_bfloat16, u));
}

static constexpr int T_LEN = 8192;
static constexpr int ROWS  = 4 * 8192;   // 32768
static constexpr int D     = 768;
static constexpr int NKV   = 1664;
static constexpr int NC    = 128;        // chunks per sequence (C=64)
static constexpr int NBH   = 48;         // B*H
static constexpr int NWG1  = NBH * NC;   // 6144
static constexpr int NG    = 16;         // groups per bh (8 chunks each)
static constexpr int NGRP  = NBH * NG;   // 768
static constexpr int CSTR  = 192;        // csbuf: [0:64) incl, [64:128) excl, [128:192) beta

// ---- swizzled 64-col bf16 LDS tile helpers (row stride 128B, slot-XOR) ----
DEVFN int swz16(int row, int slot) {
  return (row << 7) + (((slot ^ (row & 7)) & 7) << 4);
}
DEVFN int swzE(int row, int col) {
  return (row << 7) + ((((col >> 3) ^ (row & 7)) & 7) << 4) + ((col & 7) << 1);
}
DEVFN void st_bf(char* base, int row, int col, float v) {
  *(unsigned short*)(base + swzE(row, col)) = f2bf_u(v);
}
DEVFN float ld_bf(const char* base, int row, int col) {
  return bf2f(*(const unsigned short*)(base + swzE(row, col)));
}
// D[16-band x 64] += A[band]·B^T over 64-col tiles (both swizzled)
DEVFN void mm16x64(const char* aB, const char* bB, int wv, int lane, floatx4 acc[4]) {
  #pragma unroll
  for (int ks = 0; ks < 2; ++ks) {
    short8 af = *(const short8*)(aB + swz16(wv * 16 + (lane & 15), ks * 4 + (lane >> 4)));
    #pragma unroll
    for (int t = 0; t < 4; ++t) {
      short8 bf = *(const short8*)(bB + swz16(t * 16 + (lane & 15), ks * 4 + (lane >> 4)));
      acc[t] = __builtin_amdgcn_mfma_f32_16x16x32_bf16(af, bf, acc[t], 0, 0, 0);
    }
  }
}

// ---------------- weight prep ----------------
__global__ void k_prep_wt(const float* __restrict__ Wk, const float* __restrict__ Wv,
                          const float* __restrict__ Wb, const float* __restrict__ Wg,
                          __hip_bfloat16* __restrict__ WT) {
  int idx = blockIdx.x * 256 + threadIdx.x;
  if (idx >= NKV * D) return;
  int n = idx / D, k = idx % D;
  float v;
  if (n < 768)       v = Wk[k * 768 + n];
  else if (n < 1536) v = Wv[k * 768 + (n - 768)];
  else if (n < 1548) v = Wb[k * 12 + (n - 1536)];
  else if (n < 1560) v = Wg[k * 12 + (n - 1548)];
  else               v = 0.f;
  WT[idx] = __float2bfloat16(v);
}

__global__ void k_prep_wo(const float* __restrict__ Wo, __hip_bfloat16* __restrict__ WoT) {
  int idx = blockIdx.x * 256 + threadIdx.x;
  int n = idx / D, k = idx % D;
  WoT[idx] = __float2bfloat16(Wo[k * 768 + n]);
}

// ---------------- RMSNorm ----------------
__global__ void k_rmsnorm(const float* __restrict__ x, const float* __restrict__ wn,
                          __hip_bfloat16* __restrict__ xn) {
  int wid  = (blockIdx.x << 2) + (threadIdx.x >> 6);
  int lane = threadIdx.x & 63;
  const float* xr = x + (size_t)wid * D;
  float4 a = *(const float4*)(xr + lane * 4);
  float4 b = *(const float4*)(xr + 256 + lane * 4);
  float4 c = *(const float4*)(xr + 512 + lane * 4);
  float ss = a.x*a.x + a.y*a.y + a.z*a.z + a.w*a.w
           + b.x*b.x + b.y*b.y + b.z*b.z + b.w*b.w
           + c.x*c.x + c.y*c.y + c.z*c.z + c.w*c.w;
  #pragma unroll
  for (int m = 1; m < 64; m <<= 1) ss += __shfl_xor(ss, m);
  float rs = rsqrtf(ss * (1.f / 768.f) + 1e-6f);
  float4 w0 = *(const float4*)(wn + lane * 4);
  float4 w1 = *(const float4*)(wn + 256 + lane * 4);
  float4 w2 = *(const float4*)(wn + 512 + lane * 4);
  unsigned short* xo = (unsigned short*)(xn + (size_t)wid * D);
  ushort4 u;
  u.x = f2bf_u(a.x*rs*w0.x); u.y = f2bf_u(a.y*rs*w0.y); u.z = f2bf_u(a.z*rs*w0.z); u.w = f2bf_u(a.w*rs*w0.w);
  *(ushort4*)(xo + lane * 4) = u;
  u.x = f2bf_u(b.x*rs*w1.x); u.y = f2bf_u(b.y*rs*w1.y); u.z = f2bf_u(b.z*rs*w1.z); u.w = f2bf_u(b.w*rs*w1.w);
  *(ushort4*)(xo + 256 + lane * 4) = u;
  u.x = f2bf_u(c.x*rs*w2.x); u.y = f2bf_u(c.y*rs*w2.y); u.z = f2bf_u(c.z*rs*w2.z); u.w = f2bf_u(c.w*rs*w2.w);
  *(ushort4*)(xo + 512 + lane * 4) = u;
}

// ---------------- bf16 MFMA GEMM, 128x128 tile, BK=64 dbuf prefetch ----------------
template <int EPI>
__global__ __launch_bounds__(256)
void k_gemm(const __hip_bfloat16* __restrict__ A, const __hip_bfloat16* __restrict__ Bt,
            __hip_bfloat16* __restrict__ Ck, __hip_bfloat16* __restrict__ Cv,
            float* __restrict__ Cbg, float* __restrict__ C0, const float* __restrict__ Xadd) {
  __shared__ __align__(16) unsigned short As[2][128 * 64];
  __shared__ __align__(16) unsigned short Bs[2][128 * 64];
  const int K = 768, NKT = 12;
  int tid = threadIdx.x, lane = tid & 63, w = tid >> 6;
  int wr = w >> 1, wc = w & 1;
  int bx = blockIdx.x;                     // 256 m-blocks = 8 XCD chunks of 32
  bx = (bx & 7) * 32 + (bx >> 3);
  int m0 = bx * 128, n0 = blockIdx.y * 128;
  floatx4 zero = {0.f, 0.f, 0.f, 0.f};
  floatx4 acc[4][4];
  #pragma unroll
  for (int i = 0; i < 4; ++i)
    #pragma unroll
    for (int j = 0; j < 4; ++j) acc[i][j] = zero;

  auto stage = [&](int buf, int kt) {
    #pragma unroll
    for (int it = 0; it < 4; ++it) {
      int L = it * 256 + tid;
      int r = L >> 3, s = L & 7, sg = s ^ (r & 7);
      gll16(A  + (size_t)(m0 + r) * K + kt * 64 + sg * 8, &As[buf][L * 8]);
      gll16(Bt + (size_t)(n0 + r) * K + kt * 64 + sg * 8, &Bs[buf][L * 8]);
    }
  };

  stage(0, 0);
  __syncthreads();
  int buf = 0;
  for (int kt = 0; kt < NKT; ++kt) {
    if (kt + 1 < NKT) stage(buf ^ 1, kt + 1);
    __builtin_amdgcn_s_setprio(1);
    #pragma unroll
    for (int ks = 0; ks < 2; ++ks) {
      int c = ks * 4 + (lane >> 4);
      short8 af[4], bfr[4];
      #pragma unroll
      for (int i = 0; i < 4; ++i) {
        int ri = wr * 64 + i * 16 + (lane & 15);
        af[i] = *(const short8*)&As[buf][ri * 64 + ((c ^ (ri & 7)) << 3)];
      }
      #pragma unroll
      for (int j = 0; j < 4; ++j) {
        int rj = wc * 64 + j * 16 + (lane & 15);
        bfr[j] = *(const short8*)&Bs[buf][rj * 64 + ((c ^ (rj & 7)) << 3)];
      }
      #pragma unroll
      for (int i = 0; i < 4; ++i)
        #pragma unroll
        for (int j = 0; j < 4; ++j)
          acc[i][j] = __builtin_amdgcn_mfma_f32_16x16x32_bf16(af[i], bfr[j], acc[i][j], 0, 0, 0);
    }
    __builtin_amdgcn_s_setprio(0);
    __syncthreads();              // drains vmcnt(0): next buffer complete
    buf ^= 1;
  }

  if constexpr (EPI == 0) {
    if (n0 < 768) {
      #pragma unroll
      for (int i = 0; i < 4; ++i) {
        #pragma unroll
        for (int r = 0; r < 4; ++r) {
          float ss = 0.f;
          #pragma unroll
          for (int j = 0; j < 4; ++j) { float t = acc[i][j][r]; ss = fmaf(t, t, ss); }
          ss += __shfl_xor(ss, 1); ss += __shfl_xor(ss, 2);
          ss += __shfl_xor(ss, 4); ss += __shfl_xor(ss, 8);
          float sc = 1.f / fmaxf(sqrtf(ss), 1e-12f);
          int mm = m0 + wr * 64 + i * 16 + (lane >> 4) * 4 + r;
          #pragma unroll
          for (int j = 0; j < 4; ++j) {
            int n = n0 + wc * 64 + j * 16 + (lane & 15);
            Ck[(size_t)mm * 768 + n] = __float2bfloat16(acc[i][j][r] * sc);
          }
        }
      }
    } else if (n0 < 1536) {
      #pragma unroll
      for (int i = 0; i < 4; ++i)
        #pragma unroll
        for (int j = 0; j < 4; ++j) {
          int n = n0 + wc * 64 + j * 16 + (lane & 15) - 768;
          #pragma unroll
          for (int r = 0; r < 4; ++r) {
            int mm = m0 + wr * 64 + i * 16 + (lane >> 4) * 4 + r;
            Cv[(size_t)mm * 768 + n] = __float2bfloat16(acc[i][j][r]);
          }
        }
    } else {
      #pragma unroll
      for (int i = 0; i < 4; ++i)
        #pragma unroll
        for (int j = 0; j < 4; ++j) {
          int n = n0 + wc * 64 + j * 16 + (lane & 15) - 1536;
          if (n < 24) {                     // only 24 live beta/g cols
            #pragma unroll
            for (int r = 0; r < 4; ++r) {
              int mm = m0 + wr * 64 + i * 16 + (lane >> 4) * 4 + r;
              Cbg[(size_t)mm * 128 + n] = acc[i][j][r];
            }
          }
        }
    }
  } else {
    #pragma unroll
    for (int i = 0; i < 4; ++i)
      #pragma unroll
      for (int j = 0; j < 4; ++j) {
        int n = n0 + wc * 64 + j * 16 + (lane & 15);
        #pragma unroll
        for (int r = 0; r < 4; ++r) {
          int mm = m0 + wr * 64 + i * 16 + (lane >> 4) * 4 + r;
          size_t o = (size_t)mm * 768 + n;
          C0[o] = Xadd[o] + acc[i][j][r];
        }
      }
  }
}

// ---------------- fused sigmoid + gate prefix ----------------
__global__ void k_gates2(const float* __restrict__ bgraw, const float* __restrict__ bb,
                         const float* __restrict__ bgb, float* __restrict__ csbuf) {
  int wid  = blockIdx.x * 4 + (threadIdx.x >> 6);   // bh*NC + ck
  int lane = threadIdx.x & 63;
  int bh = wid >> 7, ck = wid & 127;
  int b = bh / 12, h = bh % 12;
  size_t row0 = (size_t)b * T_LEN + (size_t)ck * 64;
  const float* br = bgraw + (row0 + lane) * 128;
  float bet = 1.f / (1.f + __expf(-(br[h] + bb[h])));
  float g   = 1.f / (1.f + __expf(-(br[12 + h] + bgb[h])));
  float lg = __log2f(g);
  float ci = lg;
  #pragma unroll
  for (int d = 1; d < 64; d <<= 1) { float t = __shfl_up(ci, d); if (lane >= d) ci += t; }
  csbuf[(size_t)wid * CSTR + lane] = ci;
  csbuf[(size_t)wid * CSTR + 64 + lane] = ci - lg;
  csbuf[(size_t)wid * CSTR + 128 + lane] = bet;
}

// ---------------- pass 1: per-chunk WY factors (Uv, W) — merged ladder ------
// Phases: Lbuild | P1 | {M2,P2} | {M3,P3} | {M4,P4} | {M5,P5t} | {T,RHS} | X.
// M carried in MFMA accumulators (macc) across stages; K/V in registers.
__global__ __launch_bounds__(256)
void k_chunk1(const __hip_bfloat16* __restrict__ kb16, const __hip_bfloat16* __restrict__ vbuf,
              const float* __restrict__ csbuf,
              __hip_bfloat16* __restrict__ Uvt_g, __hip_bfloat16* __restrict__ W_g) {
  __shared__ __align__(16) char sm[6 * 8192 + 768];
  char* SA = sm;
  char* SB = sm + 8192;   // SA,SB contiguous: RHST spans both in phase s6
  char* SC = sm + 2 * 8192;
  char* SD = sm + 3 * 8192;
  char* SE = sm + 4 * 8192;
  char* SF = sm + 5 * 8192;
  float* cs   = (float*)(sm + 6 * 8192);
  float* cps  = (float*)(sm + 6 * 8192 + 256);
  float* bets = (float*)(sm + 6 * 8192 + 512);

  int blk = blockIdx.x, bh = blk >> 7, ck = blk & 127;
  int b = bh / 12, h = bh % 12;
  int tid = threadIdx.x, lane = tid & 63, wv = tid >> 6;
  size_t row0 = (size_t)b * T_LEN + (size_t)ck * 64;
  size_t wbase = (size_t)blk * 4096;

  if (tid < 64) {
    cs[tid]   = csbuf[(size_t)blk * CSTR + tid];
    cps[tid]  = csbuf[(size_t)blk * CSTR + 64 + tid];
    bets[tid] = csbuf[(size_t)blk * CSTR + 128 + tid];
  }
  int sr = tid >> 2, sc0 = (tid & 3) * 16;
  short8 k0, k1, vreg0, vreg1;
  {
    const __hip_bfloat16* kp = kb16 + (row0 + sr) * 768 + h * 64 + sc0;
    k0 = *(const short8*)kp;
    k1 = *(const short8*)(kp + 8);
    *(short8*)(SA + swz16(sr, sc0 >> 3)) = k0;
    *(short8*)(SA + swz16(sr, (sc0 >> 3) + 1)) = k1;
    const __hip_bfloat16* vp = vbuf + (row0 + sr) * 768 + h * 64 + sc0;
    vreg0 = *(const short8*)vp;
    vreg1 = *(const short8*)(vp + 8);
  }
  __syncthreads();

  floatx4 acc[4], macc[4];
  auto zacc = [&] {
    #pragma unroll
    for (int t = 0; t < 4; ++t) acc[t] = (floatx4){0.f, 0.f, 0.f, 0.f};
  };
  auto stP = [&](char* Or, char* Ot) {          // store acc row+trans
    #pragma unroll
    for (int t = 0; t < 4; ++t)
      #pragma unroll
      for (int r = 0; r < 4; ++r) {
        int i = wv * 16 + (lane >> 4) * 4 + r, j = t * 16 + (lane & 15);
        st_bf(Or, i, j, acc[t][r]);
        st_bf(Ot, j, i, acc[t][r]);
      }
  };
  auto stM = [&](char* Or) {                    // store macc row-major
    #pragma unroll
    for (int t = 0; t < 4; ++t)
      #pragma unroll
      for (int r = 0; r < 4; ++r)
        st_bf(Or, wv * 16 + (lane >> 4) * 4 + r, t * 16 + (lane & 15), macc[t][r]);
  };

  // L-build: G = K K^T -> L row(SB), L trans(SC), M1 lds(SD) + macc=M1
  zacc(); mm16x64(SA, SA, wv, lane, acc);
  #pragma unroll
  for (int t = 0; t < 4; ++t)
    #pragma unroll
    for (int r = 0; r < 4; ++r) {
      int i = wv * 16 + (lane >> 4) * 4 + r, j = t * 16 + (lane & 15);
      float Lv = (j < i) ? bets[i] * exp2f(cps[i] - cs[j]) * acc[t][r] : 0.f;
      st_bf(SB, i, j, Lv);
      st_bf(SC, j, i, Lv);
      float m1 = ((i == j) ? 1.f : 0.f) - Lv;
      st_bf(SD, i, j, m1);
      macc[t][r] = m1;
    }
  __syncthreads();                              // B1
  // s1: P1 = L^2 -> SE,SF
  zacc(); mm16x64(SB, SC, wv, lane, acc);
  stP(SE, SF);
  __syncthreads();                              // B2
  // s2: M2 = M1 + M1*P1 (macc) -> SA ; P2 = P1^2 -> SB,SC
  mm16x64(SD, SF, wv, lane, macc); stM(SA);
  zacc(); mm16x64(SE, SF, wv, lane, acc); stP(SB, SC);
  __syncthreads();                              // B3
  // s3: M3 -> SD ; P3 -> SE,SF
  mm16x64(SA, SC, wv, lane, macc); stM(SD);
  zacc(); mm16x64(SB, SC, wv, lane, acc); stP(SE, SF);
  __syncthreads();                              // B4
  // s4: M4 -> SA ; P4 -> SB,SC
  mm16x64(SD, SF, wv, lane, macc); stM(SA);
  zacc(); mm16x64(SE, SF, wv, lane, acc); stP(SB, SC);
  __syncthreads();                              // B5
  // s5: M5 -> SD ; P5 trans only -> SF
  mm16x64(SA, SC, wv, lane, macc); stM(SD);
  zacc(); mm16x64(SB, SC, wv, lane, acc);
  #pragma unroll
  for (int t = 0; t < 4; ++t)
    #pragma unroll
    for (int r = 0; r < 4; ++r)
      st_bf(SF, t * 16 + (lane & 15), wv * 16 + (lane >> 4) * 4 + r, acc[t][r]);
  __syncthreads();                              // B6
  // s6: T = M5 + M5*P5 (macc) -> SE ; RHST(128x64) -> SA..SB
  mm16x64(SD, SF, wv, lane, macc); stM(SE);
  {
    float be = bets[sr];
    #pragma unroll
    for (int q = 0; q < 8; ++q) {
      st_bf(SA, sc0 + q,     sr, be * bf2f(((unsigned short*)&vreg0)[q]));
      st_bf(SA, sc0 + 8 + q, sr, be * bf2f(((unsigned short*)&vreg1)[q]));
    }
    float scl = be * exp2f(cps[sr]);
    #pragma unroll
    for (int q = 0; q < 8; ++q) {
      st_bf(SA, 64 + sc0 + q,     sr, scl * bf2f(((unsigned short*)&k0)[q]));
      st_bf(SA, 64 + sc0 + 8 + q, sr, scl * bf2f(((unsigned short*)&k1)[q]));
    }
  }
  __syncthreads();                              // B7
  // X = T(SE) * RHS -> Uvt to SF (trans); W^T rows to HBM ([k][j])
  {
    floatx4 xacc[8];
    #pragma unroll
    for (int t = 0; t < 8; ++t) xacc[t] = (floatx4){0.f, 0.f, 0.f, 0.f};
    #pragma unroll
    for (int ks = 0; ks < 2; ++ks) {
      short8 af = *(const short8*)(SE + swz16(wv * 16 + (lane & 15), ks * 4 + (lane >> 4)));
      #pragma unroll
      for (int t = 0; t < 8; ++t) {
        short8 bf = *(const short8*)(SA + swz16(t * 16 + (lane & 15), ks * 4 + (lane >> 4)));
        xacc[t] = __builtin_amdgcn_mfma_f32_16x16x32_bf16(af, bf, xacc[t], 0, 0, 0);
      }
    }
    #pragma unroll
    for (int t = 0; t < 8; ++t) {
      int c = t * 16 + (lane & 15);
      #pragma unroll
      for (int r = 0; r < 4; ++r) {
        int i = wv * 16 + (lane >> 4) * 4 + r;
        float v = xacc[t][r];
        if (c < 64) st_bf(SF, c, i, v);
        else        W_g[wbase + (size_t)(c - 64) * 64 + i] = __float2bfloat16(v);
      }
    }
  }
  __syncthreads();                              // B8
  {
    int s2 = (tid & 3) * 2;
    short8 a0 = *(const short8*)(SF + swz16(sr, s2));
    short8 a1 = *(const short8*)(SF + swz16(sr, s2 + 1));
    *(short8*)(Uvt_g + wbase + (size_t)sr * 64 + s2 * 8) = a0;
    *(short8*)(Uvt_g + wbase + (size_t)sr * 64 + s2 * 8 + 8) = a1;
  }
}

// ---------------- scan A: per-group (8 chunks) map composition ----------------
// Bc kept in accumulator regs (C-seed); SBc tile dropped -> 48KB, 3 blocks/CU.
__global__ __launch_bounds__(256)
void k_scanA(const __hip_bfloat16* __restrict__ kb16, const __hip_bfloat16* __restrict__ W_g,
             const __hip_bfloat16* __restrict__ Uvt_g, const float* __restrict__ csbuf,
             __hip_bfloat16* __restrict__ Ag_g, __hip_bfloat16* __restrict__ Bg_g) {
  __shared__ __align__(16) char sm[6 * 8192];
  char* SK  = sm;              // Ktil^T [k][t]
  char* SW  = sm + 8192;       // Wt [k][j]
  char* SU  = sm + 2 * 8192;   // Uvt [v][t]
  char* SAc = sm + 3 * 8192;   // Ac [ko][ki]
  char* SAt = sm + 4 * 8192;   // Aacc^T [ki][ko]
  char* SBa = sm + 5 * 8192;   // Bacc [v][k]

  int blk = blockIdx.x, bh = blk >> 4, gg = blk & 15;
  int b = bh / 12, h = bh % 12;
  int tid = threadIdx.x, lane = tid & 63, wv = tid >> 6;
  int sr = tid >> 2, sc0 = (tid & 3) * 16, s2 = (tid & 3) * 2;
  int c0 = gg * 8;

  short8 z = {0, 0, 0, 0, 0, 0, 0, 0};
  *(short8*)(SAt + swz16(sr, s2)) = z;
  *(short8*)(SAt + swz16(sr, s2 + 1)) = z;
  *(short8*)(SBa + swz16(sr, s2)) = z;
  *(short8*)(SBa + swz16(sr, s2 + 1)) = z;
  __syncthreads();
  if (tid < 64) st_bf(SAt, tid, tid, 1.f);   // Aacc = I

  floatx4 acc[4], bcacc[4];
  auto zacc = [&] {
    #pragma unroll
    for (int t = 0; t < 4; ++t) acc[t] = (floatx4){0.f, 0.f, 0.f, 0.f};
  };

  for (int cc = 0; cc < 8; ++cc) {
    int c = c0 + cc;
    size_t row0 = (size_t)b * T_LEN + (size_t)c * 64;
    size_t wb = ((size_t)bh * NC + c) * 4096;
    const float* csb = csbuf + (size_t)(bh * NC + c) * CSTR;
    float cs_sr = csb[sr], cs63 = csb[63];
    const __hip_bfloat16* kp = kb16 + (row0 + sr) * 768 + h * 64 + sc0;
    short8 k0 = *(const short8*)kp, k1 = *(const short8*)(kp + 8);
    const __hip_bfloat16* wp = W_g + wb + (size_t)sr * 64 + s2 * 8;
    short8 w0 = *(const short8*)wp, w1 = *(const short8*)(wp + 8);
    const __hip_bfloat16* up = Uvt_g + wb + (size_t)sr * 64 + s2 * 8;
    short8 u0 = *(const short8*)up, u1 = *(const short8*)(up + 8);
    // stage
    float scl = exp2f(cs63 - cs_sr);
    #pragma unroll
    for (int q = 0; q < 8; ++q) {
      st_bf(SK, sc0 + q,     sr, scl * bf2f(((unsigned short*)&k0)[q]));
      st_bf(SK, sc0 + 8 + q, sr, scl * bf2f(((unsigned short*)&k1)[q]));
    }
    *(short8*)(SW + swz16(sr, s2)) = w0;
    *(short8*)(SW + swz16(sr, s2 + 1)) = w1;
    *(short8*)(SU + swz16(sr, s2)) = u0;
    *(short8*)(SU + swz16(sr, s2 + 1)) = u1;
    __syncthreads();   // (a) staged; prev compose's SAc reads done
    float gC = exp2f(cs63);
    // Bc in regs (C-seed for compose); Ac trans -> SAc
    #pragma unroll
    for (int t = 0; t < 4; ++t) bcacc[t] = (floatx4){0.f, 0.f, 0.f, 0.f};
    mm16x64(SU, SK, wv, lane, bcacc);
    zacc(); mm16x64(SW, SK, wv, lane, acc);
    #pragma unroll
    for (int t = 0; t < 4; ++t)
      #pragma unroll
      for (int r = 0; r < 4; ++r) {
        int i = wv * 16 + (lane >> 4) * 4 + r, j = t * 16 + (lane & 15);
        st_bf(SAc, j, i, ((i == j) ? gC : 0.f) - acc[t][r]);
      }
    __syncthreads();   // (b) Ac ready
    // compose in place (A-operand rows are wave-private)
    zacc(); mm16x64(SAt, SAc, wv, lane, acc);
    #pragma unroll
    for (int t = 0; t < 4; ++t)
      #pragma unroll
      for (int r = 0; r < 4; ++r)
        st_bf(SAt, wv * 16 + (lane >> 4) * 4 + r, t * 16 + (lane & 15), acc[t][r]);
    mm16x64(SBa, SAc, wv, lane, bcacc);   // Bacc*Ac + Bc
    #pragma unroll
    for (int t = 0; t < 4; ++t)
      #pragma unroll
      for (int r = 0; r < 4; ++r)
        st_bf(SBa, wv * 16 + (lane >> 4) * 4 + r, t * 16 + (lane & 15), bcacc[t][r]);
  }
  __syncthreads();
  // Ag rows [ko][ki] (scatter-transpose from SAt), Bg rows [v][k] (vector)
  size_t gb = (size_t)blk * 4096;
  #pragma unroll
  for (int q = 0; q < 16; ++q)
    Ag_g[gb + (size_t)(sc0 + q) * 64 + sr] = __float2bfloat16(ld_bf(SAt, sr, sc0 + q));
  {
    short8 b0 = *(const short8*)(SBa + swz16(sr, s2));
    short8 b1 = *(const short8*)(SBa + swz16(sr, s2 + 1));
    *(short8*)(Bg_g + gb + (size_t)sr * 64 + s2 * 8) = b0;
    *(short8*)(Bg_g + gb + (size_t)sr * 64 + s2 * 8 + 8) = b1;
  }
}

// ---------------- scan B: 16 serial group composes ----------------
__global__ __launch_bounds__(256)
void k_scanB(const __hip_bfloat16* __restrict__ Ag_g, const __hip_bfloat16* __restrict__ Bg_g,
             __hip_bfloat16* __restrict__ Sg_g, float* __restrict__ fstate) {
  __shared__ __align__(16) char sm[3 * 8192];
  char* SSt = sm;
  char* SAg = sm + 8192;
  char* SBg = sm + 2 * 8192;
  int bh = blockIdx.x;
  int tid = threadIdx.x, lane = tid & 63, wv = tid >> 6;
  int sr = tid >> 2, s2 = (tid & 3) * 2;

  short8 z = {0, 0, 0, 0, 0, 0, 0, 0};
  *(short8*)(SSt + swz16(sr, s2)) = z;
  *(short8*)(SSt + swz16(sr, s2 + 1)) = z;

  floatx4 acc[4];
  for (int g = 0; g < NG; ++g) {
    size_t gb = ((size_t)bh * NG + g) * 4096;
    const __hip_bfloat16* pa = Ag_g + gb + (size_t)sr * 64 + s2 * 8;
    short8 a0 = *(const short8*)pa, a1 = *(const short8*)(pa + 8);
    const __hip_bfloat16* pb = Bg_g + gb + (size_t)sr * 64 + s2 * 8;
    short8 b0 = *(const short8*)pb, b1 = *(const short8*)(pb + 8);
    __syncthreads();             // SSt stable; prev compose's SAg/SBg reads done
    {  // write group-start state
      short8 s0 = *(const short8*)(SSt + swz16(sr, s2));
      short8 s1 = *(const short8*)(SSt + swz16(sr, s2 + 1));
      *(short8*)(Sg_g + gb + (size_t)sr * 64 + s2 * 8) = s0;
      *(short8*)(Sg_g + gb + (size_t)sr * 64 + s2 * 8 + 8) = s1;
    }
    *(short8*)(SAg + swz16(sr, s2)) = a0;
    *(short8*)(SAg + swz16(sr, s2 + 1)) = a1;
    *(short8*)(SBg + swz16(sr, s2)) = b0;
    *(short8*)(SBg + swz16(sr, s2 + 1)) = b1;
    __syncthreads();
    #pragma unroll
    for (int t = 0; t < 4; ++t) acc[t] = (floatx4){0.f, 0.f, 0.f, 0.f};
    mm16x64(SSt, SAg, wv, lane, acc);
    #pragma unroll
    for (int t = 0; t < 4; ++t) {
      int j = t * 16 + (lane & 15);
      #pragma unroll
      for (int r = 0; r < 4; ++r) {
        int i = wv * 16 + (lane >> 4) * 4 + r;
        float val = acc[t][r] + ld_bf(SBg, i, j);
        st_bf(SSt, i, j, val);
        if (g == NG - 1) fstate[(size_t)bh * 4096 + (size_t)j * 64 + i] = val;
      }
    }
  }
}

// ---------------- fused scan C + outputs (Ueff compose, 4 barriers/iter) ----
__global__ __launch_bounds__(256)
void k_scfuse(const __hip_bfloat16* __restrict__ kb16, const __hip_bfloat16* __restrict__ W_g,
              const __hip_bfloat16* __restrict__ Uvt_g, const float* __restrict__ csbuf,
              const __hip_bfloat16* __restrict__ Sg_g, __hip_bfloat16* __restrict__ outs) {
  __shared__ __align__(16) char sm[6 * 8192];
  char* SSt = sm;              // state [v][k]
  char* SKr = sm + 8192;       // raw K [t][k]; last phase: out bounce [t][v]
  char* SKt = sm + 2 * 8192;   // Ktil^T [k][t]
  char* SG  = sm + 3 * 8192;   // scaled G [t][t']
  char* SW2 = sm + 4 * 8192;   // W row-major [t][k]
  char* SU  = sm + 5 * 8192;   // Uvt [v][t] -> Ueff

  int blk = blockIdx.x, bh = blk >> 4, gg = blk & 15;
  int b = bh / 12, h = bh % 12;
  int tid = threadIdx.x, lane = tid & 63, wv = tid >> 6;
  int sr = tid >> 2, sc0 = (tid & 3) * 16, s2 = (tid & 3) * 2;
  int c0 = gg * 8;
  int iR0 = wv * 16 + (lane >> 4) * 4;

  {
    const __hip_bfloat16* sp = Sg_g + (size_t)blk * 4096 + (size_t)sr * 64 + s2 * 8;
    short8 s0 = *(const short8*)sp, s1 = *(const short8*)(sp + 8);
    *(short8*)(SSt + swz16(sr, s2)) = s0;
    *(short8*)(SSt + swz16(sr, s2 + 1)) = s1;
  }

  floatx4 acc[4], pAcc[4];
  auto zacc = [&] {
    #pragma unroll
    for (int t = 0; t < 4; ++t) acc[t] = (floatx4){0.f, 0.f, 0.f, 0.f};
  };
  auto forRC = [&](auto&& f) {
    #pragma unroll
    for (int t = 0; t < 4; ++t)
      #pragma unroll
      for (int r = 0; r < 4; ++r)
        f(iR0 + r, t * 16 + (lane & 15), acc[t][r]);
  };

  for (int cc = 0; cc < 8; ++cc) {
    int c = c0 + cc;
    size_t row0 = (size_t)b * T_LEN + (size_t)c * 64;
    size_t wb = ((size_t)bh * NC + c) * 4096;
    const float* csb = csbuf + (size_t)(bh * NC + c) * CSTR;
    float cs_sr = csb[sr], cs63 = csb[63];
    float csI[4], csJ[4];
    #pragma unroll
    for (int r = 0; r < 4; ++r) csI[r] = csb[iR0 + r];
    #pragma unroll
    for (int t = 0; t < 4; ++t) csJ[t] = csb[t * 16 + (lane & 15)];
    const __hip_bfloat16* kp = kb16 + (row0 + sr) * 768 + h * 64 + sc0;
    short8 k0 = *(const short8*)kp, k1 = *(const short8*)(kp + 8);
    const __hip_bfloat16* wp = W_g + wb + (size_t)sr * 64 + sc0;
    short8 w0 = *(const short8*)wp, w1 = *(const short8*)(wp + 8);
    const __hip_bfloat16* up = Uvt_g + wb + (size_t)sr * 64 + sc0;
    short8 u0 = *(const short8*)up, u1 = *(const short8*)(up + 8);
    __syncthreads();             // bar A: prev iter's bounce-read + compose done
    // stage 4 tiles
    *(short8*)(SKr + swz16(sr, sc0 >> 3)) = k0;
    *(short8*)(SKr + swz16(sr, (sc0 >> 3) + 1)) = k1;
    {
      float scl = exp2f(cs63 - cs_sr);
      #pragma unroll
      for (int q = 0; q < 8; ++q) {
        st_bf(SKt, sc0 + q,     sr, scl * bf2f(((unsigned short*)&k0)[q]));
        st_bf(SKt, sc0 + 8 + q, sr, scl * bf2f(((unsigned short*)&k1)[q]));
      }
    }
    #pragma unroll
    for (int q = 0; q < 8; ++q) {          // W row-major [j][k] from Wt rows
      st_bf(SW2, sc0 + q,     sr, bf2f(((unsigned short*)&w0)[q]));
      st_bf(SW2, sc0 + 8 + q, sr, bf2f(((unsigned short*)&w1)[q]));
    }
    *(short8*)(SU + swz16(sr, s2)) = u0;
    *(short8*)(SU + swz16(sr, s2 + 1)) = u1;
    __syncthreads();             // bar B: staged
    // G (scaled, lower-tri), P = K·S0^T (regs), Ueff = Uv − S0·W^T (in place)
    zacc(); mm16x64(SKr, SKr, wv, lane, acc);
    #pragma unroll
    for (int t = 0; t < 4; ++t) {
      int j = t * 16 + (lane & 15);
      #pragma unroll
      for (int r = 0; r < 4; ++r) {
        int i = iR0 + r;
        float gs = (j <= i) ? exp2f(csI[r] - csJ[t]) * acc[t][r] : 0.f;
        st_bf(SG, i, j, gs);
      }
    }
    #pragma unroll
    for (int t = 0; t < 4; ++t) pAcc[t] = (floatx4){0.f, 0.f, 0.f, 0.f};
    mm16x64(SKr, SSt, wv, lane, pAcc);
    zacc(); mm16x64(SSt, SW2, wv, lane, acc);
    forRC([&](int i, int j, float v) { st_bf(SU, i, j, ld_bf(SU, i, j) - v); });
    __syncthreads();             // bar C: G, Ueff final; SKr free
    // O2 = G·Ueff -> out bounce in SKr; compose S' = gC·S + Ueff·Ktil
    zacc(); mm16x64(SG, SU, wv, lane, acc);
    #pragma unroll
    for (int t = 0; t < 4; ++t) {
      int vc = t * 16 + (lane & 15);
      #pragma unroll
      for (int r = 0; r < 4; ++r) {
        int i = iR0 + r;
        float o = exp2f(csI[r]) * pAcc[t][r] + acc[t][r];
        st_bf(SKr, i, vc, o);
      }
    }
    if (cc < 7) {
      float gC = exp2f(cs63);
      zacc(); mm16x64(SU, SKt, wv, lane, acc);
      forRC([&](int i, int j, float v) { st_bf(SSt, i, j, gC * ld_bf(SSt, i, j) + v); });
    }
    __syncthreads();             // bar D: bounce + state ready
    {
      short8 a0 = *(const short8*)(SKr + swz16(sr, s2));
      short8 a1 = *(const short8*)(SKr + swz16(sr, s2 + 1));
      __hip_bfloat16* op = outs + (row0 + sr) * 768 + h * 64 + s2 * 8;
      *(short8*)op = a0;
      *(short8*)(op + 8) = a1;
    }
  }
}

// ---------------- host glue ----------------
extern "C" void kernel_launch(void* const* d_in, const int* in_sizes, int n_in,
                              void* d_out, int out_size, void* d_ws, size_t ws_size,
                              hipStream_t stream) {
  (void)in_sizes; (void)n_in; (void)out_size; (void)ws_size;
  const float* x   = (const float*)d_in[0];
  const float* wn  = (const float*)d_in[1];
  const float* Wk  = (const float*)d_in[2];
  const float* Wv  = (const float*)d_in[3];
  const float* Wo  = (const float*)d_in[4];
  const float* Wb  = (const float*)d_in[5];
  const float* bb  = (const float*)d_in[6];
  const float* Wg  = (const float*)d_in[7];
  const float* bgb = (const float*)d_in[8];
  float* out = (float*)d_out;

  char* ws = (char*)d_ws;
  size_t off = 0;
  const size_t TILE = (size_t)NWG1 * 4096 * 2;           // 50.3 MB
  const size_t GTILE = (size_t)NGRP * 4096 * 2;          // 6.3 MB
  // slot1: xn (dead after gemm<0>) ∪ Uvt_g (chunk1 -> scanA/scfuse)
  __hip_bfloat16* xn   = (__hip_bfloat16*)(ws + off);
  __hip_bfloat16* Uvt  = (__hip_bfloat16*)(ws + off); off += TILE;
  __hip_bfloat16* WT   = (__hip_bfloat16*)(ws + off); off += (size_t)NKV * D * 2;
  __hip_bfloat16* WoT  = (__hip_bfloat16*)(ws + off); off += (size_t)D * D * 2;
  __hip_bfloat16* kb16 = (__hip_bfloat16*)(ws + off); off += (size_t)ROWS * D * 2;
  // slot3: vbuf (dead after chunk1) ∪ outs (scfuse -> gemm<1>)
  __hip_bfloat16* vbuf = (__hip_bfloat16*)(ws + off);
  __hip_bfloat16* outsb= (__hip_bfloat16*)(ws + off); off += TILE;
  // slot4: bgraw (dead after gates2) ∪ [Ag|Bg|Sg|W_g]
  float* bgraw         = (float*)(ws + off);
  __hip_bfloat16* Ag_g = (__hip_bfloat16*)(ws + off);
  __hip_bfloat16* Bg_g = Ag_g + (size_t)NGRP * 4096;
  __hip_bfloat16* Sg_g = Bg_g + (size_t)NGRP * 4096;
  __hip_bfloat16* W_g  = Sg_g + (size_t)NGRP * 4096;
  off += 3 * GTILE + TILE;                               // 69.2 MB slot
  float* csbuf         = (float*)(ws + off);          off += (size_t)NWG1 * CSTR * 4;
  // total ~229 MiB

  k_prep_wt<<<(NKV * D + 255) / 256, 256, 0, stream>>>(Wk, Wv, Wb, Wg, WT);
  k_prep_wo<<<(D * D) / 256, 256, 0, stream>>>(Wo, WoT);
  k_rmsnorm<<<ROWS / 4, 256, 0, stream>>>(x, wn, xn);
  k_gemm<0><<<dim3(ROWS / 128, NKV / 128), 256, 0, stream>>>(xn, WT, kb16, vbuf, bgraw, nullptr, nullptr);
  k_gates2<<<NWG1 / 4, 256, 0, stream>>>(bgraw, bb, bgb, csbuf);
  k_chunk1<<<NWG1, 256, 0, stream>>>(kb16, vbuf, csbuf, Uvt, W_g);
  k_scanA<<<NGRP, 256, 0, stream>>>(kb16, W_g, Uvt, csbuf, Ag_g, Bg_g);
  k_scanB<<<NBH, 256, 0, stream>>>(Ag_g, Bg_g, Sg_g, out + (size_t)ROWS * D);
  k_scfuse<<<NGRP, 256, 0, stream>>>(kb16, W_g, Uvt, csbuf, Sg_g, outsb);
  k_gemm<1><<<dim3(ROWS / 128, D / 128), 256, 0, stream>>>(outsb, WoT, nullptr, nullptr, nullptr, out, x);
}

// Round 13
// 444.873 us; speedup vs baseline: 1.3969x; 1.0192x over previous
//
#include <hip/hip_runtime.h>
#include <hip/hip_bf16.h>

// GatedDeltaNet B=4 T=8192 D=768 H=12 K=V=64 — chunked WY + two-level scan.
// Round 13: coalesced LDS-tiled weight transposes (k_prep_tr); gates2 folded
// into chunk1 (csbuf stride 64, written by chunk1); T14 async-stage prefetch
// in scfuse/scanA. GEMMs + chunk1 ladder + scanB as round 12 (453.4us).

typedef __attribute__((ext_vector_type(8))) short short8;
typedef __attribute__((ext_vector_type(4))) float floatx4;

#define DEVFN static __device__ __forceinline__

typedef const __attribute__((address_space(1))) unsigned int* as1_u32p;
typedef __attribute__((address_space(3))) unsigned int* as3_u32p;

DEVFN void gll16(const void* g, void* l) {
  __builtin_amdgcn_global_load_lds((as1_u32p)g, (as3_u32p)l, 16, 0, 0);
}

DEVFN unsigned short f2bf_u(float f) {
  __hip_bfloat16 h = __float2bfloat16(f);
  return __builtin_bit_cast(unsigned short, h);
}
DEVFN float bf2f(unsigned short u) {
  return __bfloat162float(__builtin_bit_cast(__hip_bfloat16, u));
}

static constexpr int T_LEN = 8192;
static constexpr int ROWS  = 4 * 8192;   // 32768
static constexpr int D     = 768;
static constexpr int NKV   = 1664;
static constexpr int NC    = 128;        // chunks per sequence (C=64)
static constexpr int NBH   = 48;         // B*H
static constexpr int NWG1  = NBH * NC;   // 6144
static constexpr int NG    = 16;         // groups per bh (8 chunks each)
static constexpr int NGRP  = NBH * NG;   // 768

// ---- swizzled 64-col bf16 LDS tile helpers (row stride 128B, slot-XOR) ----
DEVFN int swz16(int row, int slot) {
  return (row << 7) + (((slot ^ (row & 7)) & 7) << 4);
}
DEVFN int swzE(int row, int col) {
  return (row << 7) + ((((col >> 3) ^ (row & 7)) & 7) << 4) + ((col & 7) << 1);
}
DEVFN void st_bf(char* base, int row, int col, float v) {
  *(unsigned short*)(base + swzE(row, col)) = f2bf_u(v);
}
DEVFN float ld_bf(const char* base, int row, int col) {
  return bf2f(*(const unsigned short*)(base + swzE(row, col)));
}
// D[16-band x 64] += A[band]·B^T over 64-col tiles (both swizzled)
DEVFN void mm16x64(const char* aB, const char* bB, int wv, int lane, floatx4 acc[4]) {
  #pragma unroll
  for (int ks = 0; ks < 2; ++ks) {
    short8 af = *(const short8*)(aB + swz16(wv * 16 + (lane & 15), ks * 4 + (lane >> 4)));
    #pragma unroll
    for (int t = 0; t < 4; ++t) {
      short8 bf = *(const short8*)(bB + swz16(t * 16 + (lane & 15), ks * 4 + (lane >> 4)));
      acc[t] = __builtin_amdgcn_mfma_f32_16x16x32_bf16(af, bf, acc[t], 0, 0, 0);
    }
  }
}

// ---------------- weight prep: coalesced 64x64 LDS-tiled transpose ----------
// S [768][768] fp32 row-major -> Dst[n][k] bf16 (Dst = S^T).
__global__ void k_prep_tr(const float* __restrict__ S, __hip_bfloat16* __restrict__ Dst) {
  __shared__ float ld[64][65];
  int bx = blockIdx.x % 12, by = blockIdx.x / 12;
  int k0 = bx * 64, n0 = by * 64;
  int tid = threadIdx.x;
  int row = tid >> 2, c0 = (tid & 3) * 16;
  #pragma unroll
  for (int q = 0; q < 4; ++q) {
    float4 v = *(const float4*)&S[(size_t)(k0 + row) * 768 + n0 + c0 + q * 4];
    ld[row][c0 + q * 4 + 0] = v.x; ld[row][c0 + q * 4 + 1] = v.y;
    ld[row][c0 + q * 4 + 2] = v.z; ld[row][c0 + q * 4 + 3] = v.w;
  }
  __syncthreads();
  int nr = tid >> 2, kc = (tid & 3) * 16;
  unsigned short* op = (unsigned short*)Dst + (size_t)(n0 + nr) * 768 + k0 + kc;
  #pragma unroll
  for (int e4 = 0; e4 < 4; ++e4) {
    ushort4 u;
    u.x = f2bf_u(ld[kc + e4 * 4 + 0][nr]);
    u.y = f2bf_u(ld[kc + e4 * 4 + 1][nr]);
    u.z = f2bf_u(ld[kc + e4 * 4 + 2][nr]);
    u.w = f2bf_u(ld[kc + e4 * 4 + 3][nr]);
    *(ushort4*)(op + e4 * 4) = u;
  }
}

// tail: WT rows 1536..1663 (Wb cols, Wg cols, zero pad)
__global__ void k_prep_tail(const float* __restrict__ Wb, const float* __restrict__ Wg,
                            __hip_bfloat16* __restrict__ WT) {
  int idx = blockIdx.x * 256 + threadIdx.x;   // [0, 128*768)
  if (idx >= 128 * 768) return;
  int n = idx / 768 + 1536, k = idx % 768;
  float v = 0.f;
  if (n < 1548)      v = Wb[k * 12 + (n - 1536)];
  else if (n < 1560) v = Wg[k * 12 + (n - 1548)];
  WT[(size_t)n * 768 + k] = __float2bfloat16(v);
}

// ---------------- RMSNorm ----------------
__global__ void k_rmsnorm(const float* __restrict__ x, const float* __restrict__ wn,
                          __hip_bfloat16* __restrict__ xn) {
  int wid  = (blockIdx.x << 2) + (threadIdx.x >> 6);
  int lane = threadIdx.x & 63;
  const float* xr = x + (size_t)wid * D;
  float4 a = *(const float4*)(xr + lane * 4);
  float4 b = *(const float4*)(xr + 256 + lane * 4);
  float4 c = *(const float4*)(xr + 512 + lane * 4);
  float ss = a.x*a.x + a.y*a.y + a.z*a.z + a.w*a.w
           + b.x*b.x + b.y*b.y + b.z*b.z + b.w*b.w
           + c.x*c.x + c.y*c.y + c.z*c.z + c.w*c.w;
  #pragma unroll
  for (int m = 1; m < 64; m <<= 1) ss += __shfl_xor(ss, m);
  float rs = rsqrtf(ss * (1.f / 768.f) + 1e-6f);
  float4 w0 = *(const float4*)(wn + lane * 4);
  float4 w1 = *(const float4*)(wn + 256 + lane * 4);
  float4 w2 = *(const float4*)(wn + 512 + lane * 4);
  unsigned short* xo = (unsigned short*)(xn + (size_t)wid * D);
  ushort4 u;
  u.x = f2bf_u(a.x*rs*w0.x); u.y = f2bf_u(a.y*rs*w0.y); u.z = f2bf_u(a.z*rs*w0.z); u.w = f2bf_u(a.w*rs*w0.w);
  *(ushort4*)(xo + lane * 4) = u;
  u.x = f2bf_u(b.x*rs*w1.x); u.y = f2bf_u(b.y*rs*w1.y); u.z = f2bf_u(b.z*rs*w1.z); u.w = f2bf_u(b.w*rs*w1.w);
  *(ushort4*)(xo + 256 + lane * 4) = u;
  u.x = f2bf_u(c.x*rs*w2.x); u.y = f2bf_u(c.y*rs*w2.y); u.z = f2bf_u(c.z*rs*w2.z); u.w = f2bf_u(c.w*rs*w2.w);
  *(ushort4*)(xo + 512 + lane * 4) = u;
}

// ---------------- bf16 MFMA GEMM, 128x128 tile, BK=64 dbuf prefetch ----------------
template <int EPI>
__global__ __launch_bounds__(256)
void k_gemm(const __hip_bfloat16* __restrict__ A, const __hip_bfloat16* __restrict__ Bt,
            __hip_bfloat16* __restrict__ Ck, __hip_bfloat16* __restrict__ Cv,
            float* __restrict__ Cbg, float* __restrict__ C0, const float* __restrict__ Xadd) {
  __shared__ __align__(16) unsigned short As[2][128 * 64];
  __shared__ __align__(16) unsigned short Bs[2][128 * 64];
  const int K = 768, NKT = 12;
  int tid = threadIdx.x, lane = tid & 63, w = tid >> 6;
  int wr = w >> 1, wc = w & 1;
  int bx = blockIdx.x;                     // 256 m-blocks = 8 XCD chunks of 32
  bx = (bx & 7) * 32 + (bx >> 3);
  int m0 = bx * 128, n0 = blockIdx.y * 128;
  floatx4 zero = {0.f, 0.f, 0.f, 0.f};
  floatx4 acc[4][4];
  #pragma unroll
  for (int i = 0; i < 4; ++i)
    #pragma unroll
    for (int j = 0; j < 4; ++j) acc[i][j] = zero;

  auto stage = [&](int buf, int kt) {
    #pragma unroll
    for (int it = 0; it < 4; ++it) {
      int L = it * 256 + tid;
      int r = L >> 3, s = L & 7, sg = s ^ (r & 7);
      gll16(A  + (size_t)(m0 + r) * K + kt * 64 + sg * 8, &As[buf][L * 8]);
      gll16(Bt + (size_t)(n0 + r) * K + kt * 64 + sg * 8, &Bs[buf][L * 8]);
    }
  };

  stage(0, 0);
  __syncthreads();
  int buf = 0;
  for (int kt = 0; kt < NKT; ++kt) {
    if (kt + 1 < NKT) stage(buf ^ 1, kt + 1);
    __builtin_amdgcn_s_setprio(1);
    #pragma unroll
    for (int ks = 0; ks < 2; ++ks) {
      int c = ks * 4 + (lane >> 4);
      short8 af[4], bfr[4];
      #pragma unroll
      for (int i = 0; i < 4; ++i) {
        int ri = wr * 64 + i * 16 + (lane & 15);
        af[i] = *(const short8*)&As[buf][ri * 64 + ((c ^ (ri & 7)) << 3)];
      }
      #pragma unroll
      for (int j = 0; j < 4; ++j) {
        int rj = wc * 64 + j * 16 + (lane & 15);
        bfr[j] = *(const short8*)&Bs[buf][rj * 64 + ((c ^ (rj & 7)) << 3)];
      }
      #pragma unroll
      for (int i = 0; i < 4; ++i)
        #pragma unroll
        for (int j = 0; j < 4; ++j)
          acc[i][j] = __builtin_amdgcn_mfma_f32_16x16x32_bf16(af[i], bfr[j], acc[i][j], 0, 0, 0);
    }
    __builtin_amdgcn_s_setprio(0);
    __syncthreads();              // drains vmcnt(0): next buffer complete
    buf ^= 1;
  }

  if constexpr (EPI == 0) {
    if (n0 < 768) {
      #pragma unroll
      for (int i = 0; i < 4; ++i) {
        #pragma unroll
        for (int r = 0; r < 4; ++r) {
          float ss = 0.f;
          #pragma unroll
          for (int j = 0; j < 4; ++j) { float t = acc[i][j][r]; ss = fmaf(t, t, ss); }
          ss += __shfl_xor(ss, 1); ss += __shfl_xor(ss, 2);
          ss += __shfl_xor(ss, 4); ss += __shfl_xor(ss, 8);
          float sc = 1.f / fmaxf(sqrtf(ss), 1e-12f);
          int mm = m0 + wr * 64 + i * 16 + (lane >> 4) * 4 + r;
          #pragma unroll
          for (int j = 0; j < 4; ++j) {
            int n = n0 + wc * 64 + j * 16 + (lane & 15);
            Ck[(size_t)mm * 768 + n] = __float2bfloat16(acc[i][j][r] * sc);
          }
        }
      }
    } else if (n0 < 1536) {
      #pragma unroll
      for (int i = 0; i < 4; ++i)
        #pragma unroll
        for (int j = 0; j < 4; ++j) {
          int n = n0 + wc * 64 + j * 16 + (lane & 15) - 768;
          #pragma unroll
          for (int r = 0; r < 4; ++r) {
            int mm = m0 + wr * 64 + i * 16 + (lane >> 4) * 4 + r;
            Cv[(size_t)mm * 768 + n] = __float2bfloat16(acc[i][j][r]);
          }
        }
    } else {
      #pragma unroll
      for (int i = 0; i < 4; ++i)
        #pragma unroll
        for (int j = 0; j < 4; ++j) {
          int n = n0 + wc * 64 + j * 16 + (lane & 15) - 1536;
          if (n < 24) {                     // only 24 live beta/g cols
            #pragma unroll
            for (int r = 0; r < 4; ++r) {
              int mm = m0 + wr * 64 + i * 16 + (lane >> 4) * 4 + r;
              Cbg[(size_t)mm * 128 + n] = acc[i][j][r];
            }
          }
        }
    }
  } else {
    #pragma unroll
    for (int i = 0; i < 4; ++i)
      #pragma unroll
      for (int j = 0; j < 4; ++j) {
        int n = n0 + wc * 64 + j * 16 + (lane & 15);
        #pragma unroll
        for (int r = 0; r < 4; ++r) {
          int mm = m0 + wr * 64 + i * 16 + (lane >> 4) * 4 + r;
          size_t o = (size_t)mm * 768 + n;
          C0[o] = Xadd[o] + acc[i][j][r];
        }
      }
  }
}

// ---------------- pass 1: per-chunk WY factors (Uv, W) — merged ladder ------
// gates folded in: wave0 computes beta/g sigmoid + log2 prefix from bgraw,
// publishes incl prefix to csbuf (stride 64) for scanA/scfuse.
__global__ __launch_bounds__(256)
void k_chunk1(const __hip_bfloat16* __restrict__ kb16, const __hip_bfloat16* __restrict__ vbuf,
              const float* __restrict__ bgraw, const float* __restrict__ bb,
              const float* __restrict__ bgb, float* __restrict__ csbuf,
              __hip_bfloat16* __restrict__ Uvt_g, __hip_bfloat16* __restrict__ W_g) {
  __shared__ __align__(16) char sm[6 * 8192 + 768];
  char* SA = sm;
  char* SB = sm + 8192;   // SA,SB contiguous: RHST spans both in phase s6
  char* SC = sm + 2 * 8192;
  char* SD = sm + 3 * 8192;
  char* SE = sm + 4 * 8192;
  char* SF = sm + 5 * 8192;
  float* cs   = (float*)(sm + 6 * 8192);
  float* cps  = (float*)(sm + 6 * 8192 + 256);
  float* bets = (float*)(sm + 6 * 8192 + 512);

  int blk = blockIdx.x, bh = blk >> 7, ck = blk & 127;
  int b = bh / 12, h = bh % 12;
  int tid = threadIdx.x, lane = tid & 63, wv = tid >> 6;
  size_t row0 = (size_t)b * T_LEN + (size_t)ck * 64;
  size_t wbase = (size_t)blk * 4096;

  if (tid < 64) {
    const float* br = bgraw + (row0 + tid) * 128;
    float bet = 1.f / (1.f + __expf(-(br[h] + bb[h])));
    float g   = 1.f / (1.f + __expf(-(br[12 + h] + bgb[h])));
    float lg = __log2f(g);
    float ci = lg;
    #pragma unroll
    for (int d = 1; d < 64; d <<= 1) { float t = __shfl_up(ci, d); if (tid >= d) ci += t; }
    cs[tid] = ci; cps[tid] = ci - lg; bets[tid] = bet;
    csbuf[(size_t)blk * 64 + tid] = ci;
  }
  int sr = tid >> 2, sc0 = (tid & 3) * 16;
  short8 k0, k1, vreg0, vreg1;
  {
    const __hip_bfloat16* kp = kb16 + (row0 + sr) * 768 + h * 64 + sc0;
    k0 = *(const short8*)kp;
    k1 = *(const short8*)(kp + 8);
    *(short8*)(SA + swz16(sr, sc0 >> 3)) = k0;
    *(short8*)(SA + swz16(sr, (sc0 >> 3) + 1)) = k1;
    const __hip_bfloat16* vp = vbuf + (row0 + sr) * 768 + h * 64 + sc0;
    vreg0 = *(const short8*)vp;
    vreg1 = *(const short8*)(vp + 8);
  }
  __syncthreads();

  floatx4 acc[4], macc[4];
  auto zacc = [&] {
    #pragma unroll
    for (int t = 0; t < 4; ++t) acc[t] = (floatx4){0.f, 0.f, 0.f, 0.f};
  };
  auto stP = [&](char* Or, char* Ot) {          // store acc row+trans
    #pragma unroll
    for (int t = 0; t < 4; ++t)
      #pragma unroll
      for (int r = 0; r < 4; ++r) {
        int i = wv * 16 + (lane >> 4) * 4 + r, j = t * 16 + (lane & 15);
        st_bf(Or, i, j, acc[t][r]);
        st_bf(Ot, j, i, acc[t][r]);
      }
  };
  auto stM = [&](char* Or) {                    // store macc row-major
    #pragma unroll
    for (int t = 0; t < 4; ++t)
      #pragma unroll
      for (int r = 0; r < 4; ++r)
        st_bf(Or, wv * 16 + (lane >> 4) * 4 + r, t * 16 + (lane & 15), macc[t][r]);
  };

  // L-build: G = K K^T -> L row(SB), L trans(SC), M1 lds(SD) + macc=M1
  zacc(); mm16x64(SA, SA, wv, lane, acc);
  #pragma unroll
  for (int t = 0; t < 4; ++t)
    #pragma unroll
    for (int r = 0; r < 4; ++r) {
      int i = wv * 16 + (lane >> 4) * 4 + r, j = t * 16 + (lane & 15);
      float Lv = (j < i) ? bets[i] * exp2f(cps[i] - cs[j]) * acc[t][r] : 0.f;
      st_bf(SB, i, j, Lv);
      st_bf(SC, j, i, Lv);
      float m1 = ((i == j) ? 1.f : 0.f) - Lv;
      st_bf(SD, i, j, m1);
      macc[t][r] = m1;
    }
  __syncthreads();                              // B1
  zacc(); mm16x64(SB, SC, wv, lane, acc);       // s1: P1 = L^2
  stP(SE, SF);
  __syncthreads();                              // B2
  mm16x64(SD, SF, wv, lane, macc); stM(SA);     // s2: M2 ; P2
  zacc(); mm16x64(SE, SF, wv, lane, acc); stP(SB, SC);
  __syncthreads();                              // B3
  mm16x64(SA, SC, wv, lane, macc); stM(SD);     // s3: M3 ; P3
  zacc(); mm16x64(SB, SC, wv, lane, acc); stP(SE, SF);
  __syncthreads();                              // B4
  mm16x64(SD, SF, wv, lane, macc); stM(SA);     // s4: M4 ; P4
  zacc(); mm16x64(SE, SF, wv, lane, acc); stP(SB, SC);
  __syncthreads();                              // B5
  mm16x64(SA, SC, wv, lane, macc); stM(SD);     // s5: M5 ; P5 trans only
  zacc(); mm16x64(SB, SC, wv, lane, acc);
  #pragma unroll
  for (int t = 0; t < 4; ++t)
    #pragma unroll
    for (int r = 0; r < 4; ++r)
      st_bf(SF, t * 16 + (lane & 15), wv * 16 + (lane >> 4) * 4 + r, acc[t][r]);
  __syncthreads();                              // B6
  mm16x64(SD, SF, wv, lane, macc); stM(SE);     // s6: T ; RHST -> SA..SB
  {
    float be = bets[sr];
    #pragma unroll
    for (int q = 0; q < 8; ++q) {
      st_bf(SA, sc0 + q,     sr, be * bf2f(((unsigned short*)&vreg0)[q]));
      st_bf(SA, sc0 + 8 + q, sr, be * bf2f(((unsigned short*)&vreg1)[q]));
    }
    float scl = be * exp2f(cps[sr]);
    #pragma unroll
    for (int q = 0; q < 8; ++q) {
      st_bf(SA, 64 + sc0 + q,     sr, scl * bf2f(((unsigned short*)&k0)[q]));
      st_bf(SA, 64 + sc0 + 8 + q, sr, scl * bf2f(((unsigned short*)&k1)[q]));
    }
  }
  __syncthreads();                              // B7
  // X = T(SE) * RHS -> Uvt to SF (trans); W^T rows to HBM ([k][j])
  {
    floatx4 xacc[8];
    #pragma unroll
    for (int t = 0; t < 8; ++t) xacc[t] = (floatx4){0.f, 0.f, 0.f, 0.f};
    #pragma unroll
    for (int ks = 0; ks < 2; ++ks) {
      short8 af = *(const short8*)(SE + swz16(wv * 16 + (lane & 15), ks * 4 + (lane >> 4)));
      #pragma unroll
      for (int t = 0; t < 8; ++t) {
        short8 bf = *(const short8*)(SA + swz16(t * 16 + (lane & 15), ks * 4 + (lane >> 4)));
        xacc[t] = __builtin_amdgcn_mfma_f32_16x16x32_bf16(af, bf, xacc[t], 0, 0, 0);
      }
    }
    #pragma unroll
    for (int t = 0; t < 8; ++t) {
      int c = t * 16 + (lane & 15);
      #pragma unroll
      for (int r = 0; r < 4; ++r) {
        int i = wv * 16 + (lane >> 4) * 4 + r;
        float v = xacc[t][r];
        if (c < 64) st_bf(SF, c, i, v);
        else        W_g[wbase + (size_t)(c - 64) * 64 + i] = __float2bfloat16(v);
      }
    }
  }
  __syncthreads();                              // B8
  {
    int s2 = (tid & 3) * 2;
    short8 a0 = *(const short8*)(SF + swz16(sr, s2));
    short8 a1 = *(const short8*)(SF + swz16(sr, s2 + 1));
    *(short8*)(Uvt_g + wbase + (size_t)sr * 64 + s2 * 8) = a0;
    *(short8*)(Uvt_g + wbase + (size_t)sr * 64 + s2 * 8 + 8) = a1;
  }
}

// ---------------- scan A: per-group map composition (T14 prefetch) ----------
__global__ __launch_bounds__(256)
void k_scanA(const __hip_bfloat16* __restrict__ kb16, const __hip_bfloat16* __restrict__ W_g,
             const __hip_bfloat16* __restrict__ Uvt_g, const float* __restrict__ csbuf,
             __hip_bfloat16* __restrict__ Ag_g, __hip_bfloat16* __restrict__ Bg_g) {
  __shared__ __align__(16) char sm[6 * 8192];
  char* SK  = sm;              // Ktil^T [k][t]
  char* SW  = sm + 8192;       // Wt [k][j]
  char* SU  = sm + 2 * 8192;   // Uvt [v][t]
  char* SAc = sm + 3 * 8192;   // Ac [ko][ki]
  char* SAt = sm + 4 * 8192;   // Aacc^T [ki][ko]
  char* SBa = sm + 5 * 8192;   // Bacc [v][k]

  int blk = blockIdx.x, bh = blk >> 4, gg = blk & 15;
  int b = bh / 12, h = bh % 12;
  int tid = threadIdx.x, lane = tid & 63, wv = tid >> 6;
  int sr = tid >> 2, sc0 = (tid & 3) * 16, s2 = (tid & 3) * 2;
  int c0 = gg * 8;

  short8 z = {0, 0, 0, 0, 0, 0, 0, 0};
  *(short8*)(SAt + swz16(sr, s2)) = z;
  *(short8*)(SAt + swz16(sr, s2 + 1)) = z;
  *(short8*)(SBa + swz16(sr, s2)) = z;
  *(short8*)(SBa + swz16(sr, s2 + 1)) = z;
  __syncthreads();
  if (tid < 64) st_bf(SAt, tid, tid, 1.f);   // Aacc = I

  floatx4 acc[4], bcacc[4];
  auto zacc = [&] {
    #pragma unroll
    for (int t = 0; t < 4; ++t) acc[t] = (floatx4){0.f, 0.f, 0.f, 0.f};
  };
  auto ldc = [&](int c, short8& a0, short8& a1, short8& b0, short8& b1,
                 short8& u0, short8& u1) {
    size_t row0 = (size_t)b * T_LEN + (size_t)c * 64;
    size_t wb = ((size_t)bh * NC + c) * 4096;
    const __hip_bfloat16* kp = kb16 + (row0 + sr) * 768 + h * 64 + sc0;
    a0 = *(const short8*)kp; a1 = *(const short8*)(kp + 8);
    const __hip_bfloat16* wp = W_g + wb + (size_t)sr * 64 + s2 * 8;
    b0 = *(const short8*)wp; b1 = *(const short8*)(wp + 8);
    const __hip_bfloat16* up = Uvt_g + wb + (size_t)sr * 64 + s2 * 8;
    u0 = *(const short8*)up; u1 = *(const short8*)(up + 8);
  };

  short8 k0, k1, w0, w1, u0, u1;
  ldc(c0, k0, k1, w0, w1, u0, u1);

  for (int cc = 0; cc < 8; ++cc) {
    int c = c0 + cc;
    const float* csb = csbuf + (size_t)(bh * NC + c) * 64;
    float cs_sr = csb[sr], cs63 = csb[63];
    // stage
    float scl = exp2f(cs63 - cs_sr);
    #pragma unroll
    for (int q = 0; q < 8; ++q) {
      st_bf(SK, sc0 + q,     sr, scl * bf2f(((unsigned short*)&k0)[q]));
      st_bf(SK, sc0 + 8 + q, sr, scl * bf2f(((unsigned short*)&k1)[q]));
    }
    *(short8*)(SW + swz16(sr, s2)) = w0;
    *(short8*)(SW + swz16(sr, s2 + 1)) = w1;
    *(short8*)(SU + swz16(sr, s2)) = u0;
    *(short8*)(SU + swz16(sr, s2 + 1)) = u1;
    __syncthreads();   // (a) staged; prev compose's SAc reads done
    if (cc < 7) ldc(c + 1, k0, k1, w0, w1, u0, u1);   // T14 prefetch
    float gC = exp2f(cs63);
    #pragma unroll
    for (int t = 0; t < 4; ++t) bcacc[t] = (floatx4){0.f, 0.f, 0.f, 0.f};
    mm16x64(SU, SK, wv, lane, bcacc);
    zacc(); mm16x64(SW, SK, wv, lane, acc);
    #pragma unroll
    for (int t = 0; t < 4; ++t)
      #pragma unroll
      for (int r = 0; r < 4; ++r) {
        int i = wv * 16 + (lane >> 4) * 4 + r, j = t * 16 + (lane & 15);
        st_bf(SAc, j, i, ((i == j) ? gC : 0.f) - acc[t][r]);
      }
    __syncthreads();   // (b) Ac ready
    zacc(); mm16x64(SAt, SAc, wv, lane, acc);
    #pragma unroll
    for (int t = 0; t < 4; ++t)
      #pragma unroll
      for (int r = 0; r < 4; ++r)
        st_bf(SAt, wv * 16 + (lane >> 4) * 4 + r, t * 16 + (lane & 15), acc[t][r]);
    mm16x64(SBa, SAc, wv, lane, bcacc);   // Bacc*Ac + Bc
    #pragma unroll
    for (int t = 0; t < 4; ++t)
      #pragma unroll
      for (int r = 0; r < 4; ++r)
        st_bf(SBa, wv * 16 + (lane >> 4) * 4 + r, t * 16 + (lane & 15), bcacc[t][r]);
  }
  __syncthreads();
  size_t gb = (size_t)blk * 4096;
  #pragma unroll
  for (int q = 0; q < 16; ++q)
    Ag_g[gb + (size_t)(sc0 + q) * 64 + sr] = __float2bfloat16(ld_bf(SAt, sr, sc0 + q));
  {
    short8 b0 = *(const short8*)(SBa + swz16(sr, s2));
    short8 b1 = *(const short8*)(SBa + swz16(sr, s2 + 1));
    *(short8*)(Bg_g + gb + (size_t)sr * 64 + s2 * 8) = b0;
    *(short8*)(Bg_g + gb + (size_t)sr * 64 + s2 * 8 + 8) = b1;
  }
}

// ---------------- scan B: 16 serial group composes ----------------
__global__ __launch_bounds__(256)
void k_scanB(const __hip_bfloat16* __restrict__ Ag_g, const __hip_bfloat16* __restrict__ Bg_g,
             __hip_bfloat16* __restrict__ Sg_g, float* __restrict__ fstate) {
  __shared__ __align__(16) char sm[3 * 8192];
  char* SSt = sm;
  char* SAg = sm + 8192;
  char* SBg = sm + 2 * 8192;
  int bh = blockIdx.x;
  int tid = threadIdx.x, lane = tid & 63, wv = tid >> 6;
  int sr = tid >> 2, s2 = (tid & 3) * 2;

  short8 z = {0, 0, 0, 0, 0, 0, 0, 0};
  *(short8*)(SSt + swz16(sr, s2)) = z;
  *(short8*)(SSt + swz16(sr, s2 + 1)) = z;

  floatx4 acc[4];
  for (int g = 0; g < NG; ++g) {
    size_t gb = ((size_t)bh * NG + g) * 4096;
    const __hip_bfloat16* pa = Ag_g + gb + (size_t)sr * 64 + s2 * 8;
    short8 a0 = *(const short8*)pa, a1 = *(const short8*)(pa + 8);
    const __hip_bfloat16* pb = Bg_g + gb + (size_t)sr * 64 + s2 * 8;
    short8 b0 = *(const short8*)pb, b1 = *(const short8*)(pb + 8);
    __syncthreads();             // SSt stable; prev compose's SAg/SBg reads done
    {  // write group-start state
      short8 s0 = *(const short8*)(SSt + swz16(sr, s2));
      short8 s1 = *(const short8*)(SSt + swz16(sr, s2 + 1));
      *(short8*)(Sg_g + gb + (size_t)sr * 64 + s2 * 8) = s0;
      *(short8*)(Sg_g + gb + (size_t)sr * 64 + s2 * 8 + 8) = s1;
    }
    *(short8*)(SAg + swz16(sr, s2)) = a0;
    *(short8*)(SAg + swz16(sr, s2 + 1)) = a1;
    *(short8*)(SBg + swz16(sr, s2)) = b0;
    *(short8*)(SBg + swz16(sr, s2 + 1)) = b1;
    __syncthreads();
    #pragma unroll
    for (int t = 0; t < 4; ++t) acc[t] = (floatx4){0.f, 0.f, 0.f, 0.f};
    mm16x64(SSt, SAg, wv, lane, acc);
    #pragma unroll
    for (int t = 0; t < 4; ++t) {
      int j = t * 16 + (lane & 15);
      #pragma unroll
      for (int r = 0; r < 4; ++r) {
        int i = wv * 16 + (lane >> 4) * 4 + r;
        float val = acc[t][r] + ld_bf(SBg, i, j);
        st_bf(SSt, i, j, val);
        if (g == NG - 1) fstate[(size_t)bh * 4096 + (size_t)j * 64 + i] = val;
      }
    }
  }
}

// ---------------- fused scan C + outputs (Ueff compose, T14 prefetch) -------
__global__ __launch_bounds__(256)
void k_scfuse(const __hip_bfloat16* __restrict__ kb16, const __hip_bfloat16* __restrict__ W_g,
              const __hip_bfloat16* __restrict__ Uvt_g, const float* __restrict__ csbuf,
              const __hip_bfloat16* __restrict__ Sg_g, __hip_bfloat16* __restrict__ outs) {
  __shared__ __align__(16) char sm[6 * 8192];
  char* SSt = sm;              // state [v][k]
  char* SKr = sm + 8192;       // raw K [t][k]; last phase: out bounce [t][v]
  char* SKt = sm + 2 * 8192;   // Ktil^T [k][t]
  char* SG  = sm + 3 * 8192;   // scaled G [t][t']
  char* SW2 = sm + 4 * 8192;   // W row-major [t][k]
  char* SU  = sm + 5 * 8192;   // Uvt [v][t] -> Ueff

  int blk = blockIdx.x, bh = blk >> 4, gg = blk & 15;
  int b = bh / 12, h = bh % 12;
  int tid = threadIdx.x, lane = tid & 63, wv = tid >> 6;
  int sr = tid >> 2, sc0 = (tid & 3) * 16, s2 = (tid & 3) * 2;
  int c0 = gg * 8;
  int iR0 = wv * 16 + (lane >> 4) * 4;

  {
    const __hip_bfloat16* sp = Sg_g + (size_t)blk * 4096 + (size_t)sr * 64 + s2 * 8;
    short8 s0 = *(const short8*)sp, s1 = *(const short8*)(sp + 8);
    *(short8*)(SSt + swz16(sr, s2)) = s0;
    *(short8*)(SSt + swz16(sr, s2 + 1)) = s1;
  }

  floatx4 acc[4], pAcc[4];
  auto zacc = [&] {
    #pragma unroll
    for (int t = 0; t < 4; ++t) acc[t] = (floatx4){0.f, 0.f, 0.f, 0.f};
  };
  auto forRC = [&](auto&& f) {
    #pragma unroll
    for (int t = 0; t < 4; ++t)
      #pragma unroll
      for (int r = 0; r < 4; ++r)
        f(iR0 + r, t * 16 + (lane & 15), acc[t][r]);
  };
  auto ldc = [&](int c, short8& a0, short8& a1, short8& b0, short8& b1,
                 short8& u0, short8& u1) {
    size_t row0 = (size_t)b * T_LEN + (size_t)c * 64;
    size_t wb = ((size_t)bh * NC + c) * 4096;
    const __hip_bfloat16* kp = kb16 + (row0 + sr) * 768 + h * 64 + sc0;
    a0 = *(const short8*)kp; a1 = *(const short8*)(kp + 8);
    const __hip_bfloat16* wp = W_g + wb + (size_t)sr * 64 + sc0;
    b0 = *(const short8*)wp; b1 = *(const short8*)(wp + 8);
    const __hip_bfloat16* up = Uvt_g + wb + (size_t)sr * 64 + sc0;
    u0 = *(const short8*)up; u1 = *(const short8*)(up + 8);
  };

  short8 k0, k1, w0, w1, u0, u1;
  ldc(c0, k0, k1, w0, w1, u0, u1);

  for (int cc = 0; cc < 8; ++cc) {
    int c = c0 + cc;
    size_t row0 = (size_t)b * T_LEN + (size_t)c * 64;
    const float* csb = csbuf + (size_t)(bh * NC + c) * 64;
    float cs_sr = csb[sr], cs63 = csb[63];
    float csI[4], csJ[4];
    #pragma unroll
    for (int r = 0; r < 4; ++r) csI[r] = csb[iR0 + r];
    #pragma unroll
    for (int t = 0; t < 4; ++t) csJ[t] = csb[t * 16 + (lane & 15)];
    __syncthreads();             // bar A: prev iter's bounce-read + compose done
    // stage 4 tiles
    *(short8*)(SKr + swz16(sr, sc0 >> 3)) = k0;
    *(short8*)(SKr + swz16(sr, (sc0 >> 3) + 1)) = k1;
    {
      float scl = exp2f(cs63 - cs_sr);
      #pragma unroll
      for (int q = 0; q < 8; ++q) {
        st_bf(SKt, sc0 + q,     sr, scl * bf2f(((unsigned short*)&k0)[q]));
        st_bf(SKt, sc0 + 8 + q, sr, scl * bf2f(((unsigned short*)&k1)[q]));
      }
    }
    #pragma unroll
    for (int q = 0; q < 8; ++q) {          // W row-major [j][k] from Wt rows
      st_bf(SW2, sc0 + q,     sr, bf2f(((unsigned short*)&w0)[q]));
      st_bf(SW2, sc0 + 8 + q, sr, bf2f(((unsigned short*)&w1)[q]));
    }
    *(short8*)(SU + swz16(sr, s2)) = u0;
    *(short8*)(SU + swz16(sr, s2 + 1)) = u1;
    __syncthreads();             // bar B: staged
    if (cc < 7) ldc(c + 1, k0, k1, w0, w1, u0, u1);   // T14: hides under C/D
    // G (scaled, lower-tri), P = K·S0^T (regs), Ueff = Uv − S0·W^T (in place)
    zacc(); mm16x64(SKr, SKr, wv, lane, acc);
    #pragma unroll
    for (int t = 0; t < 4; ++t) {
      int j = t * 16 + (lane & 15);
      #pragma unroll
      for (int r = 0; r < 4; ++r) {
        int i = iR0 + r;
        float gs = (j <= i) ? exp2f(csI[r] - csJ[t]) * acc[t][r] : 0.f;
        st_bf(SG, i, j, gs);
      }
    }
    #pragma unroll
    for (int t = 0; t < 4; ++t) pAcc[t] = (floatx4){0.f, 0.f, 0.f, 0.f};
    mm16x64(SKr, SSt, wv, lane, pAcc);
    zacc(); mm16x64(SSt, SW2, wv, lane, acc);
    forRC([&](int i, int j, float v) { st_bf(SU, i, j, ld_bf(SU, i, j) - v); });
    __syncthreads();             // bar C: G, Ueff final; SKr free
    // O2 = G·Ueff -> out bounce in SKr; compose S' = gC·S + Ueff·Ktil
    zacc(); mm16x64(SG, SU, wv, lane, acc);
    #pragma unroll
    for (int t = 0; t < 4; ++t) {
      int vc = t * 16 + (lane & 15);
      #pragma unroll
      for (int r = 0; r < 4; ++r) {
        int i = iR0 + r;
        float o = exp2f(csI[r]) * pAcc[t][r] + acc[t][r];
        st_bf(SKr, i, vc, o);
      }
    }
    if (cc < 7) {
      float gC = exp2f(cs63);
      zacc(); mm16x64(SU, SKt, wv, lane, acc);
      forRC([&](int i, int j, float v) { st_bf(SSt, i, j, gC * ld_bf(SSt, i, j) + v); });
    }
    __syncthreads();             // bar D: bounce + state ready
    {
      short8 a0 = *(const short8*)(SKr + swz16(sr, s2));
      short8 a1 = *(const short8*)(SKr + swz16(sr, s2 + 1));
      __hip_bfloat16* op = outs + (row0 + sr) * 768 + h * 64 + s2 * 8;
      *(short8*)op = a0;
      *(short8*)(op + 8) = a1;
    }
  }
}

// ---------------- host glue ----------------
extern "C" void kernel_launch(void* const* d_in, const int* in_sizes, int n_in,
                              void* d_out, int out_size, void* d_ws, size_t ws_size,
                              hipStream_t stream) {
  (void)in_sizes; (void)n_in; (void)out_size; (void)ws_size;
  const float* x   = (const float*)d_in[0];
  const float* wn  = (const float*)d_in[1];
  const float* Wk  = (const float*)d_in[2];
  const float* Wv  = (const float*)d_in[3];
  const float* Wo  = (const float*)d_in[4];
  const float* Wb  = (const float*)d_in[5];
  const float* bb  = (const float*)d_in[6];
  const float* Wg  = (const float*)d_in[7];
  const float* bgb = (const float*)d_in[8];
  float* out = (float*)d_out;

  char* ws = (char*)d_ws;
  size_t off = 0;
  const size_t TILE = (size_t)NWG1 * 4096 * 2;           // 50.3 MB
  const size_t GTILE = (size_t)NGRP * 4096 * 2;          // 6.3 MB
  // slot1: xn (dead after gemm<0>) ∪ Uvt_g (chunk1 -> scanA/scfuse)
  __hip_bfloat16* xn   = (__hip_bfloat16*)(ws + off);
  __hip_bfloat16* Uvt  = (__hip_bfloat16*)(ws + off); off += TILE;
  __hip_bfloat16* WT   = (__hip_bfloat16*)(ws + off); off += (size_t)NKV * D * 2;
  __hip_bfloat16* WoT  = (__hip_bfloat16*)(ws + off); off += (size_t)D * D * 2;
  __hip_bfloat16* kb16 = (__hip_bfloat16*)(ws + off); off += (size_t)ROWS * D * 2;
  // slot3: vbuf (dead after chunk1) ∪ outs (scfuse -> gemm<1>)
  __hip_bfloat16* vbuf = (__hip_bfloat16*)(ws + off);
  __hip_bfloat16* outsb= (__hip_bfloat16*)(ws + off); off += TILE;
  // slot4: bgraw (dead after chunk1; first 16.8MB) ∪ [Ag|Bg|Sg(18.9MB)|W_g]
  float* bgraw         = (float*)(ws + off);
  __hip_bfloat16* Ag_g = (__hip_bfloat16*)(ws + off);
  __hip_bfloat16* Bg_g = Ag_g + (size_t)NGRP * 4096;
  __hip_bfloat16* Sg_g = Bg_g + (size_t)NGRP * 4096;
  __hip_bfloat16* W_g  = Sg_g + (size_t)NGRP * 4096;
  off += 3 * GTILE + TILE;                               // 69.2 MB slot
  float* csbuf         = (float*)(ws + off);          off += (size_t)NWG1 * 64 * 4;
  // total ~228 MiB

  k_prep_tr<<<144, 256, 0, stream>>>(Wk, WT);
  k_prep_tr<<<144, 256, 0, stream>>>(Wv, WT + (size_t)768 * 768);
  k_prep_tr<<<144, 256, 0, stream>>>(Wo, WoT);
  k_prep_tail<<<384, 256, 0, stream>>>(Wb, Wg, WT);
  k_rmsnorm<<<ROWS / 4, 256, 0, stream>>>(x, wn, xn);
  k_gemm<0><<<dim3(ROWS / 128, NKV / 128), 256, 0, stream>>>(xn, WT, kb16, vbuf, bgraw, nullptr, nullptr);
  k_chunk1<<<NWG1, 256, 0, stream>>>(kb16, vbuf, bgraw, bb, bgb, csbuf, Uvt, W_g);
  k_scanA<<<NGRP, 256, 0, stream>>>(kb16, W_g, Uvt, csbuf, Ag_g, Bg_g);
  k_scanB<<<NBH, 256, 0, stream>>>(Ag_g, Bg_g, Sg_g, out + (size_t)ROWS * D);
  k_scfuse<<<NGRP, 256, 0, stream>>>(kb16, W_g, Uvt, csbuf, Sg_g, outsb);
  k_gemm<1><<<dim3(ROWS / 128, D / 128), 256, 0, stream>>>(outsb, WoT, nullptr, nullptr, nullptr, out, x);
}